// Round 9
// baseline (3421.195 us; speedup 1.0000x reference)
//
#include <hip/hip_runtime.h>

#define S_LEN 2048
#define HID 4096
#define NH 32
#define HD 128
#define QKV_N 12288   // 3*HID

typedef __attribute__((ext_vector_type(8))) short bf16x8;
typedef __attribute__((ext_vector_type(4))) float f32x4;

__device__ __forceinline__ unsigned short f2bf(float f) {
    unsigned int u = __float_as_uint(f);
    u += 0x7FFF + ((u >> 16) & 1);
    return (unsigned short)(u >> 16);
}
__device__ __forceinline__ float bf2f(unsigned short h) {
    return __uint_as_float(((unsigned int)h) << 16);
}

typedef __attribute__((address_space(1))) const void gconst_void;
typedef __attribute__((address_space(3))) void lds_void;
__device__ __forceinline__ void gl16(const void* g, void* l) {
    __builtin_amdgcn_global_load_lds((gconst_void*)g, (lds_void*)l, 16, 0, 0);
}

#define VMCNT(n) asm volatile("s_waitcnt vmcnt(" #n ")" ::: "memory")
#define BAR()    do { asm volatile("" ::: "memory"); __builtin_amdgcn_s_barrier(); asm volatile("" ::: "memory"); } while (0)

// ---------------- fp32 -> bf16 linear convert ----------------
__global__ __launch_bounds__(256)
void cvt_f32_bf16(const float* __restrict__ in, unsigned short* __restrict__ out, int n8)
{
    int i = blockIdx.x * 256 + threadIdx.x;
    if (i >= n8) return;
    const float4* p = (const float4*)in + (size_t)i * 2;
    float4 a = p[0], b = p[1];
    bf16x8 o;
    o[0] = (short)f2bf(a.x); o[1] = (short)f2bf(a.y); o[2] = (short)f2bf(a.z); o[3] = (short)f2bf(a.w);
    o[4] = (short)f2bf(b.x); o[5] = (short)f2bf(b.y); o[6] = (short)f2bf(b.z); o[7] = (short)f2bf(b.w);
    *((bf16x8*)out + i) = o;
}

// ---------------- fp32 [K][N] -> bf16 [N][K] transpose-convert (up to 3 weights) ----------------
struct W3 { const float* w0; const float* w1; const float* w2; };

__global__ __launch_bounds__(256)
void cvt_w_t3(W3 ws3, unsigned short* __restrict__ Wt, int N, int K)
{
    __shared__ unsigned short t[64][72];
    const float* W = blockIdx.z == 0 ? ws3.w0 : (blockIdx.z == 1 ? ws3.w1 : ws3.w2);
    unsigned short* Wto = Wt + (size_t)blockIdx.z * N * K;
    const int tid = threadIdx.x;
    const int n0 = blockIdx.x * 64, k0 = blockIdx.y * 64;
    const int c4 = (tid & 15) * 4;
    const int r  = tid >> 4;
    #pragma unroll
    for (int p = 0; p < 4; ++p) {
        float4 v = *(const float4*)&W[(size_t)(k0 + r + p * 16) * N + n0 + c4];
        ushort4 o;
        o.x = f2bf(v.x); o.y = f2bf(v.y); o.z = f2bf(v.z); o.w = f2bf(v.w);
        *(ushort4*)&t[r + p * 16][c4] = o;
    }
    __syncthreads();
    const int n = tid >> 2;
    const int kq = (tid & 3) * 16;
    unsigned short* dst = &Wto[(size_t)(n0 + n) * K + k0 + kq];
    bf16x8 v0, v1;
    #pragma unroll
    for (int j = 0; j < 8; ++j) v0[j] = (short)t[kq + j][n];
    #pragma unroll
    for (int j = 0; j < 8; ++j) v1[j] = (short)t[kq + 8 + j][n];
    *(bf16x8*)dst = v0;
    *(bf16x8*)(dst + 8) = v1;
}

// ---------------- bf16 V slab [s][c] -> Vtg [c][s] transpose ----------------
__global__ __launch_bounds__(256)
void v_transpose(const unsigned short* __restrict__ QKV, unsigned short* __restrict__ Vtg)
{
    __shared__ unsigned short t[64][72];
    const int tid = threadIdx.x;
    const int s0 = blockIdx.x * 64;
    const int c0 = blockIdx.y * 64;
    #pragma unroll
    for (int i = 0; i < 2; ++i) {
        int idx = i * 256 + tid;
        int r = idx >> 3, c8 = (idx & 7) * 8;
        *(bf16x8*)&t[r][c8] = *(const bf16x8*)&QKV[(size_t)(s0 + r) * QKV_N + 2 * HID + c0 + c8];
    }
    __syncthreads();
    #pragma unroll
    for (int i = 0; i < 2; ++i) {
        int idx = i * 256 + tid;
        int oc = idx >> 3, os8 = (idx & 7) * 8;
        bf16x8 v;
        #pragma unroll
        for (int j = 0; j < 8; ++j) v[j] = (short)t[os8 + j][oc];
        *(bf16x8*)&Vtg[(size_t)(c0 + oc) * S_LEN + s0 + os8] = v;
    }
}

// ---------------- 256x256 BK=32 GEMM, 64KB LDS dbuf, 2 blocks/CU ----------------
// C[M,N] = A[M,ldk-slice] * Bt[N,ldk-slice]^T, k-slice = blockIdx.z*K .. +K
// out bf16 at Cp + blockIdx.z*M*N (z=0 for non-split calls)
__global__ __launch_bounds__(512, 4)
void gemm32(const unsigned short* __restrict__ A,
            const unsigned short* __restrict__ Bt,
            unsigned short* __restrict__ Cp, int M, int N, int K, int ldk)
{
    extern __shared__ char lds[];   // 65536: [buf 0/1][A 16KB | B 16KB]
    const int tid = threadIdx.x;
    const int l   = tid & 63;
    const int l15 = l & 15, lg = l >> 4;
    const int wid = tid >> 6;
    const int wr  = wid >> 2;      // 0..1
    const int wc  = wid & 3;       // 0..3

    // column-slab XCD mapping (nwg%8==0): XCD owns contiguous B-strips
    const int nwg = gridDim.x;
    const int bid = blockIdx.x;
    const int ntx = N >> 8;
    const int nty = M >> 8;
    const int cpx = ntx >> 3;
    const int xcd = bid & 7;
    const int idx = bid >> 3;
    const int bx = xcd * cpx + idx / nty;
    const int by = idx % nty;
    const int m0 = by * 256, n0 = bx * 256;
    const int koff = blockIdx.z * K;

    // staging maps: linear LDS dest (gl16 = wave-uniform base + lane*16),
    // pre-swizzled global k-slot: sg = sl ^ ((row>>1)&3), same formula for A and B
    const int sg = (tid & 3) ^ ((tid >> 3) & 3);
    const int arow = tid >> 2;                         // A rows: i*128 + arow
    const int col0 = tid >> 2;
    const int b0col = (col0 & 31) + ((col0 >> 5) << 6);   // strips' cols 0..31
    const int b1col = b0col + 32;                          // cols 32..63

    const unsigned short* As0 = A  + (size_t)(m0 + arow) * ldk + koff + sg * 8;
    const unsigned short* As1 = A  + (size_t)(m0 + 128 + arow) * ldk + koff + sg * 8;
    const unsigned short* Bs0 = Bt + (size_t)(n0 + b0col) * ldk + koff + sg * 8;
    const unsigned short* Bs1 = Bt + (size_t)(n0 + b1col) * ldk + koff + sg * 8;
    const int adst0 = tid * 16;
    const int adst1 = 8192 + tid * 16;
    const int bdst0 = 16384 + b0col * 64 + (tid & 3) * 16;
    const int bdst1 = 16384 + b1col * 64 + (tid & 3) * 16;

    const int rsw = ((lg ^ ((l15 >> 1) & 3)) << 4);    // read-side swizzle (byte)

    f32x4 acc[8][4] = {};
    bf16x8 af[8], bf[4];

    // prologue: tile 0 -> buf0; issue order A0,A1,B0,B1 (FIFO is load-bearing)
    gl16(As0, lds + adst0);
    gl16(As1, lds + adst1);
    gl16(Bs0, lds + bdst0);
    gl16(Bs1, lds + bdst1);
    VMCNT(1);          // A+Bg0 landed; Bg1 outstanding (invariant)
    BAR();

    const int NT = K >> 5;
    for (int t = 0; t < NT; ++t) {
        const int cb = (t & 1) << 15;
        const int nb = cb ^ 32768;
        const int kk = (t + 1) * 32;
        const bool hn = (t + 1) < NT;

        // P1: read af[0..7], bf[0..1] from cb; issue next tile (A0,A1,Bg0,Bg1)
        #pragma unroll
        for (int i = 0; i < 8; ++i)
            af[i] = *(const bf16x8*)(lds + cb + (wr * 128 + i * 16 + l15) * 64 + rsw);
        #pragma unroll
        for (int j = 0; j < 2; ++j)
            bf[j] = *(const bf16x8*)(lds + cb + 16384 + (wc * 64 + j * 16 + l15) * 64 + rsw);
        if (hn) {
            gl16(As0 + kk, lds + nb + adst0);
            gl16(As1 + kk, lds + nb + adst1);
            gl16(Bs0 + kk, lds + nb + bdst0);
            gl16(Bs1 + kk, lds + nb + bdst1);
        }
        BAR();
        __builtin_amdgcn_s_setprio(1);
        #pragma unroll
        for (int i = 0; i < 8; ++i)
            #pragma unroll
            for (int j = 0; j < 2; ++j)
                acc[i][j] = __builtin_amdgcn_mfma_f32_16x16x32_bf16(af[i], bf[j], acc[i][j], 0, 0, 0);
        __builtin_amdgcn_s_setprio(0);
        if (hn) { VMCNT(4); } else { VMCNT(0); }   // retire Bg1(t) before P2 reads it
        BAR();

        // P2: read bf[2..3] from cb
        #pragma unroll
        for (int j = 2; j < 4; ++j)
            bf[j] = *(const bf16x8*)(lds + cb + 16384 + (wc * 64 + j * 16 + l15) * 64 + rsw);
        BAR();
        __builtin_amdgcn_s_setprio(1);
        #pragma unroll
        for (int i = 0; i < 8; ++i)
            #pragma unroll
            for (int j = 2; j < 4; ++j)
                acc[i][j] = __builtin_amdgcn_mfma_f32_16x16x32_bf16(af[i], bf[j], acc[i][j], 0, 0, 0);
        __builtin_amdgcn_s_setprio(0);
        VMCNT(1);      // retire {A0,A1,Bg0}(t+1); Bg1(t+1) stays (invariant)
        BAR();
    }

    unsigned short* C = Cp + (size_t)blockIdx.z * M * N;
    const int crow = m0 + wr * 128 + lg * 4;
    const int ccol = n0 + wc * 64 + l15;
    #pragma unroll
    for (int mi = 0; mi < 8; ++mi)
        #pragma unroll
        for (int nj = 0; nj < 4; ++nj)
            #pragma unroll
            for (int rr = 0; rr < 4; ++rr)
                C[(size_t)(crow + mi * 16 + rr) * N + ccol + nj * 16] = f2bf(acc[mi][nj][rr]);
}

// ---------------- combine 4 bf16 split-K partials -> fp32 out ----------------
__global__ __launch_bounds__(256)
void combine4(const unsigned short* __restrict__ P, float* __restrict__ out)
{
    const size_t i = ((size_t)blockIdx.x * 256 + threadIdx.x) * 8;
    const size_t stride = (size_t)S_LEN * HID;
    float s[8] = {};
    #pragma unroll
    for (int z = 0; z < 4; ++z) {
        bf16x8 v = *(const bf16x8*)&P[z * stride + i];
        #pragma unroll
        for (int j = 0; j < 8; ++j) s[j] += bf2f((unsigned short)v[j]);
    }
    float4 f0 = {s[0], s[1], s[2], s[3]};
    float4 f1 = {s[4], s[5], s[6], s[7]};
    *(float4*)&out[i] = f0;
    *(float4*)&out[i + 4] = f1;
}

// ---------------- per-head LayerNorm + RoPE, in place on combined QKV bf16 [S][12288] ----------------
__global__ __launch_bounds__(256)
void ln_rope(unsigned short* __restrict__ QKV,
             const float* __restrict__ qg, const float* __restrict__ qb,
             const float* __restrict__ kg, const float* __restrict__ kb,
             const int* __restrict__ pos)
{
    const int tid = threadIdx.x;
    const int l = tid & 63;
    const int w = tid >> 6;
    const int rid = blockIdx.x * 4 + w;
    const int s = rid >> 6;
    const int hh = rid & 63;
    const int which = hh >> 5;
    const int h = hh & 31;
    unsigned short* p = QKV + (size_t)s * QKV_N + which * HID + h * HD;
    const float* gamma = which ? kg : qg;
    const float* beta  = which ? kb : qb;

    float lo = bf2f(p[l]);
    float hi = bf2f(p[l + 64]);
    float sum = lo + hi;
    #pragma unroll
    for (int off = 32; off >= 1; off >>= 1) sum += __shfl_xor(sum, off, 64);
    float mu = sum * (1.0f / 128.0f);
    float dlo = lo - mu, dhi = hi - mu;
    float vs = dlo * dlo + dhi * dhi;
    #pragma unroll
    for (int off = 32; off >= 1; off >>= 1) vs += __shfl_xor(vs, off, 64);
    float rstd = rsqrtf(vs * (1.0f / 128.0f) + 1e-5f);
    float xlo = dlo * rstd * gamma[l] + beta[l];
    float xhi = dhi * rstd * gamma[l + 64] + beta[l + 64];

    float fpos = (float)pos[s];
    float invf = exp2f(-13.287712379549449f * (float)l * (1.0f / 64.0f));
    float ang = fpos * invf;
    float sn, cs;
    sincosf(ang, &sn, &cs);
    p[l]      = f2bf(xlo * cs - xhi * sn);
    p[l + 64] = f2bf(xhi * cs + xlo * sn);
}

// ---------------- causal flash attention: KVB=64, counted-vmcnt dbuf pipeline ----------------
#define KVB 64

__global__ __launch_bounds__(256)
void attn_fwd(const unsigned short* __restrict__ QKV,   // [S][12288]
              const unsigned short* __restrict__ Vtg,   // [4096][S]
              unsigned short* __restrict__ O)           // [S][4096]
{
    __shared__ unsigned short Ks[2][KVB * HD];
    __shared__ unsigned short Vs[2][HD * KVB];
    __shared__ unsigned short Ps[4][16 * 72];

    const int tid = threadIdx.x;
    const int l = tid & 63;
    const int w = tid >> 6;
    const int l15 = l & 15, lg = l >> 4;
    const int h = blockIdx.y;
    const int qb = gridDim.x - 1 - blockIdx.x;
    const int q0 = qb * 64;
    const int qw = q0 + w * 16;

    const unsigned short* Qp = QKV + h * HD;
    const unsigned short* Kp = QKV + HID + h * HD;
    const unsigned short* Vp = Vtg + (size_t)h * HD * S_LEN;

    bf16x8 qf[4];
    #pragma unroll
    for (int d = 0; d < 4; ++d)
        qf[d] = *(const bf16x8*)&Qp[(size_t)(qw + l15) * QKV_N + d * 32 + lg * 8];

    f32x4 o_acc[8] = {};
    float mrow[4], lrow[4];
    #pragma unroll
    for (int r = 0; r < 4; ++r) { mrow[r] = -1e30f; lrow[r] = 0.0f; }

    const float scale = 0.08838834764831845f;

    const int ksl = tid & 15;
    const int kr7 = (tid >> 4) & 7;
    const int ksg = (ksl & 8) | ((ksl ^ kr7) & 7);
    const unsigned short* Kg = Kp + (size_t)(tid >> 4) * QKV_N + ksg * 8;
    const int vsg = (tid & 7) ^ ((tid >> 3) & 7);
    const unsigned short* Vg = Vp + (size_t)(tid >> 3) * S_LEN + vsg * 8;

#define STAGE(buf, kv0s) do {                                                          \
    _Pragma("unroll")                                                                  \
    for (int i_ = 0; i_ < 4; ++i_)                                                     \
        gl16(Kg + (size_t)((kv0s) + i_ * 16) * QKV_N,                                  \
             (char*)Ks[buf] + (i_ * 256 + tid) * 16);                                  \
    _Pragma("unroll")                                                                  \
    for (int i_ = 0; i_ < 4; ++i_)                                                     \
        gl16(Vg + (size_t)i_ * 32 * S_LEN + (kv0s),                                    \
             (char*)Vs[buf] + (i_ * 256 + tid) * 16);                                  \
} while (0)

    STAGE(0, 0);
    VMCNT(4);
    __syncthreads();

    const int nt = q0 / KVB + 1;
    for (int t = 0; t < nt; ++t) {
        const int kv0 = t * KVB;
        const int cur = t & 1;
        const bool hn = (t + 1) < nt;
        if (hn) STAGE(cur ^ 1, kv0 + KVB);

        f32x4 sc[4] = {};
        #pragma unroll
        for (int kvf = 0; kvf < 4; ++kvf) {
            int r = kvf * 16 + l15;
            int sw = (r & 7) << 4;
            #pragma unroll
            for (int d = 0; d < 4; ++d) {
                bf16x8 kf = *(const bf16x8*)((const char*)Ks[cur] + r * 256 + ((d * 64 + lg * 16) ^ sw));
                sc[kvf] = __builtin_amdgcn_mfma_f32_16x16x32_bf16(qf[d], kf, sc[kvf], 0, 0, 0);
            }
        }

        const bool full = (kv0 + KVB <= qw);
        #pragma unroll
        for (int r = 0; r < 4; ++r) {
            int qg = qw + lg * 4 + r;
            float s0, s1, s2, s3;
            if (full) {
                s0 = sc[0][r] * scale; s1 = sc[1][r] * scale;
                s2 = sc[2][r] * scale; s3 = sc[3][r] * scale;
            } else {
                s0 = (kv0 + l15      <= qg) ? sc[0][r] * scale : -1e30f;
                s1 = (kv0 + 16 + l15 <= qg) ? sc[1][r] * scale : -1e30f;
                s2 = (kv0 + 32 + l15 <= qg) ? sc[2][r] * scale : -1e30f;
                s3 = (kv0 + 48 + l15 <= qg) ? sc[3][r] * scale : -1e30f;
            }
            float mx = fmaxf(fmaxf(s0, s1), fmaxf(s2, s3));
            #pragma unroll
            for (int off = 8; off >= 1; off >>= 1) mx = fmaxf(mx, __shfl_xor(mx, off, 64));
            float mn = mrow[r];
            if (!__all(mx <= mn + 8.0f)) {
                mn = fmaxf(mn, mx);
                float corr = __expf(mrow[r] - mn);
                lrow[r] *= corr;
                #pragma unroll
                for (int df = 0; df < 8; ++df) o_acc[df][r] *= corr;
                mrow[r] = mn;
            }
            float p0 = __expf(s0 - mn);
            float p1 = __expf(s1 - mn);
            float p2 = __expf(s2 - mn);
            float p3 = __expf(s3 - mn);
            float rs = (p0 + p1) + (p2 + p3);
            #pragma unroll
            for (int off = 8; off >= 1; off >>= 1) rs += __shfl_xor(rs, off, 64);
            lrow[r] += rs;
            int ql = lg * 4 + r;
            Ps[w][ql * 72 + l15]      = f2bf(p0);
            Ps[w][ql * 72 + 16 + l15] = f2bf(p1);
            Ps[w][ql * 72 + 32 + l15] = f2bf(p2);
            Ps[w][ql * 72 + 48 + l15] = f2bf(p3);
        }

        if (hn) { VMCNT(8); } else { VMCNT(0); }
        BAR();

        bf16x8 pa0 = *(const bf16x8*)&Ps[w][l15 * 72 + lg * 8];
        bf16x8 pa1 = *(const bf16x8*)&Ps[w][l15 * 72 + 32 + lg * 8];
        #pragma unroll
        for (int df = 0; df < 8; ++df) {
            int d = df * 16 + l15;
            int sw = (d & 7) << 4;
            const char* vrow = (const char*)Vs[cur] + d * 128;
            bf16x8 v0 = *(const bf16x8*)(vrow + ((lg * 16) ^ sw));
            bf16x8 v1 = *(const bf16x8*)(vrow + ((64 + lg * 16) ^ sw));
            o_acc[df] = __builtin_amdgcn_mfma_f32_16x16x32_bf16(pa0, v0, o_acc[df], 0, 0, 0);
            o_acc[df] = __builtin_amdgcn_mfma_f32_16x16x32_bf16(pa1, v1, o_acc[df], 0, 0, 0);
        }

        VMCNT(4);
        BAR();
    }
#undef STAGE

    #pragma unroll
    for (int df = 0; df < 8; ++df) {
        #pragma unroll
        for (int r = 0; r < 4; ++r) {
            int q = qw + lg * 4 + r;
            int d = h * HD + df * 16 + l15;
            O[(size_t)q * HID + d] = f2bf(o_acc[df][r] / lrow[r]);
        }
    }
}

extern "C" void kernel_launch(void* const* d_in, const int* in_sizes, int n_in,
                              void* d_out, int out_size, void* d_ws, size_t ws_size,
                              hipStream_t stream)
{
    (void)in_sizes; (void)n_in; (void)out_size; (void)ws_size;
    const float* X    = (const float*)d_in[0];
    const int*   pos  = (const int*)d_in[1];
    const float* Wq   = (const float*)d_in[2];
    const float* Wk   = (const float*)d_in[3];
    const float* Wv   = (const float*)d_in[4];
    const float* Wo   = (const float*)d_in[5];
    const float* qn_w = (const float*)d_in[6];
    const float* qn_b = (const float*)d_in[7];
    const float* kn_w = (const float*)d_in[8];
    const float* kn_b = (const float*)d_in[9];
    float* out = (float*)d_out;

    // ws: Xb/Ab @0 (16.8M) | QKVb @16.8M (50.3M) | Wt(3 slots) @67.1M (100.7M)
    //     Vtg @134.2M (aliases Wv^T slot, dead after QKV GEMM)
    //     Wo split-K partials @100.7M (67.1M, alias Wk^T/Wv^T slots, dead after QKV GEMM / attn)
    unsigned short* Xb    = (unsigned short*)d_ws;
    unsigned short* QKVb  = (unsigned short*)((char*)d_ws + 16777216);
    unsigned short* Wt    = (unsigned short*)((char*)d_ws + 67108864);
    unsigned short* Vtg   = (unsigned short*)((char*)d_ws + 134217728);
    unsigned short* Pp    = (unsigned short*)((char*)d_ws + 100663296);
    unsigned short* Ab    = Xb;

    (void)hipFuncSetAttribute((const void*)gemm32, hipFuncAttributeMaxDynamicSharedMemorySize, 65536);

    dim3 blk(256);

    cvt_f32_bf16<<<dim3((S_LEN * HID / 8 + 255) / 256), blk, 0, stream>>>(X, Xb, S_LEN * HID / 8);

    W3 w3{Wq, Wk, Wv};
    cvt_w_t3<<<dim3(HID / 64, HID / 64, 3), blk, 0, stream>>>(w3, Wt, HID, HID);

    // fused QKV GEMM: 384 blocks, 2 blocks/CU co-resident, one round
    gemm32<<<dim3(384, 1, 1), dim3(512), 65536, stream>>>(Xb, Wt, QKVb, S_LEN, QKV_N, HID, HID);

    v_transpose<<<dim3(S_LEN / 64, HID / 64), blk, 0, stream>>>(QKVb, Vtg);
    ln_rope<<<dim3(S_LEN * 64 / 4), blk, 0, stream>>>(QKVb, qn_w, qn_b, kn_w, kn_b, pos);

    attn_fwd<<<dim3(S_LEN / 64, NH), blk, 0, stream>>>(QKVb, Vtg, Ab);

    W3 wo3{Wo, Wo, Wo};
    cvt_w_t3<<<dim3(HID / 64, HID / 64, 1), blk, 0, stream>>>(wo3, Wt, HID, HID);

    // Wo projection: split-K x4 (512 blocks = full machine), bf16 partials + fp32 combine
    gemm32<<<dim3(128, 1, 4), dim3(512), 65536, stream>>>(Ab, Wt, Pp, S_LEN, HID, HID / 4, HID);
    combine4<<<dim3(S_LEN * HID / 8 / 256), blk, 0, stream>>>(Pp, out);
}

// Round 10
// 576.543 us; speedup vs baseline: 5.9340x; 5.9340x over previous
//
#include <hip/hip_runtime.h>

#define S_LEN 2048
#define HID 4096
#define NH 32
#define HD 128
#define QKV_N 12288   // 3*HID

typedef __attribute__((ext_vector_type(8))) short bf16x8;
typedef __attribute__((ext_vector_type(4))) float f32x4;

__device__ __forceinline__ unsigned short f2bf(float f) {
    unsigned int u = __float_as_uint(f);
    u += 0x7FFF + ((u >> 16) & 1);
    return (unsigned short)(u >> 16);
}
__device__ __forceinline__ float bf2f(unsigned short h) {
    return __uint_as_float(((unsigned int)h) << 16);
}

typedef __attribute__((address_space(1))) const void gconst_void;
typedef __attribute__((address_space(3))) void lds_void;
__device__ __forceinline__ void gl16(const void* g, void* l) {
    __builtin_amdgcn_global_load_lds((gconst_void*)g, (lds_void*)l, 16, 0, 0);
}

#define VMCNT(n) asm volatile("s_waitcnt vmcnt(" #n ")" ::: "memory")
#define BAR()    do { asm volatile("" ::: "memory"); __builtin_amdgcn_s_barrier(); asm volatile("" ::: "memory"); } while (0)

// ---------------- fp32 -> bf16 linear convert ----------------
__global__ __launch_bounds__(256)
void cvt_f32_bf16(const float* __restrict__ in, unsigned short* __restrict__ out, int n8)
{
    int i = blockIdx.x * 256 + threadIdx.x;
    if (i >= n8) return;
    const float4* p = (const float4*)in + (size_t)i * 2;
    float4 a = p[0], b = p[1];
    bf16x8 o;
    o[0] = (short)f2bf(a.x); o[1] = (short)f2bf(a.y); o[2] = (short)f2bf(a.z); o[3] = (short)f2bf(a.w);
    o[4] = (short)f2bf(b.x); o[5] = (short)f2bf(b.y); o[6] = (short)f2bf(b.z); o[7] = (short)f2bf(b.w);
    *((bf16x8*)out + i) = o;
}

// ---------------- fp32 [K][N] -> bf16 [N][K] transpose-convert (up to 3 weights) ----------------
struct W3 { const float* w0; const float* w1; const float* w2; };

__global__ __launch_bounds__(256)
void cvt_w_t3(W3 ws3, unsigned short* __restrict__ Wt, int N, int K)
{
    __shared__ unsigned short t[64][72];
    const float* W = blockIdx.z == 0 ? ws3.w0 : (blockIdx.z == 1 ? ws3.w1 : ws3.w2);
    unsigned short* Wto = Wt + (size_t)blockIdx.z * N * K;
    const int tid = threadIdx.x;
    const int n0 = blockIdx.x * 64, k0 = blockIdx.y * 64;
    const int c4 = (tid & 15) * 4;
    const int r  = tid >> 4;
    #pragma unroll
    for (int p = 0; p < 4; ++p) {
        float4 v = *(const float4*)&W[(size_t)(k0 + r + p * 16) * N + n0 + c4];
        ushort4 o;
        o.x = f2bf(v.x); o.y = f2bf(v.y); o.z = f2bf(v.z); o.w = f2bf(v.w);
        *(ushort4*)&t[r + p * 16][c4] = o;
    }
    __syncthreads();
    const int n = tid >> 2;
    const int kq = (tid & 3) * 16;
    unsigned short* dst = &Wto[(size_t)(n0 + n) * K + k0 + kq];
    bf16x8 v0, v1;
    #pragma unroll
    for (int j = 0; j < 8; ++j) v0[j] = (short)t[kq + j][n];
    #pragma unroll
    for (int j = 0; j < 8; ++j) v1[j] = (short)t[kq + 8 + j][n];
    *(bf16x8*)dst = v0;
    *(bf16x8*)(dst + 8) = v1;
}

// ---------------- bf16 V slab [s][c] -> Vtg [c][s] transpose (+ optional split-K combine) ----------------
template<bool SPLIT>
__global__ __launch_bounds__(256)
void v_transpose(const unsigned short* __restrict__ P0, const unsigned short* __restrict__ P1,
                 unsigned short* __restrict__ Vtg)
{
    __shared__ unsigned short t[64][72];
    const int tid = threadIdx.x;
    const int s0 = blockIdx.x * 64;
    const int c0 = blockIdx.y * 64;
    #pragma unroll
    for (int i = 0; i < 2; ++i) {
        int idx = i * 256 + tid;
        int r = idx >> 3, c8 = (idx & 7) * 8;
        size_t off = (size_t)(s0 + r) * QKV_N + 2 * HID + c0 + c8;
        bf16x8 a = *(const bf16x8*)&P0[off];
        if (SPLIT) {
            bf16x8 b = *(const bf16x8*)&P1[off];
            #pragma unroll
            for (int j = 0; j < 8; ++j)
                a[j] = (short)f2bf(bf2f((unsigned short)a[j]) + bf2f((unsigned short)b[j]));
        }
        *(bf16x8*)&t[r][c8] = a;
    }
    __syncthreads();
    #pragma unroll
    for (int i = 0; i < 2; ++i) {
        int idx = i * 256 + tid;
        int oc = idx >> 3, os8 = (idx & 7) * 8;
        bf16x8 v;
        #pragma unroll
        for (int j = 0; j < 8; ++j) v[j] = (short)t[os8 + j][oc];
        *(bf16x8*)&Vtg[(size_t)(c0 + oc) * S_LEN + s0 + os8] = v;
    }
}

// ---------------- 256x256 GEMM, bf16 out, optional K-split via blockIdx.z ----------------
__device__ __forceinline__ void lda4(bf16x8 af[4][2], const char* base, int rq, int l15, int lg) {
    const int sw = (l15 & 7) << 4;
    #pragma unroll
    for (int i = 0; i < 4; ++i) {
        const char* rb = base + ((rq * 4 + i) * 16 + l15) * 128;
        af[i][0] = *(const bf16x8*)(rb + ((lg * 16) ^ sw));
        af[i][1] = *(const bf16x8*)(rb + ((64 + lg * 16) ^ sw));
    }
}
__device__ __forceinline__ void ldb2(bf16x8 bf[2][2], const char* base, int cq, int l15, int lg) {
    const int sw = (l15 & 7) << 4;
    #pragma unroll
    for (int j = 0; j < 2; ++j) {
        const char* rb = base + ((cq * 2 + j) * 16 + l15) * 128;
        bf[j][0] = *(const bf16x8*)(rb + ((lg * 16) ^ sw));
        bf[j][1] = *(const bf16x8*)(rb + ((64 + lg * 16) ^ sw));
    }
}
__device__ __forceinline__ void mfma16(f32x4 acc[8][4], const bf16x8 af[4][2], const bf16x8 bf[2][2],
                                       int mi0, int nj0) {
    __builtin_amdgcn_s_setprio(1);
    #pragma unroll
    for (int kk = 0; kk < 2; ++kk)
        #pragma unroll
        for (int i = 0; i < 4; ++i)
            #pragma unroll
            for (int j = 0; j < 2; ++j)
                acc[mi0 + i][nj0 + j] =
                    __builtin_amdgcn_mfma_f32_16x16x32_bf16(af[i][kk], bf[j][kk], acc[mi0 + i][nj0 + j], 0, 0, 0);
    __builtin_amdgcn_s_setprio(0);
}
__device__ __forceinline__ void stage2(const unsigned short* g, char* dst, int ldk, int r32, int kn) {
    gl16(g + (size_t)r32 * ldk + kn, dst);
    gl16(g + (size_t)(r32 + 8) * ldk + kn, dst + 1024);
}

__global__ __launch_bounds__(512, 2)
void gemm256(const unsigned short* __restrict__ A,   // [M][ldk] bf16
             const unsigned short* __restrict__ Bt,  // [N][ldk] bf16
             unsigned short* __restrict__ Cp,        // bf16, + z*zstride
             int N, int K, int ldk, size_t zstride)
{
    extern __shared__ char lds[];
    const int tid = threadIdx.x;
    const int l   = tid & 63;
    const int l15 = l & 15, lg = l >> 4;
    const int wid = tid >> 6;
    const int wr  = wid >> 2;
    const int wc  = wid & 3;

    // column-slab XCD mapping (verified r6: FETCH 410->180MB)
    const int nwg = gridDim.x;
    const int bid = blockIdx.x;
    const int ntx = N >> 8;
    const int nty = nwg / ntx;
    const int cpx = ntx >> 3;
    const int xcd = bid & 7;
    const int idx = bid >> 3;
    const int bx = xcd * cpx + idx / nty;
    const int by = idx % nty;
    const int m0 = by * 256, n0 = bx * 256;
    const int koff = blockIdx.z * K;

    char* const Abase = lds + wr * 16384;
    char* const Bbase = lds + 32768 + (wc >> 1) * 16384 + (wc & 1) * 8192;

    const int l8 = l >> 3, l7 = l & 7;
    const int swslot = (l7 ^ l8) << 3;

    const unsigned short* Ag = A  + (size_t)(m0 + wr * 128 + wc * 16 + l8) * ldk + koff + swslot;
    const unsigned short* Bg = Bt + (size_t)(n0 + wc * 64 + wr * 16 + l8) * ldk + koff + swslot;
    char* const Adst = Abase + (wc * 16) * 128 + l * 16;
    char* const Bdst = Bbase + (wr * 16) * 128 + l * 16;

    f32x4 acc[8][4] = {};
    bf16x8 af[4][2], bf[2][2];

    stage2(Ag, Adst, ldk, 0, 0);
    stage2(Bg, Bdst, ldk, 0, 0);
    stage2(Ag, Adst + 64 * 128, ldk, 64, 0);
    stage2(Bg, Bdst + 32 * 128, ldk, 32, 0);
    VMCNT(0);
    BAR();

    const int NT = K >> 6;
    for (int t = 0; t < NT; ++t) {
        const int cb = (t & 1) * 65536, nb = cb ^ 65536;
        const int kn = (t + 1) << 6;
        const bool hn = (t + 1) < NT;
        // P1
        lda4(af, Abase + cb, 0, l15, lg);
        ldb2(bf, Bbase + cb, 0, l15, lg);
        if (hn) { stage2(Ag, Adst + nb, ldk, 0, kn); stage2(Bg, Bdst + nb, ldk, 0, kn); }
        BAR();
        mfma16(acc, af, bf, 0, 0);
        if (hn) { VMCNT(4); } else { VMCNT(0); }
        BAR();
        // P2
        lda4(af, Abase + cb, 1, l15, lg);
        if (hn) { stage2(Ag, Adst + nb + 64 * 128, ldk, 64, kn); stage2(Bg, Bdst + nb + 32 * 128, ldk, 32, kn); }
        BAR();
        mfma16(acc, af, bf, 4, 0);
        BAR();
        // P3
        ldb2(bf, Bbase + cb, 1, l15, lg);
        BAR();
        mfma16(acc, af, bf, 4, 2);
        BAR();
        // P4
        lda4(af, Abase + cb, 0, l15, lg);
        BAR();
        mfma16(acc, af, bf, 0, 2);
        VMCNT(4);
        BAR();
    }

    unsigned short* C = Cp + (size_t)blockIdx.z * zstride;
    const int crow = m0 + wr * 128 + lg * 4;
    const int ccol = n0 + wc * 64 + l15;
    #pragma unroll
    for (int mi = 0; mi < 8; ++mi)
        #pragma unroll
        for (int nj = 0; nj < 4; ++nj)
            #pragma unroll
            for (int rr = 0; rr < 4; ++rr)
                C[(size_t)(crow + mi * 16 + rr) * N + ccol + nj * 16] = f2bf(acc[mi][nj][rr]);
}

// ---------------- combine 2 bf16 split-K partials -> fp32 out ----------------
__global__ __launch_bounds__(256)
void combine2(const unsigned short* __restrict__ P, float* __restrict__ out)
{
    const size_t i = ((size_t)blockIdx.x * 256 + threadIdx.x) * 8;
    const size_t stride = (size_t)S_LEN * HID;
    bf16x8 a = *(const bf16x8*)&P[i];
    bf16x8 b = *(const bf16x8*)&P[stride + i];
    #pragma unroll
    for (int j = 0; j < 8; ++j)
        out[i + j] = bf2f((unsigned short)a[j]) + bf2f((unsigned short)b[j]);
}

// ---------------- per-head LayerNorm + RoPE (+ optional split-K combine), writes into P0 ----------------
template<bool SPLIT>
__global__ __launch_bounds__(256)
void ln_rope(unsigned short* __restrict__ P0, const unsigned short* __restrict__ P1,
             const float* __restrict__ qg, const float* __restrict__ qb,
             const float* __restrict__ kg, const float* __restrict__ kb,
             const int* __restrict__ pos)
{
    const int tid = threadIdx.x;
    const int l = tid & 63;
    const int w = tid >> 6;
    const int rid = blockIdx.x * 4 + w;
    const int s = rid >> 6;
    const int hh = rid & 63;
    const int which = hh >> 5;
    const int h = hh & 31;
    const size_t off = (size_t)s * QKV_N + which * HID + h * HD;
    unsigned short* p = P0 + off;
    const float* gamma = which ? kg : qg;
    const float* beta  = which ? kb : qb;

    float lo = bf2f(p[l]);
    float hi = bf2f(p[l + 64]);
    if (SPLIT) {
        const unsigned short* q = P1 + off;
        lo += bf2f(q[l]);
        hi += bf2f(q[l + 64]);
    }
    float sum = lo + hi;
    #pragma unroll
    for (int off2 = 32; off2 >= 1; off2 >>= 1) sum += __shfl_xor(sum, off2, 64);
    float mu = sum * (1.0f / 128.0f);
    float dlo = lo - mu, dhi = hi - mu;
    float vs = dlo * dlo + dhi * dhi;
    #pragma unroll
    for (int off2 = 32; off2 >= 1; off2 >>= 1) vs += __shfl_xor(vs, off2, 64);
    float rstd = rsqrtf(vs * (1.0f / 128.0f) + 1e-5f);
    float xlo = dlo * rstd * gamma[l] + beta[l];
    float xhi = dhi * rstd * gamma[l + 64] + beta[l + 64];

    float fpos = (float)pos[s];
    float invf = exp2f(-13.287712379549449f * (float)l * (1.0f / 64.0f));
    float ang = fpos * invf;
    float sn, cs;
    sincosf(ang, &sn, &cs);
    p[l]      = f2bf(xlo * cs - xhi * sn);
    p[l + 64] = f2bf(xhi * cs + xlo * sn);
}

// ---------------- causal flash attention: KVB=64, counted-vmcnt dbuf pipeline (r8, verified) ----------------
#define KVB 64

__global__ __launch_bounds__(256)
void attn_fwd(const unsigned short* __restrict__ QKV,   // [S][12288]
              const unsigned short* __restrict__ Vtg,   // [4096][S]
              unsigned short* __restrict__ O)           // [S][4096]
{
    __shared__ unsigned short Ks[2][KVB * HD];
    __shared__ unsigned short Vs[2][HD * KVB];
    __shared__ unsigned short Ps[4][16 * 72];

    const int tid = threadIdx.x;
    const int l = tid & 63;
    const int w = tid >> 6;
    const int l15 = l & 15, lg = l >> 4;
    const int h = blockIdx.y;
    const int qb = gridDim.x - 1 - blockIdx.x;
    const int q0 = qb * 64;
    const int qw = q0 + w * 16;

    const unsigned short* Qp = QKV + h * HD;
    const unsigned short* Kp = QKV + HID + h * HD;
    const unsigned short* Vp = Vtg + (size_t)h * HD * S_LEN;

    bf16x8 qf[4];
    #pragma unroll
    for (int d = 0; d < 4; ++d)
        qf[d] = *(const bf16x8*)&Qp[(size_t)(qw + l15) * QKV_N + d * 32 + lg * 8];

    f32x4 o_acc[8] = {};
    float mrow[4], lrow[4];
    #pragma unroll
    for (int r = 0; r < 4; ++r) { mrow[r] = -1e30f; lrow[r] = 0.0f; }

    const float scale = 0.08838834764831845f;

    const int ksl = tid & 15;
    const int kr7 = (tid >> 4) & 7;
    const int ksg = (ksl & 8) | ((ksl ^ kr7) & 7);
    const unsigned short* Kg = Kp + (size_t)(tid >> 4) * QKV_N + ksg * 8;
    const int vsg = (tid & 7) ^ ((tid >> 3) & 7);
    const unsigned short* Vg = Vp + (size_t)(tid >> 3) * S_LEN + vsg * 8;

#define STAGE(buf, kv0s) do {                                                          \
    _Pragma("unroll")                                                                  \
    for (int i_ = 0; i_ < 4; ++i_)                                                     \
        gl16(Kg + (size_t)((kv0s) + i_ * 16) * QKV_N,                                  \
             (char*)Ks[buf] + (i_ * 256 + tid) * 16);                                  \
    _Pragma("unroll")                                                                  \
    for (int i_ = 0; i_ < 4; ++i_)                                                     \
        gl16(Vg + (size_t)i_ * 32 * S_LEN + (kv0s),                                    \
             (char*)Vs[buf] + (i_ * 256 + tid) * 16);                                  \
} while (0)

    STAGE(0, 0);
    VMCNT(4);
    __syncthreads();

    const int nt = q0 / KVB + 1;
    for (int t = 0; t < nt; ++t) {
        const int kv0 = t * KVB;
        const int cur = t & 1;
        const bool hn = (t + 1) < nt;
        if (hn) STAGE(cur ^ 1, kv0 + KVB);

        f32x4 sc[4] = {};
        #pragma unroll
        for (int kvf = 0; kvf < 4; ++kvf) {
            int r = kvf * 16 + l15;
            int sw = (r & 7) << 4;
            #pragma unroll
            for (int d = 0; d < 4; ++d) {
                bf16x8 kf = *(const bf16x8*)((const char*)Ks[cur] + r * 256 + ((d * 64 + lg * 16) ^ sw));
                sc[kvf] = __builtin_amdgcn_mfma_f32_16x16x32_bf16(qf[d], kf, sc[kvf], 0, 0, 0);
            }
        }

        const bool full = (kv0 + KVB <= qw);
        #pragma unroll
        for (int r = 0; r < 4; ++r) {
            int qg = qw + lg * 4 + r;
            float s0, s1, s2, s3;
            if (full) {
                s0 = sc[0][r] * scale; s1 = sc[1][r] * scale;
                s2 = sc[2][r] * scale; s3 = sc[3][r] * scale;
            } else {
                s0 = (kv0 + l15      <= qg) ? sc[0][r] * scale : -1e30f;
                s1 = (kv0 + 16 + l15 <= qg) ? sc[1][r] * scale : -1e30f;
                s2 = (kv0 + 32 + l15 <= qg) ? sc[2][r] * scale : -1e30f;
                s3 = (kv0 + 48 + l15 <= qg) ? sc[3][r] * scale : -1e30f;
            }
            float mx = fmaxf(fmaxf(s0, s1), fmaxf(s2, s3));
            #pragma unroll
            for (int off = 8; off >= 1; off >>= 1) mx = fmaxf(mx, __shfl_xor(mx, off, 64));
            float mn = mrow[r];
            if (!__all(mx <= mn + 8.0f)) {
                mn = fmaxf(mn, mx);
                float corr = __expf(mrow[r] - mn);
                lrow[r] *= corr;
                #pragma unroll
                for (int df = 0; df < 8; ++df) o_acc[df][r] *= corr;
                mrow[r] = mn;
            }
            float p0 = __expf(s0 - mn);
            float p1 = __expf(s1 - mn);
            float p2 = __expf(s2 - mn);
            float p3 = __expf(s3 - mn);
            float rs = (p0 + p1) + (p2 + p3);
            #pragma unroll
            for (int off = 8; off >= 1; off >>= 1) rs += __shfl_xor(rs, off, 64);
            lrow[r] += rs;
            int ql = lg * 4 + r;
            Ps[w][ql * 72 + l15]      = f2bf(p0);
            Ps[w][ql * 72 + 16 + l15] = f2bf(p1);
            Ps[w][ql * 72 + 32 + l15] = f2bf(p2);
            Ps[w][ql * 72 + 48 + l15] = f2bf(p3);
        }

        if (hn) { VMCNT(8); } else { VMCNT(0); }
        BAR();

        bf16x8 pa0 = *(const bf16x8*)&Ps[w][l15 * 72 + lg * 8];
        bf16x8 pa1 = *(const bf16x8*)&Ps[w][l15 * 72 + 32 + lg * 8];
        #pragma unroll
        for (int df = 0; df < 8; ++df) {
            int d = df * 16 + l15;
            int sw = (d & 7) << 4;
            const char* vrow = (const char*)Vs[cur] + d * 128;
            bf16x8 v0 = *(const bf16x8*)(vrow + ((lg * 16) ^ sw));
            bf16x8 v1 = *(const bf16x8*)(vrow + ((64 + lg * 16) ^ sw));
            o_acc[df] = __builtin_amdgcn_mfma_f32_16x16x32_bf16(pa0, v0, o_acc[df], 0, 0, 0);
            o_acc[df] = __builtin_amdgcn_mfma_f32_16x16x32_bf16(pa1, v1, o_acc[df], 0, 0, 0);
        }

        VMCNT(4);
        BAR();
    }
#undef STAGE

    #pragma unroll
    for (int df = 0; df < 8; ++df) {
        #pragma unroll
        for (int r = 0; r < 4; ++r) {
            int q = qw + lg * 4 + r;
            int d = h * HD + df * 16 + l15;
            O[(size_t)q * HID + d] = f2bf(o_acc[df][r] / lrow[r]);
        }
    }
}

extern "C" void kernel_launch(void* const* d_in, const int* in_sizes, int n_in,
                              void* d_out, int out_size, void* d_ws, size_t ws_size,
                              hipStream_t stream)
{
    (void)in_sizes; (void)n_in; (void)out_size;
    const float* X    = (const float*)d_in[0];
    const int*   pos  = (const int*)d_in[1];
    const float* Wq   = (const float*)d_in[2];
    const float* Wk   = (const float*)d_in[3];
    const float* Wv   = (const float*)d_in[4];
    const float* Wo   = (const float*)d_in[5];
    const float* qn_w = (const float*)d_in[6];
    const float* qn_b = (const float*)d_in[7];
    const float* kn_w = (const float*)d_in[8];
    const float* kn_b = (const float*)d_in[9];
    float* out = (float*)d_out;

    // ws layout:
    //   Xb/Ab   @ 0          (16.8M)
    //   QKVb/P0 @ 16.8M      (50.3M)
    //   Wt x3   @ 67.1M      (100.7M)  [slot2 @100.7M reused for Wo partials; slot3 @134.2M for Vtg]
    //   P1      @ 167.8M     (50.3M)   [only if ws_size >= 218.2M]
    unsigned short* Xb    = (unsigned short*)d_ws;
    unsigned short* QKVb  = (unsigned short*)((char*)d_ws + 16777216);
    unsigned short* Wt    = (unsigned short*)((char*)d_ws + 67108864);
    unsigned short* Pp    = (unsigned short*)((char*)d_ws + 100663296);
    unsigned short* Vtg   = (unsigned short*)((char*)d_ws + 134217728);
    unsigned short* P1    = (unsigned short*)((char*)d_ws + 167772160);
    unsigned short* Ab    = Xb;

    const bool splitQKV = ws_size >= (size_t)218103808;

    (void)hipFuncSetAttribute((const void*)gemm256, hipFuncAttributeMaxDynamicSharedMemorySize, 131072);

    dim3 blk(256);

    cvt_f32_bf16<<<dim3((S_LEN * HID / 8 + 255) / 256), blk, 0, stream>>>(X, Xb, S_LEN * HID / 8);

    W3 w3{Wq, Wk, Wv};
    cvt_w_t3<<<dim3(HID / 64, HID / 64, 3), blk, 0, stream>>>(w3, Wt, HID, HID);

    // fused QKV GEMM; split-K x2 when workspace allows (768 blocks = 3 full rounds vs 2x 75% rounds)
    if (splitQKV) {
        gemm256<<<dim3(384, 1, 2), dim3(512), 131072, stream>>>(
            Xb, Wt, QKVb, QKV_N, HID / 2, HID, (size_t)75497472);
        v_transpose<true><<<dim3(S_LEN / 64, HID / 64), blk, 0, stream>>>(QKVb, P1, Vtg);
        ln_rope<true><<<dim3(S_LEN * 64 / 4), blk, 0, stream>>>(QKVb, P1, qn_w, qn_b, kn_w, kn_b, pos);
    } else {
        gemm256<<<dim3(384, 1, 1), dim3(512), 131072, stream>>>(
            Xb, Wt, QKVb, QKV_N, HID, HID, (size_t)0);
        v_transpose<false><<<dim3(S_LEN / 64, HID / 64), blk, 0, stream>>>(QKVb, QKVb, Vtg);
        ln_rope<false><<<dim3(S_LEN * 64 / 4), blk, 0, stream>>>(QKVb, QKVb, qn_w, qn_b, kn_w, kn_b, pos);
    }

    attn_fwd<<<dim3(S_LEN / 64, NH), blk, 0, stream>>>(QKVb, Vtg, Ab);

    W3 wo3{Wo, Wo, Wo};
    cvt_w_t3<<<dim3(HID / 64, HID / 64, 1), blk, 0, stream>>>(wo3, Wt, HID, HID);

    // Wo projection: split-K x2 (256 blocks = exactly one full round), bf16 partials + fp32 combine
    gemm256<<<dim3(128, 1, 2), dim3(512), 131072, stream>>>(
        Ab, Wt, Pp, HID, HID / 2, HID, (size_t)S_LEN * HID);
    combine2<<<dim3(S_LEN * HID / 8 / 256), blk, 0, stream>>>(Pp, out);
}

// Round 11
// 532.429 us; speedup vs baseline: 6.4256x; 1.0829x over previous
//
#include <hip/hip_runtime.h>

#define S_LEN 2048
#define HID 4096
#define NH 32
#define HD 128
#define QKV_N 12288   // 3*HID

typedef __attribute__((ext_vector_type(8))) short bf16x8;
typedef __attribute__((ext_vector_type(4))) float f32x4;

__device__ __forceinline__ unsigned short f2bf(float f) {
    unsigned int u = __float_as_uint(f);
    u += 0x7FFF + ((u >> 16) & 1);
    return (unsigned short)(u >> 16);
}
__device__ __forceinline__ float bf2f(unsigned short h) {
    return __uint_as_float(((unsigned int)h) << 16);
}

typedef __attribute__((address_space(1))) const void gconst_void;
typedef __attribute__((address_space(3))) void lds_void;
__device__ __forceinline__ void gl16(const void* g, void* l) {
    __builtin_amdgcn_global_load_lds((gconst_void*)g, (lds_void*)l, 16, 0, 0);
}

#define VMCNT(n) asm volatile("s_waitcnt vmcnt(" #n ")" ::: "memory")
#define BAR()    do { asm volatile("" ::: "memory"); __builtin_amdgcn_s_barrier(); asm volatile("" ::: "memory"); } while (0)

// ---------------- fp32 -> bf16 linear convert ----------------
__global__ __launch_bounds__(256)
void cvt_f32_bf16(const float* __restrict__ in, unsigned short* __restrict__ out, int n8)
{
    int i = blockIdx.x * 256 + threadIdx.x;
    if (i >= n8) return;
    const float4* p = (const float4*)in + (size_t)i * 2;
    float4 a = p[0], b = p[1];
    bf16x8 o;
    o[0] = (short)f2bf(a.x); o[1] = (short)f2bf(a.y); o[2] = (short)f2bf(a.z); o[3] = (short)f2bf(a.w);
    o[4] = (short)f2bf(b.x); o[5] = (short)f2bf(b.y); o[6] = (short)f2bf(b.z); o[7] = (short)f2bf(b.w);
    *((bf16x8*)out + i) = o;
}

// ---------------- fp32 [K][N] -> bf16 [N][K] transpose-convert (up to 3 weights) ----------------
struct W3 { const float* w0; const float* w1; const float* w2; };

__global__ __launch_bounds__(256)
void cvt_w_t3(W3 ws3, unsigned short* __restrict__ Wt, int N, int K)
{
    __shared__ unsigned short t[64][72];
    const float* W = blockIdx.z == 0 ? ws3.w0 : (blockIdx.z == 1 ? ws3.w1 : ws3.w2);
    unsigned short* Wto = Wt + (size_t)blockIdx.z * N * K;
    const int tid = threadIdx.x;
    const int n0 = blockIdx.x * 64, k0 = blockIdx.y * 64;
    const int c4 = (tid & 15) * 4;
    const int r  = tid >> 4;
    #pragma unroll
    for (int p = 0; p < 4; ++p) {
        float4 v = *(const float4*)&W[(size_t)(k0 + r + p * 16) * N + n0 + c4];
        ushort4 o;
        o.x = f2bf(v.x); o.y = f2bf(v.y); o.z = f2bf(v.z); o.w = f2bf(v.w);
        *(ushort4*)&t[r + p * 16][c4] = o;
    }
    __syncthreads();
    const int n = tid >> 2;
    const int kq = (tid & 3) * 16;
    unsigned short* dst = &Wto[(size_t)(n0 + n) * K + k0 + kq];
    bf16x8 v0, v1;
    #pragma unroll
    for (int j = 0; j < 8; ++j) v0[j] = (short)t[kq + j][n];
    #pragma unroll
    for (int j = 0; j < 8; ++j) v1[j] = (short)t[kq + 8 + j][n];
    *(bf16x8*)dst = v0;
    *(bf16x8*)(dst + 8) = v1;
}

// ---------------- bf16 V slab [s][c] -> Vtg [c][s] transpose (+ optional split-K combine) ----------------
template<bool SPLIT>
__global__ __launch_bounds__(256)
void v_transpose(const unsigned short* __restrict__ P0, const unsigned short* __restrict__ P1,
                 unsigned short* __restrict__ Vtg)
{
    __shared__ unsigned short t[64][72];
    const int tid = threadIdx.x;
    const int s0 = blockIdx.x * 64;
    const int c0 = blockIdx.y * 64;
    #pragma unroll
    for (int i = 0; i < 2; ++i) {
        int idx = i * 256 + tid;
        int r = idx >> 3, c8 = (idx & 7) * 8;
        size_t off = (size_t)(s0 + r) * QKV_N + 2 * HID + c0 + c8;
        bf16x8 a = *(const bf16x8*)&P0[off];
        if (SPLIT) {
            bf16x8 b = *(const bf16x8*)&P1[off];
            #pragma unroll
            for (int j = 0; j < 8; ++j)
                a[j] = (short)f2bf(bf2f((unsigned short)a[j]) + bf2f((unsigned short)b[j]));
        }
        *(bf16x8*)&t[r][c8] = a;
    }
    __syncthreads();
    #pragma unroll
    for (int i = 0; i < 2; ++i) {
        int idx = i * 256 + tid;
        int oc = idx >> 3, os8 = (idx & 7) * 8;
        bf16x8 v;
        #pragma unroll
        for (int j = 0; j < 8; ++j) v[j] = (short)t[os8 + j][oc];
        *(bf16x8*)&Vtg[(size_t)(c0 + oc) * S_LEN + s0 + os8] = v;
    }
}

// ---------------- 256x256 GEMM, bf16 out, optional K-split via blockIdx.z ----------------
__device__ __forceinline__ void lda4(bf16x8 af[4][2], const char* base, int rq, int l15, int lg) {
    const int sw = (l15 & 7) << 4;
    #pragma unroll
    for (int i = 0; i < 4; ++i) {
        const char* rb = base + ((rq * 4 + i) * 16 + l15) * 128;
        af[i][0] = *(const bf16x8*)(rb + ((lg * 16) ^ sw));
        af[i][1] = *(const bf16x8*)(rb + ((64 + lg * 16) ^ sw));
    }
}
__device__ __forceinline__ void ldb2(bf16x8 bf[2][2], const char* base, int cq, int l15, int lg) {
    const int sw = (l15 & 7) << 4;
    #pragma unroll
    for (int j = 0; j < 2; ++j) {
        const char* rb = base + ((cq * 2 + j) * 16 + l15) * 128;
        bf[j][0] = *(const bf16x8*)(rb + ((lg * 16) ^ sw));
        bf[j][1] = *(const bf16x8*)(rb + ((64 + lg * 16) ^ sw));
    }
}
__device__ __forceinline__ void mfma16(f32x4 acc[8][4], const bf16x8 af[4][2], const bf16x8 bf[2][2],
                                       int mi0, int nj0) {
    __builtin_amdgcn_s_setprio(1);
    #pragma unroll
    for (int kk = 0; kk < 2; ++kk)
        #pragma unroll
        for (int i = 0; i < 4; ++i)
            #pragma unroll
            for (int j = 0; j < 2; ++j)
                acc[mi0 + i][nj0 + j] =
                    __builtin_amdgcn_mfma_f32_16x16x32_bf16(af[i][kk], bf[j][kk], acc[mi0 + i][nj0 + j], 0, 0, 0);
    __builtin_amdgcn_s_setprio(0);
}
__device__ __forceinline__ void stage2(const unsigned short* g, char* dst, int ldk, int r32, int kn) {
    gl16(g + (size_t)r32 * ldk + kn, dst);
    gl16(g + (size_t)(r32 + 8) * ldk + kn, dst + 1024);
}

__global__ __launch_bounds__(512, 2)
void gemm256(const unsigned short* __restrict__ A,   // [M][ldk] bf16
             const unsigned short* __restrict__ Bt,  // [N][ldk] bf16
             unsigned short* __restrict__ Cp,        // bf16, + z*zstride
             int N, int K, int ldk, size_t zstride)
{
    extern __shared__ char lds[];
    const int tid = threadIdx.x;
    const int l   = tid & 63;
    const int l15 = l & 15, lg = l >> 4;
    const int wid = tid >> 6;
    const int wr  = wid >> 2;
    const int wc  = wid & 3;

    const int nwg = gridDim.x;
    const int bid = blockIdx.x;
    const int ntx = N >> 8;
    const int nty = nwg / ntx;
    const int cpx = ntx >> 3;
    const int xcd = bid & 7;
    const int idx = bid >> 3;
    const int bx = xcd * cpx + idx / nty;
    const int by = idx % nty;
    const int m0 = by * 256, n0 = bx * 256;
    const int koff = blockIdx.z * K;

    char* const Abase = lds + wr * 16384;
    char* const Bbase = lds + 32768 + (wc >> 1) * 16384 + (wc & 1) * 8192;

    const int l8 = l >> 3, l7 = l & 7;
    const int swslot = (l7 ^ l8) << 3;

    const unsigned short* Ag = A  + (size_t)(m0 + wr * 128 + wc * 16 + l8) * ldk + koff + swslot;
    const unsigned short* Bg = Bt + (size_t)(n0 + wc * 64 + wr * 16 + l8) * ldk + koff + swslot;
    char* const Adst = Abase + (wc * 16) * 128 + l * 16;
    char* const Bdst = Bbase + (wr * 16) * 128 + l * 16;

    f32x4 acc[8][4] = {};
    bf16x8 af[4][2], bf[2][2];

    stage2(Ag, Adst, ldk, 0, 0);
    stage2(Bg, Bdst, ldk, 0, 0);
    stage2(Ag, Adst + 64 * 128, ldk, 64, 0);
    stage2(Bg, Bdst + 32 * 128, ldk, 32, 0);
    VMCNT(0);
    BAR();

    const int NT = K >> 6;
    for (int t = 0; t < NT; ++t) {
        const int cb = (t & 1) * 65536, nb = cb ^ 65536;
        const int kn = (t + 1) << 6;
        const bool hn = (t + 1) < NT;
        // P1
        lda4(af, Abase + cb, 0, l15, lg);
        ldb2(bf, Bbase + cb, 0, l15, lg);
        if (hn) { stage2(Ag, Adst + nb, ldk, 0, kn); stage2(Bg, Bdst + nb, ldk, 0, kn); }
        BAR();
        mfma16(acc, af, bf, 0, 0);
        if (hn) { VMCNT(4); } else { VMCNT(0); }
        BAR();
        // P2
        lda4(af, Abase + cb, 1, l15, lg);
        if (hn) { stage2(Ag, Adst + nb + 64 * 128, ldk, 64, kn); stage2(Bg, Bdst + nb + 32 * 128, ldk, 32, kn); }
        BAR();
        mfma16(acc, af, bf, 4, 0);
        BAR();
        // P3
        ldb2(bf, Bbase + cb, 1, l15, lg);
        BAR();
        mfma16(acc, af, bf, 4, 2);
        BAR();
        // P4
        lda4(af, Abase + cb, 0, l15, lg);
        BAR();
        mfma16(acc, af, bf, 0, 2);
        VMCNT(4);
        BAR();
    }

    unsigned short* C = Cp + (size_t)blockIdx.z * zstride;
    const int crow = m0 + wr * 128 + lg * 4;
    const int ccol = n0 + wc * 64 + l15;
    #pragma unroll
    for (int mi = 0; mi < 8; ++mi)
        #pragma unroll
        for (int nj = 0; nj < 4; ++nj)
            #pragma unroll
            for (int rr = 0; rr < 4; ++rr)
                C[(size_t)(crow + mi * 16 + rr) * N + ccol + nj * 16] = f2bf(acc[mi][nj][rr]);
}

// ---------------- combine 2 bf16 split-K partials -> fp32 out ----------------
__global__ __launch_bounds__(256)
void combine2(const unsigned short* __restrict__ P, float* __restrict__ out)
{
    const size_t i = ((size_t)blockIdx.x * 256 + threadIdx.x) * 8;
    const size_t stride = (size_t)S_LEN * HID;
    bf16x8 a = *(const bf16x8*)&P[i];
    bf16x8 b = *(const bf16x8*)&P[stride + i];
    #pragma unroll
    for (int j = 0; j < 8; ++j)
        out[i + j] = bf2f((unsigned short)a[j]) + bf2f((unsigned short)b[j]);
}

// ---------------- per-head LayerNorm + RoPE (+ optional split-K combine), writes into P0 ----------------
template<bool SPLIT>
__global__ __launch_bounds__(256)
void ln_rope(unsigned short* __restrict__ P0, const unsigned short* __restrict__ P1,
             const float* __restrict__ qg, const float* __restrict__ qb,
             const float* __restrict__ kg, const float* __restrict__ kb,
             const int* __restrict__ pos)
{
    const int tid = threadIdx.x;
    const int l = tid & 63;
    const int w = tid >> 6;
    const int rid = blockIdx.x * 4 + w;
    const int s = rid >> 6;
    const int hh = rid & 63;
    const int which = hh >> 5;
    const int h = hh & 31;
    const size_t off = (size_t)s * QKV_N + which * HID + h * HD;
    unsigned short* p = P0 + off;
    const float* gamma = which ? kg : qg;
    const float* beta  = which ? kb : qb;

    float lo = bf2f(p[l]);
    float hi = bf2f(p[l + 64]);
    if (SPLIT) {
        const unsigned short* q = P1 + off;
        lo += bf2f(q[l]);
        hi += bf2f(q[l + 64]);
    }
    float sum = lo + hi;
    #pragma unroll
    for (int off2 = 32; off2 >= 1; off2 >>= 1) sum += __shfl_xor(sum, off2, 64);
    float mu = sum * (1.0f / 128.0f);
    float dlo = lo - mu, dhi = hi - mu;
    float vs = dlo * dlo + dhi * dhi;
    #pragma unroll
    for (int off2 = 32; off2 >= 1; off2 >>= 1) vs += __shfl_xor(vs, off2, 64);
    float rstd = rsqrtf(vs * (1.0f / 128.0f) + 1e-5f);
    float xlo = dlo * rstd * gamma[l] + beta[l];
    float xhi = dhi * rstd * gamma[l + 64] + beta[l + 64];

    float fpos = (float)pos[s];
    float invf = exp2f(-13.287712379549449f * (float)l * (1.0f / 64.0f));
    float ang = fpos * invf;
    float sn, cs;
    sincosf(ang, &sn, &cs);
    p[l]      = f2bf(xlo * cs - xhi * sn);
    p[l + 64] = f2bf(xhi * cs + xlo * sn);
}

// ---------------- causal flash attention: 8 waves x 16 rows (QBLK=128), KVB=64 dbuf pipeline ----------------
#define KVB 64

__global__ __launch_bounds__(512)
void attn_fwd(const unsigned short* __restrict__ QKV,   // [S][12288]
              const unsigned short* __restrict__ Vtg,   // [4096][S]
              unsigned short* __restrict__ O)           // [S][4096]
{
    __shared__ unsigned short Ks[2][KVB * HD];   // 16KB each; K/V shared by 8 waves
    __shared__ unsigned short Vs[2][HD * KVB];
    __shared__ unsigned short Ps[8][16 * 72];

    const int tid = threadIdx.x;
    const int l = tid & 63;
    const int w = tid >> 6;                      // 0..7
    const int l15 = l & 15, lg = l >> 4;
    const int h = blockIdx.y;
    const int qb = gridDim.x - 1 - blockIdx.x;   // longest blocks first
    const int q0 = qb * 128;
    const int qw = q0 + w * 16;

    const unsigned short* Qp = QKV + h * HD;
    const unsigned short* Kp = QKV + HID + h * HD;
    const unsigned short* Vp = Vtg + (size_t)h * HD * S_LEN;

    bf16x8 qf[4];
    #pragma unroll
    for (int d = 0; d < 4; ++d)
        qf[d] = *(const bf16x8*)&Qp[(size_t)(qw + l15) * QKV_N + d * 32 + lg * 8];

    f32x4 o_acc[8] = {};
    float mrow[4], lsum[4];                       // lsum: per-LANE partial row sums
    #pragma unroll
    for (int r = 0; r < 4; ++r) { mrow[r] = -1e30f; lsum[r] = 0.0f; }

    const float scale = 0.08838834764831845f;

    // staging (512 threads, 2 chunks each for K and V; pre-swizzled global sources)
    const int ksl = tid & 15;
    const int kr7 = (tid >> 4) & 7;
    const int ksg = (ksl & 8) | ((ksl ^ kr7) & 7);
    const unsigned short* Kg = Kp + (size_t)(tid >> 4) * QKV_N + ksg * 8;
    const int vsg = (tid & 7) ^ ((tid >> 3) & 7);
    const unsigned short* Vg = Vp + (size_t)(tid >> 3) * S_LEN + vsg * 8;

    // issue order per tile: K,K then V,V (FIFO order is load-bearing for the vmcnt counts)
#define STAGE(buf, kv0s) do {                                                          \
    _Pragma("unroll")                                                                  \
    for (int i_ = 0; i_ < 2; ++i_)                                                     \
        gl16(Kg + (size_t)((kv0s) + i_ * 32) * QKV_N,                                  \
             (char*)Ks[buf] + (i_ * 512 + tid) * 16);                                  \
    _Pragma("unroll")                                                                  \
    for (int i_ = 0; i_ < 2; ++i_)                                                     \
        gl16(Vg + (size_t)i_ * 64 * S_LEN + (kv0s),                                    \
             (char*)Vs[buf] + (i_ * 512 + tid) * 16);                                  \
} while (0)

    STAGE(0, 0);
    VMCNT(2);        // K0 landed; V0's 2 stay in flight
    __syncthreads();

    // invariant entering tile t: outstanding = V(t) x2
    const int nt = 2 * qb + 2;
    for (int t = 0; t < nt; ++t) {
        const int kv0 = t * KVB;
        const int cur = t & 1;
        const bool hn = (t + 1) < nt;
        if (hn) STAGE(cur ^ 1, kv0 + KVB);   // outstanding: V(t)2 + K(t+1)2 + V(t+1)2

        f32x4 sc[4] = {};
        #pragma unroll
        for (int kvf = 0; kvf < 4; ++kvf) {
            int r = kvf * 16 + l15;
            int sw = (r & 7) << 4;
            #pragma unroll
            for (int d = 0; d < 4; ++d) {
                bf16x8 kf = *(const bf16x8*)((const char*)Ks[cur] + r * 256 + ((d * 64 + lg * 16) ^ sw));
                sc[kvf] = __builtin_amdgcn_mfma_f32_16x16x32_bf16(qf[d], kf, sc[kvf], 0, 0, 0);
            }
        }

        const bool full = (kv0 + KVB <= qw);
        #pragma unroll
        for (int r = 0; r < 4; ++r) {
            int qg = qw + lg * 4 + r;
            float s0, s1, s2, s3;
            if (full) {
                s0 = sc[0][r] * scale; s1 = sc[1][r] * scale;
                s2 = sc[2][r] * scale; s3 = sc[3][r] * scale;
            } else {
                s0 = (kv0 + l15      <= qg) ? sc[0][r] * scale : -1e30f;
                s1 = (kv0 + 16 + l15 <= qg) ? sc[1][r] * scale : -1e30f;
                s2 = (kv0 + 32 + l15 <= qg) ? sc[2][r] * scale : -1e30f;
                s3 = (kv0 + 48 + l15 <= qg) ? sc[3][r] * scale : -1e30f;
            }
            float mx = fmaxf(fmaxf(s0, s1), fmaxf(s2, s3));
            #pragma unroll
            for (int off = 8; off >= 1; off >>= 1) mx = fmaxf(mx, __shfl_xor(mx, off, 64));
            float mn = mrow[r];
            if (!__all(mx <= mn + 8.0f)) {
                mn = fmaxf(mn, mx);
                float corr = __expf(mrow[r] - mn);
                lsum[r] *= corr;
                #pragma unroll
                for (int df = 0; df < 8; ++df) o_acc[df][r] *= corr;
                mrow[r] = mn;
            }
            float p0 = __expf(s0 - mn);
            float p1 = __expf(s1 - mn);
            float p2 = __expf(s2 - mn);
            float p3 = __expf(s3 - mn);
            lsum[r] += (p0 + p1) + (p2 + p3);   // per-lane partial; reduced once at the end
            int ql = lg * 4 + r;
            Ps[w][ql * 72 + l15]      = f2bf(p0);
            Ps[w][ql * 72 + 16 + l15] = f2bf(p1);
            Ps[w][ql * 72 + 32 + l15] = f2bf(p2);
            Ps[w][ql * 72 + 48 + l15] = f2bf(p3);
        }

        // own V(t) landed (oldest 2); mid-barrier: ALL waves' V(t) landed (V rows cross-wave)
        if (hn) { VMCNT(4); } else { VMCNT(0); }
        BAR();

        bf16x8 pa0 = *(const bf16x8*)&Ps[w][l15 * 72 + lg * 8];
        bf16x8 pa1 = *(const bf16x8*)&Ps[w][l15 * 72 + 32 + lg * 8];
        #pragma unroll
        for (int df = 0; df < 8; ++df) {
            int d = df * 16 + l15;
            int sw = (d & 7) << 4;
            const char* vrow = (const char*)Vs[cur] + d * 128;
            bf16x8 v0 = *(const bf16x8*)(vrow + ((lg * 16) ^ sw));
            bf16x8 v1 = *(const bf16x8*)(vrow + ((64 + lg * 16) ^ sw));
            o_acc[df] = __builtin_amdgcn_mfma_f32_16x16x32_bf16(pa0, v0, o_acc[df], 0, 0, 0);
            o_acc[df] = __builtin_amdgcn_mfma_f32_16x16x32_bf16(pa1, v1, o_acc[df], 0, 0, 0);
        }

        VMCNT(2);   // K(t+1) landed; leaves V(t+1) x2 -> invariant
        BAR();
    }
#undef STAGE

    // final row-sum reduce (once, not per tile)
    float inv[4];
    #pragma unroll
    for (int r = 0; r < 4; ++r) {
        float s = lsum[r];
        #pragma unroll
        for (int off = 8; off >= 1; off >>= 1) s += __shfl_xor(s, off, 64);
        inv[r] = 1.0f / s;
    }
    #pragma unroll
    for (int df = 0; df < 8; ++df) {
        #pragma unroll
        for (int r = 0; r < 4; ++r) {
            int q = qw + lg * 4 + r;
            int d = h * HD + df * 16 + l15;
            O[(size_t)q * HID + d] = f2bf(o_acc[df][r] * inv[r]);
        }
    }
}

extern "C" void kernel_launch(void* const* d_in, const int* in_sizes, int n_in,
                              void* d_out, int out_size, void* d_ws, size_t ws_size,
                              hipStream_t stream)
{
    (void)in_sizes; (void)n_in; (void)out_size;
    const float* X    = (const float*)d_in[0];
    const int*   pos  = (const int*)d_in[1];
    const float* Wq   = (const float*)d_in[2];
    const float* Wk   = (const float*)d_in[3];
    const float* Wv   = (const float*)d_in[4];
    const float* Wo   = (const float*)d_in[5];
    const float* qn_w = (const float*)d_in[6];
    const float* qn_b = (const float*)d_in[7];
    const float* kn_w = (const float*)d_in[8];
    const float* kn_b = (const float*)d_in[9];
    float* out = (float*)d_out;

    unsigned short* Xb    = (unsigned short*)d_ws;
    unsigned short* QKVb  = (unsigned short*)((char*)d_ws + 16777216);
    unsigned short* Wt    = (unsigned short*)((char*)d_ws + 67108864);
    unsigned short* Pp    = (unsigned short*)((char*)d_ws + 100663296);
    unsigned short* Vtg   = (unsigned short*)((char*)d_ws + 134217728);
    unsigned short* P1    = (unsigned short*)((char*)d_ws + 167772160);
    unsigned short* Ab    = Xb;

    const bool splitQKV = ws_size >= (size_t)218103808;

    (void)hipFuncSetAttribute((const void*)gemm256, hipFuncAttributeMaxDynamicSharedMemorySize, 131072);

    dim3 blk(256);

    cvt_f32_bf16<<<dim3((S_LEN * HID / 8 + 255) / 256), blk, 0, stream>>>(X, Xb, S_LEN * HID / 8);

    W3 w3{Wq, Wk, Wv};
    cvt_w_t3<<<dim3(HID / 64, HID / 64, 3), blk, 0, stream>>>(w3, Wt, HID, HID);

    if (splitQKV) {
        gemm256<<<dim3(384, 1, 2), dim3(512), 131072, stream>>>(
            Xb, Wt, QKVb, QKV_N, HID / 2, HID, (size_t)75497472);
        v_transpose<true><<<dim3(S_LEN / 64, HID / 64), blk, 0, stream>>>(QKVb, P1, Vtg);
        ln_rope<true><<<dim3(S_LEN * 64 / 4), blk, 0, stream>>>(QKVb, P1, qn_w, qn_b, kn_w, kn_b, pos);
    } else {
        gemm256<<<dim3(384, 1, 1), dim3(512), 131072, stream>>>(
            Xb, Wt, QKVb, QKV_N, HID, HID, (size_t)0);
        v_transpose<false><<<dim3(S_LEN / 64, HID / 64), blk, 0, stream>>>(QKVb, QKVb, Vtg);
        ln_rope<false><<<dim3(S_LEN * 64 / 4), blk, 0, stream>>>(QKVb, QKVb, qn_w, qn_b, kn_w, kn_b, pos);
    }

    attn_fwd<<<dim3(S_LEN / 128, NH), dim3(512), 0, stream>>>(QKVb, Vtg, Ab);

    W3 wo3{Wo, Wo, Wo};
    cvt_w_t3<<<dim3(HID / 64, HID / 64, 1), blk, 0, stream>>>(wo3, Wt, HID, HID);

    gemm256<<<dim3(128, 1, 2), dim3(512), 131072, stream>>>(
        Ab, Wt, Pp, HID, HID / 2, HID, (size_t)S_LEN * HID);
    combine2<<<dim3(S_LEN * HID / 8 / 256), blk, 0, stream>>>(Pp, out);
}

// Round 12
// 530.521 us; speedup vs baseline: 6.4488x; 1.0036x over previous
//
#include <hip/hip_runtime.h>

#define S_LEN 2048
#define HID 4096
#define NH 32
#define HD 128
#define QKV_N 12288   // 3*HID

typedef __attribute__((ext_vector_type(8))) short bf16x8;
typedef __attribute__((ext_vector_type(4))) float f32x4;

__device__ __forceinline__ unsigned short f2bf(float f) {
    unsigned int u = __float_as_uint(f);
    u += 0x7FFF + ((u >> 16) & 1);
    return (unsigned short)(u >> 16);
}
__device__ __forceinline__ float bf2f(unsigned short h) {
    return __uint_as_float(((unsigned int)h) << 16);
}

typedef __attribute__((address_space(1))) const void gconst_void;
typedef __attribute__((address_space(3))) void lds_void;
__device__ __forceinline__ void gl16(const void* g, void* l) {
    __builtin_amdgcn_global_load_lds((gconst_void*)g, (lds_void*)l, 16, 0, 0);
}

#define VMCNT(n) asm volatile("s_waitcnt vmcnt(" #n ")" ::: "memory")
#define BAR()    do { asm volatile("" ::: "memory"); __builtin_amdgcn_s_barrier(); asm volatile("" ::: "memory"); } while (0)

// ---------------- fp32 -> bf16 linear convert ----------------
__global__ __launch_bounds__(256)
void cvt_f32_bf16(const float* __restrict__ in, unsigned short* __restrict__ out, int n8)
{
    int i = blockIdx.x * 256 + threadIdx.x;
    if (i >= n8) return;
    const float4* p = (const float4*)in + (size_t)i * 2;
    float4 a = p[0], b = p[1];
    bf16x8 o;
    o[0] = (short)f2bf(a.x); o[1] = (short)f2bf(a.y); o[2] = (short)f2bf(a.z); o[3] = (short)f2bf(a.w);
    o[4] = (short)f2bf(b.x); o[5] = (short)f2bf(b.y); o[6] = (short)f2bf(b.z); o[7] = (short)f2bf(b.w);
    *((bf16x8*)out + i) = o;
}

// ---------------- fp32 [K][N] -> bf16 [N][K] transpose-convert (up to 3 weights) ----------------
struct W3 { const float* w0; const float* w1; const float* w2; };

__global__ __launch_bounds__(256)
void cvt_w_t3(W3 ws3, unsigned short* __restrict__ Wt, int N, int K)
{
    __shared__ unsigned short t[64][72];
    const float* W = blockIdx.z == 0 ? ws3.w0 : (blockIdx.z == 1 ? ws3.w1 : ws3.w2);
    unsigned short* Wto = Wt + (size_t)blockIdx.z * N * K;
    const int tid = threadIdx.x;
    const int n0 = blockIdx.x * 64, k0 = blockIdx.y * 64;
    const int c4 = (tid & 15) * 4;
    const int r  = tid >> 4;
    #pragma unroll
    for (int p = 0; p < 4; ++p) {
        float4 v = *(const float4*)&W[(size_t)(k0 + r + p * 16) * N + n0 + c4];
        ushort4 o;
        o.x = f2bf(v.x); o.y = f2bf(v.y); o.z = f2bf(v.z); o.w = f2bf(v.w);
        *(ushort4*)&t[r + p * 16][c4] = o;
    }
    __syncthreads();
    const int n = tid >> 2;
    const int kq = (tid & 3) * 16;
    unsigned short* dst = &Wto[(size_t)(n0 + n) * K + k0 + kq];
    bf16x8 v0, v1;
    #pragma unroll
    for (int j = 0; j < 8; ++j) v0[j] = (short)t[kq + j][n];
    #pragma unroll
    for (int j = 0; j < 8; ++j) v1[j] = (short)t[kq + 8 + j][n];
    *(bf16x8*)dst = v0;
    *(bf16x8*)(dst + 8) = v1;
}

// ---------------- bf16 V slab [s][c] -> Vtg [c][s] transpose (+ optional split-K combine) ----------------
template<bool SPLIT>
__global__ __launch_bounds__(256)
void v_transpose(const unsigned short* __restrict__ P0, const unsigned short* __restrict__ P1,
                 unsigned short* __restrict__ Vtg)
{
    __shared__ unsigned short t[64][72];
    const int tid = threadIdx.x;
    const int s0 = blockIdx.x * 64;
    const int c0 = blockIdx.y * 64;
    #pragma unroll
    for (int i = 0; i < 2; ++i) {
        int idx = i * 256 + tid;
        int r = idx >> 3, c8 = (idx & 7) * 8;
        size_t off = (size_t)(s0 + r) * QKV_N + 2 * HID + c0 + c8;
        bf16x8 a = *(const bf16x8*)&P0[off];
        if (SPLIT) {
            bf16x8 b = *(const bf16x8*)&P1[off];
            #pragma unroll
            for (int j = 0; j < 8; ++j)
                a[j] = (short)f2bf(bf2f((unsigned short)a[j]) + bf2f((unsigned short)b[j]));
        }
        *(bf16x8*)&t[r][c8] = a;
    }
    __syncthreads();
    #pragma unroll
    for (int i = 0; i < 2; ++i) {
        int idx = i * 256 + tid;
        int oc = idx >> 3, os8 = (idx & 7) * 8;
        bf16x8 v;
        #pragma unroll
        for (int j = 0; j < 8; ++j) v[j] = (short)t[os8 + j][oc];
        *(bf16x8*)&Vtg[(size_t)(c0 + oc) * S_LEN + s0 + os8] = v;
    }
}

// ---------------- 256x256 GEMM, bf16 out, optional K-split via blockIdx.z ----------------
// 3-phase K-tile: quadrant order (r0,c0)->(r0,c1)->(r1,c1)+(r1,c0), both B quadrants live
__device__ __forceinline__ void lda4(bf16x8 af[4][2], const char* base, int rq, int l15, int lg) {
    const int sw = (l15 & 7) << 4;
    #pragma unroll
    for (int i = 0; i < 4; ++i) {
        const char* rb = base + ((rq * 4 + i) * 16 + l15) * 128;
        af[i][0] = *(const bf16x8*)(rb + ((lg * 16) ^ sw));
        af[i][1] = *(const bf16x8*)(rb + ((64 + lg * 16) ^ sw));
    }
}
__device__ __forceinline__ void ldb2(bf16x8 bf[2][2], const char* base, int cq, int l15, int lg) {
    const int sw = (l15 & 7) << 4;
    #pragma unroll
    for (int j = 0; j < 2; ++j) {
        const char* rb = base + ((cq * 2 + j) * 16 + l15) * 128;
        bf[j][0] = *(const bf16x8*)(rb + ((lg * 16) ^ sw));
        bf[j][1] = *(const bf16x8*)(rb + ((64 + lg * 16) ^ sw));
    }
}
__device__ __forceinline__ void mfma16(f32x4 acc[8][4], const bf16x8 af[4][2], const bf16x8 bf[2][2],
                                       int mi0, int nj0) {
    __builtin_amdgcn_s_setprio(1);
    #pragma unroll
    for (int kk = 0; kk < 2; ++kk)
        #pragma unroll
        for (int i = 0; i < 4; ++i)
            #pragma unroll
            for (int j = 0; j < 2; ++j)
                acc[mi0 + i][nj0 + j] =
                    __builtin_amdgcn_mfma_f32_16x16x32_bf16(af[i][kk], bf[j][kk], acc[mi0 + i][nj0 + j], 0, 0, 0);
    __builtin_amdgcn_s_setprio(0);
}
__device__ __forceinline__ void stage2(const unsigned short* g, char* dst, int ldk, int r32, int kn) {
    gl16(g + (size_t)r32 * ldk + kn, dst);
    gl16(g + (size_t)(r32 + 8) * ldk + kn, dst + 1024);
}

__global__ __launch_bounds__(512, 2)
void gemm256(const unsigned short* __restrict__ A,   // [M][ldk] bf16
             const unsigned short* __restrict__ Bt,  // [N][ldk] bf16
             unsigned short* __restrict__ Cp,        // bf16, + z*zstride
             int N, int K, int ldk, size_t zstride)
{
    extern __shared__ char lds[];
    const int tid = threadIdx.x;
    const int l   = tid & 63;
    const int l15 = l & 15, lg = l >> 4;
    const int wid = tid >> 6;
    const int wr  = wid >> 2;
    const int wc  = wid & 3;

    // column-slab XCD mapping (verified r6: FETCH 410->180MB)
    const int nwg = gridDim.x;
    const int bid = blockIdx.x;
    const int ntx = N >> 8;
    const int nty = nwg / ntx;
    const int cpx = ntx >> 3;
    const int xcd = bid & 7;
    const int idx = bid >> 3;
    const int bx = xcd * cpx + idx / nty;
    const int by = idx % nty;
    const int m0 = by * 256, n0 = bx * 256;
    const int koff = blockIdx.z * K;

    char* const Abase = lds + wr * 16384;
    char* const Bbase = lds + 32768 + (wc >> 1) * 16384 + (wc & 1) * 8192;

    const int l8 = l >> 3, l7 = l & 7;
    const int swslot = (l7 ^ l8) << 3;

    const unsigned short* Ag = A  + (size_t)(m0 + wr * 128 + wc * 16 + l8) * ldk + koff + swslot;
    const unsigned short* Bg = Bt + (size_t)(n0 + wc * 64 + wr * 16 + l8) * ldk + koff + swslot;
    char* const Adst = Abase + (wc * 16) * 128 + l * 16;
    char* const Bdst = Bbase + (wr * 16) * 128 + l * 16;

    f32x4 acc[8][4] = {};
    bf16x8 af[4][2], bfA[2][2], bfB[2][2];

    // prologue: A0B0(0) then A1B1(0); counted drain leaves A1B1 in flight (= loop invariant)
    stage2(Ag, Adst, ldk, 0, 0);
    stage2(Bg, Bdst, ldk, 0, 0);
    stage2(Ag, Adst + 64 * 128, ldk, 64, 0);
    stage2(Bg, Bdst + 32 * 128, ldk, 32, 0);
    VMCNT(4);
    BAR();

    // ledger: entering tile t, outstanding = A1B1(t) x4
    //   Ph1 issues A0B0(t+1); Ph1-end vmcnt(4) retires A1B1(t) [read Ph2/Ph3] (vmcnt(0) if last)
    //   Ph2 issues A1B1(t+1)
    //   Ph3-end vmcnt(4) retires A0B0(t+1) [read next Ph1] -> invariant holds
    const int NT = K >> 6;
    for (int t = 0; t < NT; ++t) {
        const int cb = (t & 1) * 65536, nb = cb ^ 65536;
        const int kn = (t + 1) << 6;
        const bool hn = (t + 1) < NT;
        // Ph1: quadrant (r0,c0)
        lda4(af, Abase + cb, 0, l15, lg);
        ldb2(bfA, Bbase + cb, 0, l15, lg);
        if (hn) { stage2(Ag, Adst + nb, ldk, 0, kn); stage2(Bg, Bdst + nb, ldk, 0, kn); }
        BAR();
        mfma16(acc, af, bfA, 0, 0);
        if (hn) { VMCNT(4); } else { VMCNT(0); }
        BAR();
        // Ph2: quadrant (r0,c1)
        ldb2(bfB, Bbase + cb, 1, l15, lg);
        if (hn) { stage2(Ag, Adst + nb + 64 * 128, ldk, 64, kn); stage2(Bg, Bdst + nb + 32 * 128, ldk, 32, kn); }
        BAR();
        mfma16(acc, af, bfB, 0, 2);
        BAR();
        // Ph3: quadrants (r1,c1) and (r1,c0) — both B quadrants still live in regs
        lda4(af, Abase + cb, 1, l15, lg);
        BAR();
        mfma16(acc, af, bfB, 4, 2);
        mfma16(acc, af, bfA, 4, 0);
        if (hn) { VMCNT(4); } else { VMCNT(0); }
        BAR();
    }

    unsigned short* C = Cp + (size_t)blockIdx.z * zstride;
    const int crow = m0 + wr * 128 + lg * 4;
    const int ccol = n0 + wc * 64 + l15;
    #pragma unroll
    for (int mi = 0; mi < 8; ++mi)
        #pragma unroll
        for (int nj = 0; nj < 4; ++nj)
            #pragma unroll
            for (int rr = 0; rr < 4; ++rr)
                C[(size_t)(crow + mi * 16 + rr) * N + ccol + nj * 16] = f2bf(acc[mi][nj][rr]);
}

// ---------------- combine 2 bf16 split-K partials -> fp32 out ----------------
__global__ __launch_bounds__(256)
void combine2(const unsigned short* __restrict__ P, float* __restrict__ out)
{
    const size_t i = ((size_t)blockIdx.x * 256 + threadIdx.x) * 8;
    const size_t stride = (size_t)S_LEN * HID;
    bf16x8 a = *(const bf16x8*)&P[i];
    bf16x8 b = *(const bf16x8*)&P[stride + i];
    #pragma unroll
    for (int j = 0; j < 8; ++j)
        out[i + j] = bf2f((unsigned short)a[j]) + bf2f((unsigned short)b[j]);
}

// ---------------- per-head LayerNorm + RoPE (+ optional split-K combine), writes into P0 ----------------
template<bool SPLIT>
__global__ __launch_bounds__(256)
void ln_rope(unsigned short* __restrict__ P0, const unsigned short* __restrict__ P1,
             const float* __restrict__ qg, const float* __restrict__ qb,
             const float* __restrict__ kg, const float* __restrict__ kb,
             const int* __restrict__ pos)
{
    const int tid = threadIdx.x;
    const int l = tid & 63;
    const int w = tid >> 6;
    const int rid = blockIdx.x * 4 + w;
    const int s = rid >> 6;
    const int hh = rid & 63;
    const int which = hh >> 5;
    const int h = hh & 31;
    const size_t off = (size_t)s * QKV_N + which * HID + h * HD;
    unsigned short* p = P0 + off;
    const float* gamma = which ? kg : qg;
    const float* beta  = which ? kb : qb;

    float lo = bf2f(p[l]);
    float hi = bf2f(p[l + 64]);
    if (SPLIT) {
        const unsigned short* q = P1 + off;
        lo += bf2f(q[l]);
        hi += bf2f(q[l + 64]);
    }
    float sum = lo + hi;
    #pragma unroll
    for (int off2 = 32; off2 >= 1; off2 >>= 1) sum += __shfl_xor(sum, off2, 64);
    float mu = sum * (1.0f / 128.0f);
    float dlo = lo - mu, dhi = hi - mu;
    float vs = dlo * dlo + dhi * dhi;
    #pragma unroll
    for (int off2 = 32; off2 >= 1; off2 >>= 1) vs += __shfl_xor(vs, off2, 64);
    float rstd = rsqrtf(vs * (1.0f / 128.0f) + 1e-5f);
    float xlo = dlo * rstd * gamma[l] + beta[l];
    float xhi = dhi * rstd * gamma[l + 64] + beta[l + 64];

    float fpos = (float)pos[s];
    float invf = exp2f(-13.287712379549449f * (float)l * (1.0f / 64.0f));
    float ang = fpos * invf;
    float sn, cs;
    sincosf(ang, &sn, &cs);
    p[l]      = f2bf(xlo * cs - xhi * sn);
    p[l + 64] = f2bf(xhi * cs + xlo * sn);
}

// ---------------- causal flash attention: 8 waves x 16 rows (QBLK=128), KVB=64 dbuf pipeline ----------------
#define KVB 64

__global__ __launch_bounds__(512)
void attn_fwd(const unsigned short* __restrict__ QKV,   // [S][12288]
              const unsigned short* __restrict__ Vtg,   // [4096][S]
              unsigned short* __restrict__ O)           // [S][4096]
{
    __shared__ unsigned short Ks[2][KVB * HD];
    __shared__ unsigned short Vs[2][HD * KVB];
    __shared__ unsigned short Ps[8][16 * 72];

    const int tid = threadIdx.x;
    const int l = tid & 63;
    const int w = tid >> 6;
    const int l15 = l & 15, lg = l >> 4;
    const int h = blockIdx.y;
    const int qb = gridDim.x - 1 - blockIdx.x;
    const int q0 = qb * 128;
    const int qw = q0 + w * 16;

    const unsigned short* Qp = QKV + h * HD;
    const unsigned short* Kp = QKV + HID + h * HD;
    const unsigned short* Vp = Vtg + (size_t)h * HD * S_LEN;

    bf16x8 qf[4];
    #pragma unroll
    for (int d = 0; d < 4; ++d)
        qf[d] = *(const bf16x8*)&Qp[(size_t)(qw + l15) * QKV_N + d * 32 + lg * 8];

    f32x4 o_acc[8] = {};
    float mrow[4], lsum[4];
    #pragma unroll
    for (int r = 0; r < 4; ++r) { mrow[r] = -1e30f; lsum[r] = 0.0f; }

    const float scale = 0.08838834764831845f;

    const int ksl = tid & 15;
    const int kr7 = (tid >> 4) & 7;
    const int ksg = (ksl & 8) | ((ksl ^ kr7) & 7);
    const unsigned short* Kg = Kp + (size_t)(tid >> 4) * QKV_N + ksg * 8;
    const int vsg = (tid & 7) ^ ((tid >> 3) & 7);
    const unsigned short* Vg = Vp + (size_t)(tid >> 3) * S_LEN + vsg * 8;

#define STAGE(buf, kv0s) do {                                                          \
    _Pragma("unroll")                                                                  \
    for (int i_ = 0; i_ < 2; ++i_)                                                     \
        gl16(Kg + (size_t)((kv0s) + i_ * 32) * QKV_N,                                  \
             (char*)Ks[buf] + (i_ * 512 + tid) * 16);                                  \
    _Pragma("unroll")                                                                  \
    for (int i_ = 0; i_ < 2; ++i_)                                                     \
        gl16(Vg + (size_t)i_ * 64 * S_LEN + (kv0s),                                    \
             (char*)Vs[buf] + (i_ * 512 + tid) * 16);                                  \
} while (0)

    STAGE(0, 0);
    VMCNT(2);
    __syncthreads();

    const int nt = 2 * qb + 2;
    for (int t = 0; t < nt; ++t) {
        const int kv0 = t * KVB;
        const int cur = t & 1;
        const bool hn = (t + 1) < nt;
        if (hn) STAGE(cur ^ 1, kv0 + KVB);

        f32x4 sc[4] = {};
        #pragma unroll
        for (int kvf = 0; kvf < 4; ++kvf) {
            int r = kvf * 16 + l15;
            int sw = (r & 7) << 4;
            #pragma unroll
            for (int d = 0; d < 4; ++d) {
                bf16x8 kf = *(const bf16x8*)((const char*)Ks[cur] + r * 256 + ((d * 64 + lg * 16) ^ sw));
                sc[kvf] = __builtin_amdgcn_mfma_f32_16x16x32_bf16(qf[d], kf, sc[kvf], 0, 0, 0);
            }
        }

        const bool full = (kv0 + KVB <= qw);
        #pragma unroll
        for (int r = 0; r < 4; ++r) {
            int qg = qw + lg * 4 + r;
            float s0, s1, s2, s3;
            if (full) {
                s0 = sc[0][r] * scale; s1 = sc[1][r] * scale;
                s2 = sc[2][r] * scale; s3 = sc[3][r] * scale;
            } else {
                s0 = (kv0 + l15      <= qg) ? sc[0][r] * scale : -1e30f;
                s1 = (kv0 + 16 + l15 <= qg) ? sc[1][r] * scale : -1e30f;
                s2 = (kv0 + 32 + l15 <= qg) ? sc[2][r] * scale : -1e30f;
                s3 = (kv0 + 48 + l15 <= qg) ? sc[3][r] * scale : -1e30f;
            }
            float mx = fmaxf(fmaxf(s0, s1), fmaxf(s2, s3));
            #pragma unroll
            for (int off = 8; off >= 1; off >>= 1) mx = fmaxf(mx, __shfl_xor(mx, off, 64));
            float mn = mrow[r];
            if (!__all(mx <= mn + 8.0f)) {
                mn = fmaxf(mn, mx);
                float corr = __expf(mrow[r] - mn);
                lsum[r] *= corr;
                #pragma unroll
                for (int df = 0; df < 8; ++df) o_acc[df][r] *= corr;
                mrow[r] = mn;
            }
            float p0 = __expf(s0 - mn);
            float p1 = __expf(s1 - mn);
            float p2 = __expf(s2 - mn);
            float p3 = __expf(s3 - mn);
            lsum[r] += (p0 + p1) + (p2 + p3);
            int ql = lg * 4 + r;
            Ps[w][ql * 72 + l15]      = f2bf(p0);
            Ps[w][ql * 72 + 16 + l15] = f2bf(p1);
            Ps[w][ql * 72 + 32 + l15] = f2bf(p2);
            Ps[w][ql * 72 + 48 + l15] = f2bf(p3);
        }

        if (hn) { VMCNT(4); } else { VMCNT(0); }
        BAR();

        bf16x8 pa0 = *(const bf16x8*)&Ps[w][l15 * 72 + lg * 8];
        bf16x8 pa1 = *(const bf16x8*)&Ps[w][l15 * 72 + 32 + lg * 8];
        #pragma unroll
        for (int df = 0; df < 8; ++df) {
            int d = df * 16 + l15;
            int sw = (d & 7) << 4;
            const char* vrow = (const char*)Vs[cur] + d * 128;
            bf16x8 v0 = *(const bf16x8*)(vrow + ((lg * 16) ^ sw));
            bf16x8 v1 = *(const bf16x8*)(vrow + ((64 + lg * 16) ^ sw));
            o_acc[df] = __builtin_amdgcn_mfma_f32_16x16x32_bf16(pa0, v0, o_acc[df], 0, 0, 0);
            o_acc[df] = __builtin_amdgcn_mfma_f32_16x16x32_bf16(pa1, v1, o_acc[df], 0, 0, 0);
        }

        VMCNT(2);
        BAR();
    }
#undef STAGE

    float inv[4];
    #pragma unroll
    for (int r = 0; r < 4; ++r) {
        float s = lsum[r];
        #pragma unroll
        for (int off = 8; off >= 1; off >>= 1) s += __shfl_xor(s, off, 64);
        inv[r] = 1.0f / s;
    }
    #pragma unroll
    for (int df = 0; df < 8; ++df) {
        #pragma unroll
        for (int r = 0; r < 4; ++r) {
            int q = qw + lg * 4 + r;
            int d = h * HD + df * 16 + l15;
            O[(size_t)q * HID + d] = f2bf(o_acc[df][r] * inv[r]);
        }
    }
}

extern "C" void kernel_launch(void* const* d_in, const int* in_sizes, int n_in,
                              void* d_out, int out_size, void* d_ws, size_t ws_size,
                              hipStream_t stream)
{
    (void)in_sizes; (void)n_in; (void)out_size;
    const float* X    = (const float*)d_in[0];
    const int*   pos  = (const int*)d_in[1];
    const float* Wq   = (const float*)d_in[2];
    const float* Wk   = (const float*)d_in[3];
    const float* Wv   = (const float*)d_in[4];
    const float* Wo   = (const float*)d_in[5];
    const float* qn_w = (const float*)d_in[6];
    const float* qn_b = (const float*)d_in[7];
    const float* kn_w = (const float*)d_in[8];
    const float* kn_b = (const float*)d_in[9];
    float* out = (float*)d_out;

    unsigned short* Xb    = (unsigned short*)d_ws;
    unsigned short* QKVb  = (unsigned short*)((char*)d_ws + 16777216);
    unsigned short* Wt    = (unsigned short*)((char*)d_ws + 67108864);
    unsigned short* Pp    = (unsigned short*)((char*)d_ws + 100663296);
    unsigned short* Vtg   = (unsigned short*)((char*)d_ws + 134217728);
    unsigned short* P1    = (unsigned short*)((char*)d_ws + 167772160);
    unsigned short* Ab    = Xb;

    const bool splitQKV = ws_size >= (size_t)218103808;

    (void)hipFuncSetAttribute((const void*)gemm256, hipFuncAttributeMaxDynamicSharedMemorySize, 131072);

    dim3 blk(256);

    cvt_f32_bf16<<<dim3((S_LEN * HID / 8 + 255) / 256), blk, 0, stream>>>(X, Xb, S_LEN * HID / 8);

    W3 w3{Wq, Wk, Wv};
    cvt_w_t3<<<dim3(HID / 64, HID / 64, 3), blk, 0, stream>>>(w3, Wt, HID, HID);

    if (splitQKV) {
        gemm256<<<dim3(384, 1, 2), dim3(512), 131072, stream>>>(
            Xb, Wt, QKVb, QKV_N, HID / 2, HID, (size_t)75497472);
        v_transpose<true><<<dim3(S_LEN / 64, HID / 64), blk, 0, stream>>>(QKVb, P1, Vtg);
        ln_rope<true><<<dim3(S_LEN * 64 / 4), blk, 0, stream>>>(QKVb, P1, qn_w, qn_b, kn_w, kn_b, pos);
    } else {
        gemm256<<<dim3(384, 1, 1), dim3(512), 131072, stream>>>(
            Xb, Wt, QKVb, QKV_N, HID, HID, (size_t)0);
        v_transpose<false><<<dim3(S_LEN / 64, HID / 64), blk, 0, stream>>>(QKVb, QKVb, Vtg);
        ln_rope<false><<<dim3(S_LEN * 64 / 4), blk, 0, stream>>>(QKVb, QKVb, qn_w, qn_b, kn_w, kn_b, pos);
    }

    attn_fwd<<<dim3(S_LEN / 128, NH), dim3(512), 0, stream>>>(QKVb, Vtg, Ab);

    W3 wo3{Wo, Wo, Wo};
    cvt_w_t3<<<dim3(HID / 64, HID / 64, 1), blk, 0, stream>>>(wo3, Wt, HID, HID);

    gemm256<<<dim3(128, 1, 2), dim3(512), 131072, stream>>>(
        Ab, Wt, Pp, HID, HID / 2, HID, (size_t)S_LEN * HID);
    combine2<<<dim3(S_LEN * HID / 8 / 256), blk, 0, stream>>>(Pp, out);
}

// Round 13
// 516.504 us; speedup vs baseline: 6.6238x; 1.0271x over previous
//
#include <hip/hip_runtime.h>

#define S_LEN 2048
#define HID 4096
#define NH 32
#define HD 128
#define QKV_N 12288   // 3*HID

typedef __attribute__((ext_vector_type(8))) short bf16x8;
typedef __attribute__((ext_vector_type(4))) float f32x4;

__device__ __forceinline__ unsigned short f2bf(float f) {
    unsigned int u = __float_as_uint(f);
    u += 0x7FFF + ((u >> 16) & 1);
    return (unsigned short)(u >> 16);
}
__device__ __forceinline__ float bf2f(unsigned short h) {
    return __uint_as_float(((unsigned int)h) << 16);
}

typedef __attribute__((address_space(1))) const void gconst_void;
typedef __attribute__((address_space(3))) void lds_void;
__device__ __forceinline__ void gl16(const void* g, void* l) {
    __builtin_amdgcn_global_load_lds((gconst_void*)g, (lds_void*)l, 16, 0, 0);
}

#define VMCNT(n) asm volatile("s_waitcnt vmcnt(" #n ")" ::: "memory")
#define BAR()    do { asm volatile("" ::: "memory"); __builtin_amdgcn_s_barrier(); asm volatile("" ::: "memory"); } while (0)

// ---------------- fp32 -> bf16 linear convert ----------------
__global__ __launch_bounds__(256)
void cvt_f32_bf16(const float* __restrict__ in, unsigned short* __restrict__ out, int n8)
{
    int i = blockIdx.x * 256 + threadIdx.x;
    if (i >= n8) return;
    const float4* p = (const float4*)in + (size_t)i * 2;
    float4 a = p[0], b = p[1];
    bf16x8 o;
    o[0] = (short)f2bf(a.x); o[1] = (short)f2bf(a.y); o[2] = (short)f2bf(a.z); o[3] = (short)f2bf(a.w);
    o[4] = (short)f2bf(b.x); o[5] = (short)f2bf(b.y); o[6] = (short)f2bf(b.z); o[7] = (short)f2bf(b.w);
    *((bf16x8*)out + i) = o;
}

// ---------------- fp32 [K][N] -> bf16 [N][K] transpose-convert (up to 3 weights) ----------------
struct W3 { const float* w0; const float* w1; const float* w2; };

__global__ __launch_bounds__(256)
void cvt_w_t3(W3 ws3, unsigned short* __restrict__ Wt, int N, int K)
{
    __shared__ unsigned short t[64][72];
    const float* W = blockIdx.z == 0 ? ws3.w0 : (blockIdx.z == 1 ? ws3.w1 : ws3.w2);
    unsigned short* Wto = Wt + (size_t)blockIdx.z * N * K;
    const int tid = threadIdx.x;
    const int n0 = blockIdx.x * 64, k0 = blockIdx.y * 64;
    const int c4 = (tid & 15) * 4;
    const int r  = tid >> 4;
    #pragma unroll
    for (int p = 0; p < 4; ++p) {
        float4 v = *(const float4*)&W[(size_t)(k0 + r + p * 16) * N + n0 + c4];
        ushort4 o;
        o.x = f2bf(v.x); o.y = f2bf(v.y); o.z = f2bf(v.z); o.w = f2bf(v.w);
        *(ushort4*)&t[r + p * 16][c4] = o;
    }
    __syncthreads();
    const int n = tid >> 2;
    const int kq = (tid & 3) * 16;
    unsigned short* dst = &Wto[(size_t)(n0 + n) * K + k0 + kq];
    bf16x8 v0, v1;
    #pragma unroll
    for (int j = 0; j < 8; ++j) v0[j] = (short)t[kq + j][n];
    #pragma unroll
    for (int j = 0; j < 8; ++j) v1[j] = (short)t[kq + 8 + j][n];
    *(bf16x8*)dst = v0;
    *(bf16x8*)(dst + 8) = v1;
}

// ---------------- bf16 V slab [s][c] -> Vtg [c][s] transpose (+ optional split-K combine) ----------------
template<bool SPLIT>
__global__ __launch_bounds__(256)
void v_transpose(const unsigned short* __restrict__ P0, const unsigned short* __restrict__ P1,
                 unsigned short* __restrict__ Vtg)
{
    __shared__ unsigned short t[64][72];
    const int tid = threadIdx.x;
    const int s0 = blockIdx.x * 64;
    const int c0 = blockIdx.y * 64;
    #pragma unroll
    for (int i = 0; i < 2; ++i) {
        int idx = i * 256 + tid;
        int r = idx >> 3, c8 = (idx & 7) * 8;
        size_t off = (size_t)(s0 + r) * QKV_N + 2 * HID + c0 + c8;
        bf16x8 a = *(const bf16x8*)&P0[off];
        if (SPLIT) {
            bf16x8 b = *(const bf16x8*)&P1[off];
            #pragma unroll
            for (int j = 0; j < 8; ++j)
                a[j] = (short)f2bf(bf2f((unsigned short)a[j]) + bf2f((unsigned short)b[j]));
        }
        *(bf16x8*)&t[r][c8] = a;
    }
    __syncthreads();
    #pragma unroll
    for (int i = 0; i < 2; ++i) {
        int idx = i * 256 + tid;
        int oc = idx >> 3, os8 = (idx & 7) * 8;
        bf16x8 v;
        #pragma unroll
        for (int j = 0; j < 8; ++j) v[j] = (short)t[os8 + j][oc];
        *(bf16x8*)&Vtg[(size_t)(c0 + oc) * S_LEN + s0 + os8] = v;
    }
}

// ---------------- 256x256 GEMM, bf16 out, optional K-split via blockIdx.z ----------------
// single-barrier K-tile: waves free-run through {reads, stage, MFMA}; one vmcnt(0)+barrier per tile
__device__ __forceinline__ void lda4(bf16x8 af[4][2], const char* base, int rq, int l15, int lg) {
    const int sw = (l15 & 7) << 4;
    #pragma unroll
    for (int i = 0; i < 4; ++i) {
        const char* rb = base + ((rq * 4 + i) * 16 + l15) * 128;
        af[i][0] = *(const bf16x8*)(rb + ((lg * 16) ^ sw));
        af[i][1] = *(const bf16x8*)(rb + ((64 + lg * 16) ^ sw));
    }
}
__device__ __forceinline__ void ldb2(bf16x8 bf[2][2], const char* base, int cq, int l15, int lg) {
    const int sw = (l15 & 7) << 4;
    #pragma unroll
    for (int j = 0; j < 2; ++j) {
        const char* rb = base + ((cq * 2 + j) * 16 + l15) * 128;
        bf[j][0] = *(const bf16x8*)(rb + ((lg * 16) ^ sw));
        bf[j][1] = *(const bf16x8*)(rb + ((64 + lg * 16) ^ sw));
    }
}
__device__ __forceinline__ void mfma16(f32x4 acc[8][4], const bf16x8 af[4][2], const bf16x8 bf[2][2],
                                       int mi0, int nj0) {
    __builtin_amdgcn_s_setprio(1);
    #pragma unroll
    for (int kk = 0; kk < 2; ++kk)
        #pragma unroll
        for (int i = 0; i < 4; ++i)
            #pragma unroll
            for (int j = 0; j < 2; ++j)
                acc[mi0 + i][nj0 + j] =
                    __builtin_amdgcn_mfma_f32_16x16x32_bf16(af[i][kk], bf[j][kk], acc[mi0 + i][nj0 + j], 0, 0, 0);
    __builtin_amdgcn_s_setprio(0);
}
__device__ __forceinline__ void stage2(const unsigned short* g, char* dst, int ldk, int r32, int kn) {
    gl16(g + (size_t)r32 * ldk + kn, dst);
    gl16(g + (size_t)(r32 + 8) * ldk + kn, dst + 1024);
}

__global__ __launch_bounds__(512, 2)
void gemm256(const unsigned short* __restrict__ A,   // [M][ldk] bf16
             const unsigned short* __restrict__ Bt,  // [N][ldk] bf16
             unsigned short* __restrict__ Cp,        // bf16, + z*zstride
             int N, int K, int ldk, size_t zstride)
{
    extern __shared__ char lds[];
    const int tid = threadIdx.x;
    const int l   = tid & 63;
    const int l15 = l & 15, lg = l >> 4;
    const int wid = tid >> 6;
    const int wr  = wid >> 2;
    const int wc  = wid & 3;

    // column-slab XCD mapping (verified r6: FETCH 410->180MB)
    const int nwg = gridDim.x;
    const int bid = blockIdx.x;
    const int ntx = N >> 8;
    const int nty = nwg / ntx;
    const int cpx = ntx >> 3;
    const int xcd = bid & 7;
    const int idx = bid >> 3;
    const int bx = xcd * cpx + idx / nty;
    const int by = idx % nty;
    const int m0 = by * 256, n0 = bx * 256;
    const int koff = blockIdx.z * K;

    char* const Abase = lds + wr * 16384;
    char* const Bbase = lds + 32768 + (wc >> 1) * 16384 + (wc & 1) * 8192;

    const int l8 = l >> 3, l7 = l & 7;
    const int swslot = (l7 ^ l8) << 3;

    const unsigned short* Ag = A  + (size_t)(m0 + wr * 128 + wc * 16 + l8) * ldk + koff + swslot;
    const unsigned short* Bg = Bt + (size_t)(n0 + wc * 64 + wr * 16 + l8) * ldk + koff + swslot;
    char* const Adst = Abase + (wc * 16) * 128 + l * 16;
    char* const Bdst = Bbase + (wr * 16) * 128 + l * 16;

    f32x4 acc[8][4] = {};
    bf16x8 af[4][2], bfA[2][2], bfB[2][2];

    // prologue: tile 0 fully staged, drain, barrier
    stage2(Ag, Adst, ldk, 0, 0);
    stage2(Bg, Bdst, ldk, 0, 0);
    stage2(Ag, Adst + 64 * 128, ldk, 64, 0);
    stage2(Bg, Bdst + 32 * 128, ldk, 32, 0);
    VMCNT(0);
    BAR();

    // Safety argument (1 barrier/K-tile):
    //  - cb is fully staged before tile t's entry barrier (each wave VMCNT(0)'s its OWN
    //    stages, then barrier => all waves' stages visible to all).
    //  - during tile t, stages target only nb; nb's last readers (tile t-1) consumed
    //    their ds_read data (lgkm-waited by their MFMAs) before reaching the t-1 barrier.
    //  - waves free-run within the tile: wave B's ds_reads overlap wave A's MFMAs.
    const int NT = K >> 6;
    for (int t = 0; t < NT; ++t) {
        const int cb = (t & 1) * 65536, nb = cb ^ 65536;
        const int kn = (t + 1) << 6;
        const bool hn = (t + 1) < NT;

        lda4(af, Abase + cb, 0, l15, lg);
        ldb2(bfA, Bbase + cb, 0, l15, lg);
        if (hn) { stage2(Ag, Adst + nb, ldk, 0, kn); stage2(Bg, Bdst + nb, ldk, 0, kn); }
        mfma16(acc, af, bfA, 0, 0);

        ldb2(bfB, Bbase + cb, 1, l15, lg);
        if (hn) { stage2(Ag, Adst + nb + 64 * 128, ldk, 64, kn); stage2(Bg, Bdst + nb + 32 * 128, ldk, 32, kn); }
        mfma16(acc, af, bfB, 0, 2);

        lda4(af, Abase + cb, 1, l15, lg);
        mfma16(acc, af, bfB, 4, 2);
        mfma16(acc, af, bfA, 4, 0);

        VMCNT(0);   // t+1 stages issued >=2 phases ago -> usually already landed
        BAR();      // all waves done reading cb; all stages visible
    }

    unsigned short* C = Cp + (size_t)blockIdx.z * zstride;
    const int crow = m0 + wr * 128 + lg * 4;
    const int ccol = n0 + wc * 64 + l15;
    #pragma unroll
    for (int mi = 0; mi < 8; ++mi)
        #pragma unroll
        for (int nj = 0; nj < 4; ++nj)
            #pragma unroll
            for (int rr = 0; rr < 4; ++rr)
                C[(size_t)(crow + mi * 16 + rr) * N + ccol + nj * 16] = f2bf(acc[mi][nj][rr]);
}

// ---------------- combine 2 bf16 split-K partials -> fp32 out ----------------
__global__ __launch_bounds__(256)
void combine2(const unsigned short* __restrict__ P, float* __restrict__ out)
{
    const size_t i = ((size_t)blockIdx.x * 256 + threadIdx.x) * 8;
    const size_t stride = (size_t)S_LEN * HID;
    bf16x8 a = *(const bf16x8*)&P[i];
    bf16x8 b = *(const bf16x8*)&P[stride + i];
    #pragma unroll
    for (int j = 0; j < 8; ++j)
        out[i + j] = bf2f((unsigned short)a[j]) + bf2f((unsigned short)b[j]);
}

// ---------------- per-head LayerNorm + RoPE (+ optional split-K combine), writes into P0 ----------------
template<bool SPLIT>
__global__ __launch_bounds__(256)
void ln_rope(unsigned short* __restrict__ P0, const unsigned short* __restrict__ P1,
             const float* __restrict__ qg, const float* __restrict__ qb,
             const float* __restrict__ kg, const float* __restrict__ kb,
             const int* __restrict__ pos)
{
    const int tid = threadIdx.x;
    const int l = tid & 63;
    const int w = tid >> 6;
    const int rid = blockIdx.x * 4 + w;
    const int s = rid >> 6;
    const int hh = rid & 63;
    const int which = hh >> 5;
    const int h = hh & 31;
    const size_t off = (size_t)s * QKV_N + which * HID + h * HD;
    unsigned short* p = P0 + off;
    const float* gamma = which ? kg : qg;
    const float* beta  = which ? kb : qb;

    float lo = bf2f(p[l]);
    float hi = bf2f(p[l + 64]);
    if (SPLIT) {
        const unsigned short* q = P1 + off;
        lo += bf2f(q[l]);
        hi += bf2f(q[l + 64]);
    }
    float sum = lo + hi;
    #pragma unroll
    for (int off2 = 32; off2 >= 1; off2 >>= 1) sum += __shfl_xor(sum, off2, 64);
    float mu = sum * (1.0f / 128.0f);
    float dlo = lo - mu, dhi = hi - mu;
    float vs = dlo * dlo + dhi * dhi;
    #pragma unroll
    for (int off2 = 32; off2 >= 1; off2 >>= 1) vs += __shfl_xor(vs, off2, 64);
    float rstd = rsqrtf(vs * (1.0f / 128.0f) + 1e-5f);
    float xlo = dlo * rstd * gamma[l] + beta[l];
    float xhi = dhi * rstd * gamma[l + 64] + beta[l + 64];

    float fpos = (float)pos[s];
    float invf = exp2f(-13.287712379549449f * (float)l * (1.0f / 64.0f));
    float ang = fpos * invf;
    float sn, cs;
    sincosf(ang, &sn, &cs);
    p[l]      = f2bf(xlo * cs - xhi * sn);
    p[l + 64] = f2bf(xhi * cs + xlo * sn);
}

// ---------------- causal flash attention: 8 waves x 16 rows (QBLK=128), KVB=64 dbuf pipeline ----------------
#define KVB 64

__global__ __launch_bounds__(512)
void attn_fwd(const unsigned short* __restrict__ QKV,   // [S][12288]
              const unsigned short* __restrict__ Vtg,   // [4096][S]
              unsigned short* __restrict__ O)           // [S][4096]
{
    __shared__ unsigned short Ks[2][KVB * HD];
    __shared__ unsigned short Vs[2][HD * KVB];
    __shared__ unsigned short Ps[8][16 * 72];

    const int tid = threadIdx.x;
    const int l = tid & 63;
    const int w = tid >> 6;
    const int l15 = l & 15, lg = l >> 4;
    const int h = blockIdx.y;
    const int qb = gridDim.x - 1 - blockIdx.x;
    const int q0 = qb * 128;
    const int qw = q0 + w * 16;

    const unsigned short* Qp = QKV + h * HD;
    const unsigned short* Kp = QKV + HID + h * HD;
    const unsigned short* Vp = Vtg + (size_t)h * HD * S_LEN;

    bf16x8 qf[4];
    #pragma unroll
    for (int d = 0; d < 4; ++d)
        qf[d] = *(const bf16x8*)&Qp[(size_t)(qw + l15) * QKV_N + d * 32 + lg * 8];

    f32x4 o_acc[8] = {};
    float mrow[4], lsum[4];
    #pragma unroll
    for (int r = 0; r < 4; ++r) { mrow[r] = -1e30f; lsum[r] = 0.0f; }

    const float scale = 0.08838834764831845f;

    const int ksl = tid & 15;
    const int kr7 = (tid >> 4) & 7;
    const int ksg = (ksl & 8) | ((ksl ^ kr7) & 7);
    const unsigned short* Kg = Kp + (size_t)(tid >> 4) * QKV_N + ksg * 8;
    const int vsg = (tid & 7) ^ ((tid >> 3) & 7);
    const unsigned short* Vg = Vp + (size_t)(tid >> 3) * S_LEN + vsg * 8;

#define STAGE(buf, kv0s) do {                                                          \
    _Pragma("unroll")                                                                  \
    for (int i_ = 0; i_ < 2; ++i_)                                                     \
        gl16(Kg + (size_t)((kv0s) + i_ * 32) * QKV_N,                                  \
             (char*)Ks[buf] + (i_ * 512 + tid) * 16);                                  \
    _Pragma("unroll")                                                                  \
    for (int i_ = 0; i_ < 2; ++i_)                                                     \
        gl16(Vg + (size_t)i_ * 64 * S_LEN + (kv0s),                                    \
             (char*)Vs[buf] + (i_ * 512 + tid) * 16);                                  \
} while (0)

    STAGE(0, 0);
    VMCNT(2);
    __syncthreads();

    const int nt = 2 * qb + 2;
    for (int t = 0; t < nt; ++t) {
        const int kv0 = t * KVB;
        const int cur = t & 1;
        const bool hn = (t + 1) < nt;
        if (hn) STAGE(cur ^ 1, kv0 + KVB);

        f32x4 sc[4] = {};
        #pragma unroll
        for (int kvf = 0; kvf < 4; ++kvf) {
            int r = kvf * 16 + l15;
            int sw = (r & 7) << 4;
            #pragma unroll
            for (int d = 0; d < 4; ++d) {
                bf16x8 kf = *(const bf16x8*)((const char*)Ks[cur] + r * 256 + ((d * 64 + lg * 16) ^ sw));
                sc[kvf] = __builtin_amdgcn_mfma_f32_16x16x32_bf16(qf[d], kf, sc[kvf], 0, 0, 0);
            }
        }

        const bool full = (kv0 + KVB <= qw);
        #pragma unroll
        for (int r = 0; r < 4; ++r) {
            int qg = qw + lg * 4 + r;
            float s0, s1, s2, s3;
            if (full) {
                s0 = sc[0][r] * scale; s1 = sc[1][r] * scale;
                s2 = sc[2][r] * scale; s3 = sc[3][r] * scale;
            } else {
                s0 = (kv0 + l15      <= qg) ? sc[0][r] * scale : -1e30f;
                s1 = (kv0 + 16 + l15 <= qg) ? sc[1][r] * scale : -1e30f;
                s2 = (kv0 + 32 + l15 <= qg) ? sc[2][r] * scale : -1e30f;
                s3 = (kv0 + 48 + l15 <= qg) ? sc[3][r] * scale : -1e30f;
            }
            float mx = fmaxf(fmaxf(s0, s1), fmaxf(s2, s3));
            #pragma unroll
            for (int off = 8; off >= 1; off >>= 1) mx = fmaxf(mx, __shfl_xor(mx, off, 64));
            float mn = mrow[r];
            if (!__all(mx <= mn + 8.0f)) {
                mn = fmaxf(mn, mx);
                float corr = __expf(mrow[r] - mn);
                lsum[r] *= corr;
                #pragma unroll
                for (int df = 0; df < 8; ++df) o_acc[df][r] *= corr;
                mrow[r] = mn;
            }
            float p0 = __expf(s0 - mn);
            float p1 = __expf(s1 - mn);
            float p2 = __expf(s2 - mn);
            float p3 = __expf(s3 - mn);
            lsum[r] += (p0 + p1) + (p2 + p3);
            int ql = lg * 4 + r;
            Ps[w][ql * 72 + l15]      = f2bf(p0);
            Ps[w][ql * 72 + 16 + l15] = f2bf(p1);
            Ps[w][ql * 72 + 32 + l15] = f2bf(p2);
            Ps[w][ql * 72 + 48 + l15] = f2bf(p3);
        }

        if (hn) { VMCNT(4); } else { VMCNT(0); }
        BAR();

        bf16x8 pa0 = *(const bf16x8*)&Ps[w][l15 * 72 + lg * 8];
        bf16x8 pa1 = *(const bf16x8*)&Ps[w][l15 * 72 + 32 + lg * 8];
        #pragma unroll
        for (int df = 0; df < 8; ++df) {
            int d = df * 16 + l15;
            int sw = (d & 7) << 4;
            const char* vrow = (const char*)Vs[cur] + d * 128;
            bf16x8 v0 = *(const bf16x8*)(vrow + ((lg * 16) ^ sw));
            bf16x8 v1 = *(const bf16x8*)(vrow + ((64 + lg * 16) ^ sw));
            o_acc[df] = __builtin_amdgcn_mfma_f32_16x16x32_bf16(pa0, v0, o_acc[df], 0, 0, 0);
            o_acc[df] = __builtin_amdgcn_mfma_f32_16x16x32_bf16(pa1, v1, o_acc[df], 0, 0, 0);
        }

        VMCNT(2);
        BAR();
    }
#undef STAGE

    float inv[4];
    #pragma unroll
    for (int r = 0; r < 4; ++r) {
        float s = lsum[r];
        #pragma unroll
        for (int off = 8; off >= 1; off >>= 1) s += __shfl_xor(s, off, 64);
        inv[r] = 1.0f / s;
    }
    #pragma unroll
    for (int df = 0; df < 8; ++df) {
        #pragma unroll
        for (int r = 0; r < 4; ++r) {
            int q = qw + lg * 4 + r;
            int d = h * HD + df * 16 + l15;
            O[(size_t)q * HID + d] = f2bf(o_acc[df][r] * inv[r]);
        }
    }
}

extern "C" void kernel_launch(void* const* d_in, const int* in_sizes, int n_in,
                              void* d_out, int out_size, void* d_ws, size_t ws_size,
                              hipStream_t stream)
{
    (void)in_sizes; (void)n_in; (void)out_size;
    const float* X    = (const float*)d_in[0];
    const int*   pos  = (const int*)d_in[1];
    const float* Wq   = (const float*)d_in[2];
    const float* Wk   = (const float*)d_in[3];
    const float* Wv   = (const float*)d_in[4];
    const float* Wo   = (const float*)d_in[5];
    const float* qn_w = (const float*)d_in[6];
    const float* qn_b = (const float*)d_in[7];
    const float* kn_w = (const float*)d_in[8];
    const float* kn_b = (const float*)d_in[9];
    float* out = (float*)d_out;

    unsigned short* Xb    = (unsigned short*)d_ws;
    unsigned short* QKVb  = (unsigned short*)((char*)d_ws + 16777216);
    unsigned short* Wt    = (unsigned short*)((char*)d_ws + 67108864);
    unsigned short* Pp    = (unsigned short*)((char*)d_ws + 100663296);
    unsigned short* Vtg   = (unsigned short*)((char*)d_ws + 134217728);
    unsigned short* P1    = (unsigned short*)((char*)d_ws + 167772160);
    unsigned short* Ab    = Xb;

    const bool splitQKV = ws_size >= (size_t)218103808;

    (void)hipFuncSetAttribute((const void*)gemm256, hipFuncAttributeMaxDynamicSharedMemorySize, 131072);

    dim3 blk(256);

    cvt_f32_bf16<<<dim3((S_LEN * HID / 8 + 255) / 256), blk, 0, stream>>>(X, Xb, S_LEN * HID / 8);

    W3 w3{Wq, Wk, Wv};
    cvt_w_t3<<<dim3(HID / 64, HID / 64, 3), blk, 0, stream>>>(w3, Wt, HID, HID);

    if (splitQKV) {
        gemm256<<<dim3(384, 1, 2), dim3(512), 131072, stream>>>(
            Xb, Wt, QKVb, QKV_N, HID / 2, HID, (size_t)75497472);
        v_transpose<true><<<dim3(S_LEN / 64, HID / 64), blk, 0, stream>>>(QKVb, P1, Vtg);
        ln_rope<true><<<dim3(S_LEN * 64 / 4), blk, 0, stream>>>(QKVb, P1, qn_w, qn_b, kn_w, kn_b, pos);
    } else {
        gemm256<<<dim3(384, 1, 1), dim3(512), 131072, stream>>>(
            Xb, Wt, QKVb, QKV_N, HID, HID, (size_t)0);
        v_transpose<false><<<dim3(S_LEN / 64, HID / 64), blk, 0, stream>>>(QKVb, QKVb, Vtg);
        ln_rope<false><<<dim3(S_LEN * 64 / 4), blk, 0, stream>>>(QKVb, QKVb, qn_w, qn_b, kn_w, kn_b, pos);
    }

    attn_fwd<<<dim3(S_LEN / 128, NH), dim3(512), 0, stream>>>(QKVb, Vtg, Ab);

    W3 wo3{Wo, Wo, Wo};
    cvt_w_t3<<<dim3(HID / 64, HID / 64, 1), blk, 0, stream>>>(wo3, Wt, HID, HID);

    gemm256<<<dim3(128, 1, 2), dim3(512), 131072, stream>>>(
        Ab, Wt, Pp, HID, HID / 2, HID, (size_t)S_LEN * HID);
    combine2<<<dim3(S_LEN * HID / 8 / 256), blk, 0, stream>>>(Pp, out);
}

// Round 14
// 505.727 us; speedup vs baseline: 6.7649x; 1.0213x over previous
//
#include <hip/hip_runtime.h>

#define S_LEN 2048
#define HID 4096
#define NH 32
#define HD 128
#define QKV_N 12288   // 3*HID

typedef __attribute__((ext_vector_type(8))) short bf16x8;
typedef __attribute__((ext_vector_type(4))) float f32x4;

__device__ __forceinline__ unsigned short f2bf(float f) {
    unsigned int u = __float_as_uint(f);
    u += 0x7FFF + ((u >> 16) & 1);
    return (unsigned short)(u >> 16);
}
__device__ __forceinline__ float bf2f(unsigned short h) {
    return __uint_as_float(((unsigned int)h) << 16);
}

typedef __attribute__((address_space(1))) const void gconst_void;
typedef __attribute__((address_space(3))) void lds_void;
__device__ __forceinline__ void gl16(const void* g, void* l) {
    __builtin_amdgcn_global_load_lds((gconst_void*)g, (lds_void*)l, 16, 0, 0);
}

#define VMCNT(n) asm volatile("s_waitcnt vmcnt(" #n ")" ::: "memory")
#define BAR()    do { asm volatile("" ::: "memory"); __builtin_amdgcn_s_barrier(); asm volatile("" ::: "memory"); } while (0)

// ---------------- fp32 -> bf16 linear convert ----------------
__global__ __launch_bounds__(256)
void cvt_f32_bf16(const float* __restrict__ in, unsigned short* __restrict__ out, int n8)
{
    int i = blockIdx.x * 256 + threadIdx.x;
    if (i >= n8) return;
    const float4* p = (const float4*)in + (size_t)i * 2;
    float4 a = p[0], b = p[1];
    bf16x8 o;
    o[0] = (short)f2bf(a.x); o[1] = (short)f2bf(a.y); o[2] = (short)f2bf(a.z); o[3] = (short)f2bf(a.w);
    o[4] = (short)f2bf(b.x); o[5] = (short)f2bf(b.y); o[6] = (short)f2bf(b.z); o[7] = (short)f2bf(b.w);
    *((bf16x8*)out + i) = o;
}

// ---------------- fp32 [K][N] -> bf16 [N][K] transpose-convert (up to 3 weights) ----------------
struct W3 { const float* w0; const float* w1; const float* w2; };

__global__ __launch_bounds__(256)
void cvt_w_t3(W3 ws3, unsigned short* __restrict__ Wt, int N, int K)
{
    __shared__ unsigned short t[64][72];
    const float* W = blockIdx.z == 0 ? ws3.w0 : (blockIdx.z == 1 ? ws3.w1 : ws3.w2);
    unsigned short* Wto = Wt + (size_t)blockIdx.z * N * K;
    const int tid = threadIdx.x;
    const int n0 = blockIdx.x * 64, k0 = blockIdx.y * 64;
    const int c4 = (tid & 15) * 4;
    const int r  = tid >> 4;
    #pragma unroll
    for (int p = 0; p < 4; ++p) {
        float4 v = *(const float4*)&W[(size_t)(k0 + r + p * 16) * N + n0 + c4];
        ushort4 o;
        o.x = f2bf(v.x); o.y = f2bf(v.y); o.z = f2bf(v.z); o.w = f2bf(v.w);
        *(ushort4*)&t[r + p * 16][c4] = o;
    }
    __syncthreads();
    const int n = tid >> 2;
    const int kq = (tid & 3) * 16;
    unsigned short* dst = &Wto[(size_t)(n0 + n) * K + k0 + kq];
    bf16x8 v0, v1;
    #pragma unroll
    for (int j = 0; j < 8; ++j) v0[j] = (short)t[kq + j][n];
    #pragma unroll
    for (int j = 0; j < 8; ++j) v1[j] = (short)t[kq + 8 + j][n];
    *(bf16x8*)dst = v0;
    *(bf16x8*)(dst + 8) = v1;
}

// ---------------- bf16 V slab [s][c] -> Vtg [c][s] transpose (+ optional split-K combine) ----------------
template<bool SPLIT>
__global__ __launch_bounds__(256)
void v_transpose(const unsigned short* __restrict__ P0, const unsigned short* __restrict__ P1,
                 unsigned short* __restrict__ Vtg)
{
    __shared__ unsigned short t[64][72];
    const int tid = threadIdx.x;
    const int s0 = blockIdx.x * 64;
    const int c0 = blockIdx.y * 64;
    #pragma unroll
    for (int i = 0; i < 2; ++i) {
        int idx = i * 256 + tid;
        int r = idx >> 3, c8 = (idx & 7) * 8;
        size_t off = (size_t)(s0 + r) * QKV_N + 2 * HID + c0 + c8;
        bf16x8 a = *(const bf16x8*)&P0[off];
        if (SPLIT) {
            bf16x8 b = *(const bf16x8*)&P1[off];
            #pragma unroll
            for (int j = 0; j < 8; ++j)
                a[j] = (short)f2bf(bf2f((unsigned short)a[j]) + bf2f((unsigned short)b[j]));
        }
        *(bf16x8*)&t[r][c8] = a;
    }
    __syncthreads();
    #pragma unroll
    for (int i = 0; i < 2; ++i) {
        int idx = i * 256 + tid;
        int oc = idx >> 3, os8 = (idx & 7) * 8;
        bf16x8 v;
        #pragma unroll
        for (int j = 0; j < 8; ++j) v[j] = (short)t[os8 + j][oc];
        *(bf16x8*)&Vtg[(size_t)(c0 + oc) * S_LEN + s0 + os8] = v;
    }
}

// ---------------- 256x256 GEMM, bf16 out, optional K-split via blockIdx.z ----------------
// single-barrier K-tile (r13, verified): waves free-run; one vmcnt(0)+barrier per tile
__device__ __forceinline__ void lda4(bf16x8 af[4][2], const char* base, int rq, int l15, int lg) {
    const int sw = (l15 & 7) << 4;
    #pragma unroll
    for (int i = 0; i < 4; ++i) {
        const char* rb = base + ((rq * 4 + i) * 16 + l15) * 128;
        af[i][0] = *(const bf16x8*)(rb + ((lg * 16) ^ sw));
        af[i][1] = *(const bf16x8*)(rb + ((64 + lg * 16) ^ sw));
    }
}
__device__ __forceinline__ void ldb2(bf16x8 bf[2][2], const char* base, int cq, int l15, int lg) {
    const int sw = (l15 & 7) << 4;
    #pragma unroll
    for (int j = 0; j < 2; ++j) {
        const char* rb = base + ((cq * 2 + j) * 16 + l15) * 128;
        bf[j][0] = *(const bf16x8*)(rb + ((lg * 16) ^ sw));
        bf[j][1] = *(const bf16x8*)(rb + ((64 + lg * 16) ^ sw));
    }
}
__device__ __forceinline__ void mfma16(f32x4 acc[8][4], const bf16x8 af[4][2], const bf16x8 bf[2][2],
                                       int mi0, int nj0) {
    __builtin_amdgcn_s_setprio(1);
    #pragma unroll
    for (int kk = 0; kk < 2; ++kk)
        #pragma unroll
        for (int i = 0; i < 4; ++i)
            #pragma unroll
            for (int j = 0; j < 2; ++j)
                acc[mi0 + i][nj0 + j] =
                    __builtin_amdgcn_mfma_f32_16x16x32_bf16(af[i][kk], bf[j][kk], acc[mi0 + i][nj0 + j], 0, 0, 0);
    __builtin_amdgcn_s_setprio(0);
}
__device__ __forceinline__ void stage2(const unsigned short* g, char* dst, int ldk, int r32, int kn) {
    gl16(g + (size_t)r32 * ldk + kn, dst);
    gl16(g + (size_t)(r32 + 8) * ldk + kn, dst + 1024);
}

__global__ __launch_bounds__(512, 2)
void gemm256(const unsigned short* __restrict__ A,   // [M][ldk] bf16
             const unsigned short* __restrict__ Bt,  // [N][ldk] bf16
             unsigned short* __restrict__ Cp,        // bf16, + z*zstride
             int N, int K, int ldk, size_t zstride)
{
    extern __shared__ char lds[];
    const int tid = threadIdx.x;
    const int l   = tid & 63;
    const int l15 = l & 15, lg = l >> 4;
    const int wid = tid >> 6;
    const int wr  = wid >> 2;
    const int wc  = wid & 3;

    const int nwg = gridDim.x;
    const int bid = blockIdx.x;
    const int ntx = N >> 8;
    const int nty = nwg / ntx;
    const int cpx = ntx >> 3;
    const int xcd = bid & 7;
    const int idx = bid >> 3;
    const int bx = xcd * cpx + idx / nty;
    const int by = idx % nty;
    const int m0 = by * 256, n0 = bx * 256;
    const int koff = blockIdx.z * K;

    char* const Abase = lds + wr * 16384;
    char* const Bbase = lds + 32768 + (wc >> 1) * 16384 + (wc & 1) * 8192;

    const int l8 = l >> 3, l7 = l & 7;
    const int swslot = (l7 ^ l8) << 3;

    const unsigned short* Ag = A  + (size_t)(m0 + wr * 128 + wc * 16 + l8) * ldk + koff + swslot;
    const unsigned short* Bg = Bt + (size_t)(n0 + wc * 64 + wr * 16 + l8) * ldk + koff + swslot;
    char* const Adst = Abase + (wc * 16) * 128 + l * 16;
    char* const Bdst = Bbase + (wr * 16) * 128 + l * 16;

    f32x4 acc[8][4] = {};
    bf16x8 af[4][2], bfA[2][2], bfB[2][2];

    stage2(Ag, Adst, ldk, 0, 0);
    stage2(Bg, Bdst, ldk, 0, 0);
    stage2(Ag, Adst + 64 * 128, ldk, 64, 0);
    stage2(Bg, Bdst + 32 * 128, ldk, 32, 0);
    VMCNT(0);
    BAR();

    const int NT = K >> 6;
    for (int t = 0; t < NT; ++t) {
        const int cb = (t & 1) * 65536, nb = cb ^ 65536;
        const int kn = (t + 1) << 6;
        const bool hn = (t + 1) < NT;

        lda4(af, Abase + cb, 0, l15, lg);
        ldb2(bfA, Bbase + cb, 0, l15, lg);
        if (hn) { stage2(Ag, Adst + nb, ldk, 0, kn); stage2(Bg, Bdst + nb, ldk, 0, kn); }
        mfma16(acc, af, bfA, 0, 0);

        ldb2(bfB, Bbase + cb, 1, l15, lg);
        if (hn) { stage2(Ag, Adst + nb + 64 * 128, ldk, 64, kn); stage2(Bg, Bdst + nb + 32 * 128, ldk, 32, kn); }
        mfma16(acc, af, bfB, 0, 2);

        lda4(af, Abase + cb, 1, l15, lg);
        mfma16(acc, af, bfB, 4, 2);
        mfma16(acc, af, bfA, 4, 0);

        VMCNT(0);
        BAR();
    }

    unsigned short* C = Cp + (size_t)blockIdx.z * zstride;
    const int crow = m0 + wr * 128 + lg * 4;
    const int ccol = n0 + wc * 64 + l15;
    #pragma unroll
    for (int mi = 0; mi < 8; ++mi)
        #pragma unroll
        for (int nj = 0; nj < 4; ++nj)
            #pragma unroll
            for (int rr = 0; rr < 4; ++rr)
                C[(size_t)(crow + mi * 16 + rr) * N + ccol + nj * 16] = f2bf(acc[mi][nj][rr]);
}

// ---------------- combine 2 bf16 split-K partials -> fp32 out ----------------
__global__ __launch_bounds__(256)
void combine2(const unsigned short* __restrict__ P, float* __restrict__ out)
{
    const size_t i = ((size_t)blockIdx.x * 256 + threadIdx.x) * 8;
    const size_t stride = (size_t)S_LEN * HID;
    bf16x8 a = *(const bf16x8*)&P[i];
    bf16x8 b = *(const bf16x8*)&P[stride + i];
    #pragma unroll
    for (int j = 0; j < 8; ++j)
        out[i + j] = bf2f((unsigned short)a[j]) + bf2f((unsigned short)b[j]);
}

// ---------------- per-head LayerNorm + RoPE (+ optional split-K combine), writes into P0 ----------------
template<bool SPLIT>
__global__ __launch_bounds__(256)
void ln_rope(unsigned short* __restrict__ P0, const unsigned short* __restrict__ P1,
             const float* __restrict__ qg, const float* __restrict__ qb,
             const float* __restrict__ kg, const float* __restrict__ kb,
             const int* __restrict__ pos)
{
    const int tid = threadIdx.x;
    const int l = tid & 63;
    const int w = tid >> 6;
    const int rid = blockIdx.x * 4 + w;
    const int s = rid >> 6;
    const int hh = rid & 63;
    const int which = hh >> 5;
    const int h = hh & 31;
    const size_t off = (size_t)s * QKV_N + which * HID + h * HD;
    unsigned short* p = P0 + off;
    const float* gamma = which ? kg : qg;
    const float* beta  = which ? kb : qb;

    float lo = bf2f(p[l]);
    float hi = bf2f(p[l + 64]);
    if (SPLIT) {
        const unsigned short* q = P1 + off;
        lo += bf2f(q[l]);
        hi += bf2f(q[l + 64]);
    }
    float sum = lo + hi;
    #pragma unroll
    for (int off2 = 32; off2 >= 1; off2 >>= 1) sum += __shfl_xor(sum, off2, 64);
    float mu = sum * (1.0f / 128.0f);
    float dlo = lo - mu, dhi = hi - mu;
    float vs = dlo * dlo + dhi * dhi;
    #pragma unroll
    for (int off2 = 32; off2 >= 1; off2 >>= 1) vs += __shfl_xor(vs, off2, 64);
    float rstd = rsqrtf(vs * (1.0f / 128.0f) + 1e-5f);
    float xlo = dlo * rstd * gamma[l] + beta[l];
    float xhi = dhi * rstd * gamma[l + 64] + beta[l + 64];

    float fpos = (float)pos[s];
    float invf = exp2f(-13.287712379549449f * (float)l * (1.0f / 64.0f));
    float ang = fpos * invf;
    float sn, cs;
    sincosf(ang, &sn, &cs);
    p[l]      = f2bf(xlo * cs - xhi * sn);
    p[l + 64] = f2bf(xhi * cs + xlo * sn);
}

// ---------------- causal flash attention: 8 waves x 16 rows (QBLK=128), KVB=128 dbuf pipeline ----------------
#define KVB 128
// dynamic LDS: Ks[2][128*128] | Vs[2][128*128] | Ps[8][16*72]  = 149504 B
#define ATTN_LDS 149504

__global__ __launch_bounds__(512)
void attn_fwd(const unsigned short* __restrict__ QKV,   // [S][12288]
              const unsigned short* __restrict__ Vtg,   // [4096][S]
              unsigned short* __restrict__ O)           // [S][4096]
{
    extern __shared__ char shb[];
    // byte offsets: Ks[buf] @ buf*32768 ; Vs[buf] @ 65536 + buf*32768 ; Ps @ 131072
    unsigned short* const Psw = (unsigned short*)(shb + 131072) + (threadIdx.x >> 6) * (16 * 72);

    const int tid = threadIdx.x;
    const int l = tid & 63;
    const int w = tid >> 6;
    const int l15 = l & 15, lg = l >> 4;
    const int h = blockIdx.y;
    const int qb = gridDim.x - 1 - blockIdx.x;   // longest blocks first
    const int q0 = qb * 128;
    const int qw = q0 + w * 16;

    const unsigned short* Qp = QKV + h * HD;
    const unsigned short* Kp = QKV + HID + h * HD;
    const unsigned short* Vp = Vtg + (size_t)h * HD * S_LEN;

    bf16x8 qf[4];
    #pragma unroll
    for (int d = 0; d < 4; ++d)
        qf[d] = *(const bf16x8*)&Qp[(size_t)(qw + l15) * QKV_N + d * 32 + lg * 8];

    f32x4 o_acc[8] = {};
    float mrow[4], lsum[4];
    #pragma unroll
    for (int r = 0; r < 4; ++r) { mrow[r] = -1e30f; lsum[r] = 0.0f; }

    const float scale = 0.08838834764831845f;

    // staging: 512 threads x 4 chunks for K and V each (16 slots/row of 256B, swizzled)
    const int ksl = tid & 15;
    const int kr7 = (tid >> 4) & 7;
    const int ksg = (ksl & 8) | ((ksl ^ kr7) & 7);
    const unsigned short* Kg = Kp + (size_t)(tid >> 4) * QKV_N + ksg * 8;
    const unsigned short* Vg = Vp + (size_t)(tid >> 4) * S_LEN + ksg * 8;

    // issue order per tile: 4x K then 4x V (FIFO order is load-bearing for vmcnt)
#define STAGE(buf, kv0s) do {                                                          \
    _Pragma("unroll")                                                                  \
    for (int i_ = 0; i_ < 4; ++i_)                                                     \
        gl16(Kg + (size_t)((kv0s) + i_ * 32) * QKV_N,                                  \
             shb + (buf) * 32768 + (i_ * 512 + tid) * 16);                             \
    _Pragma("unroll")                                                                  \
    for (int i_ = 0; i_ < 4; ++i_)                                                     \
        gl16(Vg + (size_t)i_ * 32 * S_LEN + (kv0s),                                    \
             shb + 65536 + (buf) * 32768 + (i_ * 512 + tid) * 16);                     \
} while (0)

    STAGE(0, 0);
    VMCNT(4);        // K0 landed; V0's 4 stay in flight
    __syncthreads();

    // invariant entering tile t: outstanding = V(t) x4
    const int nt = qb + 1;
    for (int t = 0; t < nt; ++t) {
        const int kv0 = t * KVB;
        const int cur = t & 1;
        const bool hn = (t + 1) < nt;
        if (hn) STAGE(cur ^ 1, kv0 + KVB);   // outstanding: V(t)4 + K(t+1)4 + V(t+1)4

        // S = Q K^T over 8 kv fragments
        f32x4 sc[8] = {};
        const char* Kb = shb + cur * 32768;
        #pragma unroll
        for (int kvf = 0; kvf < 8; ++kvf) {
            int r = kvf * 16 + l15;
            int sw = (r & 7) << 4;
            #pragma unroll
            for (int d = 0; d < 4; ++d) {
                bf16x8 kf = *(const bf16x8*)(Kb + r * 256 + ((d * 64 + lg * 16) ^ sw));
                sc[kvf] = __builtin_amdgcn_mfma_f32_16x16x32_bf16(qf[d], kf, sc[kvf], 0, 0, 0);
            }
        }

        // online softmax (defer-max THR=8); half1 p-values kept in regs
        const bool full = (kv0 + KVB <= qw);
        float ph[4][4];
        #pragma unroll
        for (int r = 0; r < 4; ++r) {
            int qg = qw + lg * 4 + r;
            float sv[8];
            #pragma unroll
            for (int k = 0; k < 8; ++k) {
                float v = sc[k][r] * scale;
                if (!full && (kv0 + k * 16 + l15 > qg)) v = -1e30f;
                sv[k] = v;
            }
            float mx = sv[0];
            #pragma unroll
            for (int k = 1; k < 8; ++k) mx = fmaxf(mx, sv[k]);
            #pragma unroll
            for (int off = 8; off >= 1; off >>= 1) mx = fmaxf(mx, __shfl_xor(mx, off, 64));
            float mn = mrow[r];
            if (!__all(mx <= mn + 8.0f)) {
                mn = fmaxf(mn, mx);
                float corr = __expf(mrow[r] - mn);
                lsum[r] *= corr;
                #pragma unroll
                for (int df = 0; df < 8; ++df) o_acc[df][r] *= corr;
                mrow[r] = mn;
            }
            int ql = lg * 4 + r;
            float psum = 0.0f;
            #pragma unroll
            for (int k = 0; k < 8; ++k) {
                float p = __expf(sv[k] - mn);
                psum += p;
                if (k < 4) Psw[ql * 72 + k * 16 + l15] = f2bf(p);
                else       ph[r][k - 4] = p;
            }
            lsum[r] += psum;
        }

        // own V(t) landed (oldest 4); barrier: ALL waves' V(t) visible (V rows cross-wave)
        if (hn) { VMCNT(8); } else { VMCNT(0); }
        BAR();

        const char* Vb = shb + 65536 + cur * 32768;
        // PV half 0 (kv 0..63)
        {
            bf16x8 pa0 = *(const bf16x8*)&Psw[l15 * 72 + lg * 8];
            bf16x8 pa1 = *(const bf16x8*)&Psw[l15 * 72 + 32 + lg * 8];
            #pragma unroll
            for (int df = 0; df < 8; ++df) {
                int d = df * 16 + l15;
                int sw = (d & 7) << 4;
                const char* vrow = Vb + d * 256;
                bf16x8 v0 = *(const bf16x8*)(vrow + ((lg * 16) ^ sw));
                bf16x8 v1 = *(const bf16x8*)(vrow + ((64 + lg * 16) ^ sw));
                o_acc[df] = __builtin_amdgcn_mfma_f32_16x16x32_bf16(pa0, v0, o_acc[df], 0, 0, 0);
                o_acc[df] = __builtin_amdgcn_mfma_f32_16x16x32_bf16(pa1, v1, o_acc[df], 0, 0, 0);
            }
        }
        // write half 1 P into the same per-wave Ps slice (same-wave lgkm ordering)
        #pragma unroll
        for (int r = 0; r < 4; ++r) {
            int ql = lg * 4 + r;
            #pragma unroll
            for (int k = 0; k < 4; ++k)
                Psw[ql * 72 + k * 16 + l15] = f2bf(ph[r][k]);
        }
        // PV half 1 (kv 64..127)
        {
            bf16x8 pa0 = *(const bf16x8*)&Psw[l15 * 72 + lg * 8];
            bf16x8 pa1 = *(const bf16x8*)&Psw[l15 * 72 + 32 + lg * 8];
            #pragma unroll
            for (int df = 0; df < 8; ++df) {
                int d = df * 16 + l15;
                int sw = (d & 7) << 4;
                const char* vrow = Vb + d * 256;
                bf16x8 v0 = *(const bf16x8*)(vrow + ((128 + lg * 16) ^ sw));
                bf16x8 v1 = *(const bf16x8*)(vrow + ((128 + 64 + lg * 16) ^ sw));
                o_acc[df] = __builtin_amdgcn_mfma_f32_16x16x32_bf16(pa0, v0, o_acc[df], 0, 0, 0);
                o_acc[df] = __builtin_amdgcn_mfma_f32_16x16x32_bf16(pa1, v1, o_acc[df], 0, 0, 0);
            }
        }

        VMCNT(4);   // K(t+1) landed; leaves V(t+1) x4 -> invariant
        BAR();
    }
#undef STAGE

    float inv[4];
    #pragma unroll
    for (int r = 0; r < 4; ++r) {
        float s = lsum[r];
        #pragma unroll
        for (int off = 8; off >= 1; off >>= 1) s += __shfl_xor(s, off, 64);
        inv[r] = 1.0f / s;
    }
    #pragma unroll
    for (int df = 0; df < 8; ++df) {
        #pragma unroll
        for (int r = 0; r < 4; ++r) {
            int q = qw + lg * 4 + r;
            int d = h * HD + df * 16 + l15;
            O[(size_t)q * HID + d] = f2bf(o_acc[df][r] * inv[r]);
        }
    }
}

extern "C" void kernel_launch(void* const* d_in, const int* in_sizes, int n_in,
                              void* d_out, int out_size, void* d_ws, size_t ws_size,
                              hipStream_t stream)
{
    (void)in_sizes; (void)n_in; (void)out_size;
    const float* X    = (const float*)d_in[0];
    const int*   pos  = (const int*)d_in[1];
    const float* Wq   = (const float*)d_in[2];
    const float* Wk   = (const float*)d_in[3];
    const float* Wv   = (const float*)d_in[4];
    const float* Wo   = (const float*)d_in[5];
    const float* qn_w = (const float*)d_in[6];
    const float* qn_b = (const float*)d_in[7];
    const float* kn_w = (const float*)d_in[8];
    const float* kn_b = (const float*)d_in[9];
    float* out = (float*)d_out;

    unsigned short* Xb    = (unsigned short*)d_ws;
    unsigned short* QKVb  = (unsigned short*)((char*)d_ws + 16777216);
    unsigned short* Wt    = (unsigned short*)((char*)d_ws + 67108864);
    unsigned short* Pp    = (unsigned short*)((char*)d_ws + 100663296);
    unsigned short* Vtg   = (unsigned short*)((char*)d_ws + 134217728);
    unsigned short* P1    = (unsigned short*)((char*)d_ws + 167772160);
    unsigned short* Ab    = Xb;

    const bool splitQKV = ws_size >= (size_t)218103808;

    (void)hipFuncSetAttribute((const void*)gemm256, hipFuncAttributeMaxDynamicSharedMemorySize, 131072);
    (void)hipFuncSetAttribute((const void*)attn_fwd, hipFuncAttributeMaxDynamicSharedMemorySize, ATTN_LDS);

    dim3 blk(256);

    cvt_f32_bf16<<<dim3((S_LEN * HID / 8 + 255) / 256), blk, 0, stream>>>(X, Xb, S_LEN * HID / 8);

    W3 w3{Wq, Wk, Wv};
    cvt_w_t3<<<dim3(HID / 64, HID / 64, 3), blk, 0, stream>>>(w3, Wt, HID, HID);

    if (splitQKV) {
        gemm256<<<dim3(384, 1, 2), dim3(512), 131072, stream>>>(
            Xb, Wt, QKVb, QKV_N, HID / 2, HID, (size_t)75497472);
        v_transpose<true><<<dim3(S_LEN / 64, HID / 64), blk, 0, stream>>>(QKVb, P1, Vtg);
        ln_rope<true><<<dim3(S_LEN * 64 / 4), blk, 0, stream>>>(QKVb, P1, qn_w, qn_b, kn_w, kn_b, pos);
    } else {
        gemm256<<<dim3(384, 1, 1), dim3(512), 131072, stream>>>(
            Xb, Wt, QKVb, QKV_N, HID, HID, (size_t)0);
        v_transpose<false><<<dim3(S_LEN / 64, HID / 64), blk, 0, stream>>>(QKVb, QKVb, Vtg);
        ln_rope<false><<<dim3(S_LEN * 64 / 4), blk, 0, stream>>>(QKVb, QKVb, qn_w, qn_b, kn_w, kn_b, pos);
    }

    attn_fwd<<<dim3(S_LEN / 128, NH), dim3(512), ATTN_LDS, stream>>>(QKVb, Vtg, Ab);

    W3 wo3{Wo, Wo, Wo};
    cvt_w_t3<<<dim3(HID / 64, HID / 64, 1), blk, 0, stream>>>(wo3, Wt, HID, HID);

    gemm256<<<dim3(128, 1, 2), dim3(512), 131072, stream>>>(
        Ab, Wt, Pp, HID, HID / 2, HID, (size_t)S_LEN * HID);
    combine2<<<dim3(S_LEN * HID / 8 / 256), blk, 0, stream>>>(Pp, out);
}

// Round 15
// 484.126 us; speedup vs baseline: 7.0667x; 1.0446x over previous
//
#include <hip/hip_runtime.h>

#define S_LEN 2048
#define HID 4096
#define NH 32
#define HD 128
#define QKV_N 12288   // 3*HID

typedef __attribute__((ext_vector_type(8))) short bf16x8;
typedef __attribute__((ext_vector_type(4))) float f32x4;

__device__ __forceinline__ unsigned short f2bf(float f) {
    unsigned int u = __float_as_uint(f);
    u += 0x7FFF + ((u >> 16) & 1);
    return (unsigned short)(u >> 16);
}
__device__ __forceinline__ float bf2f(unsigned short h) {
    return __uint_as_float(((unsigned int)h) << 16);
}

typedef __attribute__((address_space(1))) const void gconst_void;
typedef __attribute__((address_space(3))) void lds_void;
__device__ __forceinline__ void gl16(const void* g, void* l) {
    __builtin_amdgcn_global_load_lds((gconst_void*)g, (lds_void*)l, 16, 0, 0);
}

#define VMCNT(n) asm volatile("s_waitcnt vmcnt(" #n ")" ::: "memory")
#define BAR()    do { asm volatile("" ::: "memory"); __builtin_amdgcn_s_barrier(); asm volatile("" ::: "memory"); } while (0)

// ---------------- fp32 -> bf16 linear convert ----------------
__global__ __launch_bounds__(256)
void cvt_f32_bf16(const float* __restrict__ in, unsigned short* __restrict__ out, int n8)
{
    int i = blockIdx.x * 256 + threadIdx.x;
    if (i >= n8) return;
    const float4* p = (const float4*)in + (size_t)i * 2;
    float4 a = p[0], b = p[1];
    bf16x8 o;
    o[0] = (short)f2bf(a.x); o[1] = (short)f2bf(a.y); o[2] = (short)f2bf(a.z); o[3] = (short)f2bf(a.w);
    o[4] = (short)f2bf(b.x); o[5] = (short)f2bf(b.y); o[6] = (short)f2bf(b.z); o[7] = (short)f2bf(b.w);
    *((bf16x8*)out + i) = o;
}

// ---------------- fp32 [K][N] -> bf16 [N][K] transpose-convert (up to 3 weights) ----------------
struct W3 { const float* w0; const float* w1; const float* w2; };

__global__ __launch_bounds__(256)
void cvt_w_t3(W3 ws3, unsigned short* __restrict__ Wt, int N, int K)
{
    __shared__ unsigned short t[64][72];
    const float* W = blockIdx.z == 0 ? ws3.w0 : (blockIdx.z == 1 ? ws3.w1 : ws3.w2);
    unsigned short* Wto = Wt + (size_t)blockIdx.z * N * K;
    const int tid = threadIdx.x;
    const int n0 = blockIdx.x * 64, k0 = blockIdx.y * 64;
    const int c4 = (tid & 15) * 4;
    const int r  = tid >> 4;
    #pragma unroll
    for (int p = 0; p < 4; ++p) {
        float4 v = *(const float4*)&W[(size_t)(k0 + r + p * 16) * N + n0 + c4];
        ushort4 o;
        o.x = f2bf(v.x); o.y = f2bf(v.y); o.z = f2bf(v.z); o.w = f2bf(v.w);
        *(ushort4*)&t[r + p * 16][c4] = o;
    }
    __syncthreads();
    const int n = tid >> 2;
    const int kq = (tid & 3) * 16;
    unsigned short* dst = &Wto[(size_t)(n0 + n) * K + k0 + kq];
    bf16x8 v0, v1;
    #pragma unroll
    for (int j = 0; j < 8; ++j) v0[j] = (short)t[kq + j][n];
    #pragma unroll
    for (int j = 0; j < 8; ++j) v1[j] = (short)t[kq + 8 + j][n];
    *(bf16x8*)dst = v0;
    *(bf16x8*)(dst + 8) = v1;
}

// ---------------- bf16 V slab [s][c] -> Vtg [c][s] transpose (+ optional split-K combine) ----------------
template<bool SPLIT>
__global__ __launch_bounds__(256)
void v_transpose(const unsigned short* __restrict__ P0, const unsigned short* __restrict__ P1,
                 unsigned short* __restrict__ Vtg)
{
    __shared__ unsigned short t[64][72];
    const int tid = threadIdx.x;
    const int s0 = blockIdx.x * 64;
    const int c0 = blockIdx.y * 64;
    #pragma unroll
    for (int i = 0; i < 2; ++i) {
        int idx = i * 256 + tid;
        int r = idx >> 3, c8 = (idx & 7) * 8;
        size_t off = (size_t)(s0 + r) * QKV_N + 2 * HID + c0 + c8;
        bf16x8 a = *(const bf16x8*)&P0[off];
        if (SPLIT) {
            bf16x8 b = *(const bf16x8*)&P1[off];
            #pragma unroll
            for (int j = 0; j < 8; ++j)
                a[j] = (short)f2bf(bf2f((unsigned short)a[j]) + bf2f((unsigned short)b[j]));
        }
        *(bf16x8*)&t[r][c8] = a;
    }
    __syncthreads();
    #pragma unroll
    for (int i = 0; i < 2; ++i) {
        int idx = i * 256 + tid;
        int oc = idx >> 3, os8 = (idx & 7) * 8;
        bf16x8 v;
        #pragma unroll
        for (int j = 0; j < 8; ++j) v[j] = (short)t[os8 + j][oc];
        *(bf16x8*)&Vtg[(size_t)(c0 + oc) * S_LEN + s0 + os8] = v;
    }
}

// ---------------- 256x256 GEMM, bf16 out, optional K-split via blockIdx.z ----------------
// single-barrier K-tile (r13, verified): waves free-run; one vmcnt(0)+barrier per tile
__device__ __forceinline__ void lda4(bf16x8 af[4][2], const char* base, int rq, int l15, int lg) {
    const int sw = (l15 & 7) << 4;
    #pragma unroll
    for (int i = 0; i < 4; ++i) {
        const char* rb = base + ((rq * 4 + i) * 16 + l15) * 128;
        af[i][0] = *(const bf16x8*)(rb + ((lg * 16) ^ sw));
        af[i][1] = *(const bf16x8*)(rb + ((64 + lg * 16) ^ sw));
    }
}
__device__ __forceinline__ void ldb2(bf16x8 bf[2][2], const char* base, int cq, int l15, int lg) {
    const int sw = (l15 & 7) << 4;
    #pragma unroll
    for (int j = 0; j < 2; ++j) {
        const char* rb = base + ((cq * 2 + j) * 16 + l15) * 128;
        bf[j][0] = *(const bf16x8*)(rb + ((lg * 16) ^ sw));
        bf[j][1] = *(const bf16x8*)(rb + ((64 + lg * 16) ^ sw));
    }
}
__device__ __forceinline__ void mfma16(f32x4 acc[8][4], const bf16x8 af[4][2], const bf16x8 bf[2][2],
                                       int mi0, int nj0) {
    __builtin_amdgcn_s_setprio(1);
    #pragma unroll
    for (int kk = 0; kk < 2; ++kk)
        #pragma unroll
        for (int i = 0; i < 4; ++i)
            #pragma unroll
            for (int j = 0; j < 2; ++j)
                acc[mi0 + i][nj0 + j] =
                    __builtin_amdgcn_mfma_f32_16x16x32_bf16(af[i][kk], bf[j][kk], acc[mi0 + i][nj0 + j], 0, 0, 0);
    __builtin_amdgcn_s_setprio(0);
}
__device__ __forceinline__ void stage2(const unsigned short* g, char* dst, int ldk, int r32, int kn) {
    gl16(g + (size_t)r32 * ldk + kn, dst);
    gl16(g + (size_t)(r32 + 8) * ldk + kn, dst + 1024);
}

__global__ __launch_bounds__(512, 2)
void gemm256(const unsigned short* __restrict__ A,   // [M][ldk] bf16
             const unsigned short* __restrict__ Bt,  // [N][ldk] bf16
             unsigned short* __restrict__ Cp,        // bf16, + z*zstride
             int N, int K, int ldk, size_t zstride)
{
    extern __shared__ char lds[];
    const int tid = threadIdx.x;
    const int l   = tid & 63;
    const int l15 = l & 15, lg = l >> 4;
    const int wid = tid >> 6;
    const int wr  = wid >> 2;
    const int wc  = wid & 3;

    const int nwg = gridDim.x;
    const int bid = blockIdx.x;
    const int ntx = N >> 8;
    const int nty = nwg / ntx;
    const int cpx = ntx >> 3;
    const int xcd = bid & 7;
    const int idx = bid >> 3;
    const int bx = xcd * cpx + idx / nty;
    const int by = idx % nty;
    const int m0 = by * 256, n0 = bx * 256;
    const int koff = blockIdx.z * K;

    char* const Abase = lds + wr * 16384;
    char* const Bbase = lds + 32768 + (wc >> 1) * 16384 + (wc & 1) * 8192;

    const int l8 = l >> 3, l7 = l & 7;
    const int swslot = (l7 ^ l8) << 3;

    const unsigned short* Ag = A  + (size_t)(m0 + wr * 128 + wc * 16 + l8) * ldk + koff + swslot;
    const unsigned short* Bg = Bt + (size_t)(n0 + wc * 64 + wr * 16 + l8) * ldk + koff + swslot;
    char* const Adst = Abase + (wc * 16) * 128 + l * 16;
    char* const Bdst = Bbase + (wr * 16) * 128 + l * 16;

    f32x4 acc[8][4] = {};
    bf16x8 af[4][2], bfA[2][2], bfB[2][2];

    stage2(Ag, Adst, ldk, 0, 0);
    stage2(Bg, Bdst, ldk, 0, 0);
    stage2(Ag, Adst + 64 * 128, ldk, 64, 0);
    stage2(Bg, Bdst + 32 * 128, ldk, 32, 0);
    VMCNT(0);
    BAR();

    const int NT = K >> 6;
    for (int t = 0; t < NT; ++t) {
        const int cb = (t & 1) * 65536, nb = cb ^ 65536;
        const int kn = (t + 1) << 6;
        const bool hn = (t + 1) < NT;

        lda4(af, Abase + cb, 0, l15, lg);
        ldb2(bfA, Bbase + cb, 0, l15, lg);
        if (hn) { stage2(Ag, Adst + nb, ldk, 0, kn); stage2(Bg, Bdst + nb, ldk, 0, kn); }
        mfma16(acc, af, bfA, 0, 0);

        ldb2(bfB, Bbase + cb, 1, l15, lg);
        if (hn) { stage2(Ag, Adst + nb + 64 * 128, ldk, 64, kn); stage2(Bg, Bdst + nb + 32 * 128, ldk, 32, kn); }
        mfma16(acc, af, bfB, 0, 2);

        lda4(af, Abase + cb, 1, l15, lg);
        mfma16(acc, af, bfB, 4, 2);
        mfma16(acc, af, bfA, 4, 0);

        VMCNT(0);
        BAR();
    }

    unsigned short* C = Cp + (size_t)blockIdx.z * zstride;
    const int crow = m0 + wr * 128 + lg * 4;
    const int ccol = n0 + wc * 64 + l15;
    #pragma unroll
    for (int mi = 0; mi < 8; ++mi)
        #pragma unroll
        for (int nj = 0; nj < 4; ++nj)
            #pragma unroll
            for (int rr = 0; rr < 4; ++rr)
                C[(size_t)(crow + mi * 16 + rr) * N + ccol + nj * 16] = f2bf(acc[mi][nj][rr]);
}

// ---------------- combine 2 bf16 split-K partials -> fp32 out ----------------
__global__ __launch_bounds__(256)
void combine2(const unsigned short* __restrict__ P, float* __restrict__ out)
{
    const size_t i = ((size_t)blockIdx.x * 256 + threadIdx.x) * 8;
    const size_t stride = (size_t)S_LEN * HID;
    bf16x8 a = *(const bf16x8*)&P[i];
    bf16x8 b = *(const bf16x8*)&P[stride + i];
    #pragma unroll
    for (int j = 0; j < 8; ++j)
        out[i + j] = bf2f((unsigned short)a[j]) + bf2f((unsigned short)b[j]);
}

// ---------------- per-head LayerNorm + RoPE (+ optional split-K combine), writes into P0 ----------------
template<bool SPLIT>
__global__ __launch_bounds__(256)
void ln_rope(unsigned short* __restrict__ P0, const unsigned short* __restrict__ P1,
             const float* __restrict__ qg, const float* __restrict__ qb,
             const float* __restrict__ kg, const float* __restrict__ kb,
             const int* __restrict__ pos)
{
    const int tid = threadIdx.x;
    const int l = tid & 63;
    const int w = tid >> 6;
    const int rid = blockIdx.x * 4 + w;
    const int s = rid >> 6;
    const int hh = rid & 63;
    const int which = hh >> 5;
    const int h = hh & 31;
    const size_t off = (size_t)s * QKV_N + which * HID + h * HD;
    unsigned short* p = P0 + off;
    const float* gamma = which ? kg : qg;
    const float* beta  = which ? kb : qb;

    float lo = bf2f(p[l]);
    float hi = bf2f(p[l + 64]);
    if (SPLIT) {
        const unsigned short* q = P1 + off;
        lo += bf2f(q[l]);
        hi += bf2f(q[l + 64]);
    }
    float sum = lo + hi;
    #pragma unroll
    for (int off2 = 32; off2 >= 1; off2 >>= 1) sum += __shfl_xor(sum, off2, 64);
    float mu = sum * (1.0f / 128.0f);
    float dlo = lo - mu, dhi = hi - mu;
    float vs = dlo * dlo + dhi * dhi;
    #pragma unroll
    for (int off2 = 32; off2 >= 1; off2 >>= 1) vs += __shfl_xor(vs, off2, 64);
    float rstd = rsqrtf(vs * (1.0f / 128.0f) + 1e-5f);
    float xlo = dlo * rstd * gamma[l] + beta[l];
    float xhi = dhi * rstd * gamma[l + 64] + beta[l + 64];

    float fpos = (float)pos[s];
    float invf = exp2f(-13.287712379549449f * (float)l * (1.0f / 64.0f));
    float ang = fpos * invf;
    float sn, cs;
    sincosf(ang, &sn, &cs);
    p[l]      = f2bf(xlo * cs - xhi * sn);
    p[l + 64] = f2bf(xhi * cs + xlo * sn);
}

// ---------------- causal flash attention: 8 waves x 16 rows (QBLK=128), KVB=128 dbuf pipeline ----------------
// r15: group-max softmax — one shared running max per lane's 4 rows (defer-max bound still holds)
#define KVB 128
#define ATTN_LDS 149504

__global__ __launch_bounds__(512)
void attn_fwd(const unsigned short* __restrict__ QKV,   // [S][12288]
              const unsigned short* __restrict__ Vtg,   // [4096][S]
              unsigned short* __restrict__ O)           // [S][4096]
{
    extern __shared__ char shb[];
    unsigned short* const Psw = (unsigned short*)(shb + 131072) + (threadIdx.x >> 6) * (16 * 72);

    const int tid = threadIdx.x;
    const int l = tid & 63;
    const int w = tid >> 6;
    const int l15 = l & 15, lg = l >> 4;
    const int h = blockIdx.y;
    const int qb = gridDim.x - 1 - blockIdx.x;
    const int q0 = qb * 128;
    const int qw = q0 + w * 16;

    const unsigned short* Qp = QKV + h * HD;
    const unsigned short* Kp = QKV + HID + h * HD;
    const unsigned short* Vp = Vtg + (size_t)h * HD * S_LEN;

    bf16x8 qf[4];
    #pragma unroll
    for (int d = 0; d < 4; ++d)
        qf[d] = *(const bf16x8*)&Qp[(size_t)(qw + l15) * QKV_N + d * 32 + lg * 8];

    f32x4 o_acc[8] = {};
    float mgrp = -1e30f;              // shared running max for this lane's 4 rows
    float lsum[4] = {0.0f, 0.0f, 0.0f, 0.0f};

    const float scale = 0.08838834764831845f;

    const int ksl = tid & 15;
    const int kr7 = (tid >> 4) & 7;
    const int ksg = (ksl & 8) | ((ksl ^ kr7) & 7);
    const unsigned short* Kg = Kp + (size_t)(tid >> 4) * QKV_N + ksg * 8;
    const unsigned short* Vg = Vp + (size_t)(tid >> 4) * S_LEN + ksg * 8;

#define STAGE(buf, kv0s) do {                                                          \
    _Pragma("unroll")                                                                  \
    for (int i_ = 0; i_ < 4; ++i_)                                                     \
        gl16(Kg + (size_t)((kv0s) + i_ * 32) * QKV_N,                                  \
             shb + (buf) * 32768 + (i_ * 512 + tid) * 16);                             \
    _Pragma("unroll")                                                                  \
    for (int i_ = 0; i_ < 4; ++i_)                                                     \
        gl16(Vg + (size_t)i_ * 32 * S_LEN + (kv0s),                                    \
             shb + 65536 + (buf) * 32768 + (i_ * 512 + tid) * 16);                     \
} while (0)

    STAGE(0, 0);
    VMCNT(4);
    __syncthreads();

    const int nt = qb + 1;
    for (int t = 0; t < nt; ++t) {
        const int kv0 = t * KVB;
        const int cur = t & 1;
        const bool hn = (t + 1) < nt;
        if (hn) STAGE(cur ^ 1, kv0 + KVB);

        f32x4 sc[8] = {};
        const char* Kb = shb + cur * 32768;
        #pragma unroll
        for (int kvf = 0; kvf < 8; ++kvf) {
            int r = kvf * 16 + l15;
            int sw = (r & 7) << 4;
            #pragma unroll
            for (int d = 0; d < 4; ++d) {
                bf16x8 kf = *(const bf16x8*)(Kb + r * 256 + ((d * 64 + lg * 16) ^ sw));
                sc[kvf] = __builtin_amdgcn_mfma_f32_16x16x32_bf16(qf[d], kf, sc[kvf], 0, 0, 0);
            }
        }

        const bool full = (kv0 + KVB <= qw);
        // diagonal tile: mask in place (raw-score domain, scale > 0 so order preserved)
        if (!full) {
            #pragma unroll
            for (int k = 0; k < 8; ++k) {
                #pragma unroll
                for (int r = 0; r < 4; ++r) {
                    int qg = qw + lg * 4 + r;
                    if (kv0 + k * 16 + l15 > qg) sc[k][r] = -1e30f;
                }
            }
        }
        // group max over all 32 scores, then over the 16 lanes sharing lg
        float mx = fmaxf(fmaxf(sc[0][0], sc[0][1]), fmaxf(sc[0][2], sc[0][3]));
        #pragma unroll
        for (int k = 1; k < 8; ++k) {
            float m2 = fmaxf(fmaxf(sc[k][0], sc[k][1]), fmaxf(sc[k][2], sc[k][3]));
            mx = fmaxf(mx, m2);
        }
        mx *= scale;
        #pragma unroll
        for (int off = 8; off >= 1; off >>= 1) mx = fmaxf(mx, __shfl_xor(mx, off, 64));
        if (!__all(mx <= mgrp + 8.0f)) {
            float mn = fmaxf(mgrp, mx);
            float corr = __expf(mgrp - mn);
            #pragma unroll
            for (int r = 0; r < 4; ++r) lsum[r] *= corr;
            #pragma unroll
            for (int df = 0; df < 8; ++df) o_acc[df] *= corr;
            mgrp = mn;
        }
        const float mn = mgrp;

        float ph[4][4];
        #pragma unroll
        for (int r = 0; r < 4; ++r) {
            int ql = lg * 4 + r;
            float psum = 0.0f;
            #pragma unroll
            for (int k = 0; k < 8; ++k) {
                float p = __expf(fmaf(sc[k][r], scale, -mn));
                psum += p;
                if (k < 4) Psw[ql * 72 + k * 16 + l15] = f2bf(p);
                else       ph[r][k - 4] = p;
            }
            lsum[r] += psum;
        }

        if (hn) { VMCNT(8); } else { VMCNT(0); }
        BAR();

        const char* Vb = shb + 65536 + cur * 32768;
        {
            bf16x8 pa0 = *(const bf16x8*)&Psw[l15 * 72 + lg * 8];
            bf16x8 pa1 = *(const bf16x8*)&Psw[l15 * 72 + 32 + lg * 8];
            #pragma unroll
            for (int df = 0; df < 8; ++df) {
                int d = df * 16 + l15;
                int sw = (d & 7) << 4;
                const char* vrow = Vb + d * 256;
                bf16x8 v0 = *(const bf16x8*)(vrow + ((lg * 16) ^ sw));
                bf16x8 v1 = *(const bf16x8*)(vrow + ((64 + lg * 16) ^ sw));
                o_acc[df] = __builtin_amdgcn_mfma_f32_16x16x32_bf16(pa0, v0, o_acc[df], 0, 0, 0);
                o_acc[df] = __builtin_amdgcn_mfma_f32_16x16x32_bf16(pa1, v1, o_acc[df], 0, 0, 0);
            }
        }
        #pragma unroll
        for (int r = 0; r < 4; ++r) {
            int ql = lg * 4 + r;
            #pragma unroll
            for (int k = 0; k < 4; ++k)
                Psw[ql * 72 + k * 16 + l15] = f2bf(ph[r][k]);
        }
        {
            bf16x8 pa0 = *(const bf16x8*)&Psw[l15 * 72 + lg * 8];
            bf16x8 pa1 = *(const bf16x8*)&Psw[l15 * 72 + 32 + lg * 8];
            #pragma unroll
            for (int df = 0; df < 8; ++df) {
                int d = df * 16 + l15;
                int sw = (d & 7) << 4;
                const char* vrow = Vb + d * 256;
                bf16x8 v0 = *(const bf16x8*)(vrow + ((128 + lg * 16) ^ sw));
                bf16x8 v1 = *(const bf16x8*)(vrow + ((128 + 64 + lg * 16) ^ sw));
                o_acc[df] = __builtin_amdgcn_mfma_f32_16x16x32_bf16(pa0, v0, o_acc[df], 0, 0, 0);
                o_acc[df] = __builtin_amdgcn_mfma_f32_16x16x32_bf16(pa1, v1, o_acc[df], 0, 0, 0);
            }
        }

        VMCNT(4);
        BAR();
    }
#undef STAGE

    float inv[4];
    #pragma unroll
    for (int r = 0; r < 4; ++r) {
        float s = lsum[r];
        #pragma unroll
        for (int off = 8; off >= 1; off >>= 1) s += __shfl_xor(s, off, 64);
        inv[r] = 1.0f / s;
    }
    #pragma unroll
    for (int df = 0; df < 8; ++df) {
        #pragma unroll
        for (int r = 0; r < 4; ++r) {
            int q = qw + lg * 4 + r;
            int d = h * HD + df * 16 + l15;
            O[(size_t)q * HID + d] = f2bf(o_acc[df][r] * inv[r]);
        }
    }
}

extern "C" void kernel_launch(void* const* d_in, const int* in_sizes, int n_in,
                              void* d_out, int out_size, void* d_ws, size_t ws_size,
                              hipStream_t stream)
{
    (void)in_sizes; (void)n_in; (void)out_size;
    const float* X    = (const float*)d_in[0];
    const int*   pos  = (const int*)d_in[1];
    const float* Wq   = (const float*)d_in[2];
    const float* Wk   = (const float*)d_in[3];
    const float* Wv   = (const float*)d_in[4];
    const float* Wo   = (const float*)d_in[5];
    const float* qn_w = (const float*)d_in[6];
    const float* qn_b = (const float*)d_in[7];
    const float* kn_w = (const float*)d_in[8];
    const float* kn_b = (const float*)d_in[9];
    float* out = (float*)d_out;

    unsigned short* Xb    = (unsigned short*)d_ws;
    unsigned short* QKVb  = (unsigned short*)((char*)d_ws + 16777216);
    unsigned short* Wt    = (unsigned short*)((char*)d_ws + 67108864);
    unsigned short* Pp    = (unsigned short*)((char*)d_ws + 100663296);
    unsigned short* Vtg   = (unsigned short*)((char*)d_ws + 134217728);
    unsigned short* P1    = (unsigned short*)((char*)d_ws + 167772160);
    unsigned short* Ab    = Xb;

    const bool splitQKV = ws_size >= (size_t)218103808;

    (void)hipFuncSetAttribute((const void*)gemm256, hipFuncAttributeMaxDynamicSharedMemorySize, 131072);
    (void)hipFuncSetAttribute((const void*)attn_fwd, hipFuncAttributeMaxDynamicSharedMemorySize, ATTN_LDS);

    dim3 blk(256);

    cvt_f32_bf16<<<dim3((S_LEN * HID / 8 + 255) / 256), blk, 0, stream>>>(X, Xb, S_LEN * HID / 8);

    W3 w3{Wq, Wk, Wv};
    cvt_w_t3<<<dim3(HID / 64, HID / 64, 3), blk, 0, stream>>>(w3, Wt, HID, HID);

    if (splitQKV) {
        gemm256<<<dim3(384, 1, 2), dim3(512), 131072, stream>>>(
            Xb, Wt, QKVb, QKV_N, HID / 2, HID, (size_t)75497472);
        v_transpose<true><<<dim3(S_LEN / 64, HID / 64), blk, 0, stream>>>(QKVb, P1, Vtg);
        ln_rope<true><<<dim3(S_LEN * 64 / 4), blk, 0, stream>>>(QKVb, P1, qn_w, qn_b, kn_w, kn_b, pos);
    } else {
        gemm256<<<dim3(384, 1, 1), dim3(512), 131072, stream>>>(
            Xb, Wt, QKVb, QKV_N, HID, HID, (size_t)0);
        v_transpose<false><<<dim3(S_LEN / 64, HID / 64), blk, 0, stream>>>(QKVb, QKVb, Vtg);
        ln_rope<false><<<dim3(S_LEN * 64 / 4), blk, 0, stream>>>(QKVb, QKVb, qn_w, qn_b, kn_w, kn_b, pos);
    }

    attn_fwd<<<dim3(S_LEN / 128, NH), dim3(512), ATTN_LDS, stream>>>(QKVb, Vtg, Ab);

    W3 wo3{Wo, Wo, Wo};
    cvt_w_t3<<<dim3(HID / 64, HID / 64, 1), blk, 0, stream>>>(wo3, Wt, HID, HID);

    gemm256<<<dim3(128, 1, 2), dim3(512), 131072, stream>>>(
        Ab, Wt, Pp, HID, HID / 2, HID, (size_t)S_LEN * HID);
    combine2<<<dim3(S_LEN * HID / 8 / 256), blk, 0, stream>>>(Pp, out);
}

// Round 16
// 483.988 us; speedup vs baseline: 7.0688x; 1.0003x over previous
//
#include <hip/hip_runtime.h>

#define S_LEN 2048
#define HID 4096
#define NH 32
#define HD 128
#define QKV_N 12288   // 3*HID

typedef __attribute__((ext_vector_type(8))) short bf16x8;
typedef __attribute__((ext_vector_type(4))) float f32x4;

__device__ __forceinline__ unsigned short f2bf(float f) {
    unsigned int u = __float_as_uint(f);
    u += 0x7FFF + ((u >> 16) & 1);
    return (unsigned short)(u >> 16);
}
__device__ __forceinline__ float bf2f(unsigned short h) {
    return __uint_as_float(((unsigned int)h) << 16);
}

typedef __attribute__((address_space(1))) const void gconst_void;
typedef __attribute__((address_space(3))) void lds_void;
__device__ __forceinline__ void gl16(const void* g, void* l) {
    __builtin_amdgcn_global_load_lds((gconst_void*)g, (lds_void*)l, 16, 0, 0);
}

#define VMCNT(n) asm volatile("s_waitcnt vmcnt(" #n ")" ::: "memory")
#define BAR()    do { asm volatile("" ::: "memory"); __builtin_amdgcn_s_barrier(); asm volatile("" ::: "memory"); } while (0)

// ---------------- fp32 -> bf16 linear convert ----------------
__global__ __launch_bounds__(256)
void cvt_f32_bf16(const float* __restrict__ in, unsigned short* __restrict__ out, int n8)
{
    int i = blockIdx.x * 256 + threadIdx.x;
    if (i >= n8) return;
    const float4* p = (const float4*)in + (size_t)i * 2;
    float4 a = p[0], b = p[1];
    bf16x8 o;
    o[0] = (short)f2bf(a.x); o[1] = (short)f2bf(a.y); o[2] = (short)f2bf(a.z); o[3] = (short)f2bf(a.w);
    o[4] = (short)f2bf(b.x); o[5] = (short)f2bf(b.y); o[6] = (short)f2bf(b.z); o[7] = (short)f2bf(b.w);
    *((bf16x8*)out + i) = o;
}

// ---------------- fp32 [K][N] -> bf16 [N][K] transpose-convert (up to 3 weights) ----------------
struct W3 { const float* w0; const float* w1; const float* w2; };

__global__ __launch_bounds__(256)
void cvt_w_t3(W3 ws3, unsigned short* __restrict__ Wt, int N, int K)
{
    __shared__ unsigned short t[64][72];
    const float* W = blockIdx.z == 0 ? ws3.w0 : (blockIdx.z == 1 ? ws3.w1 : ws3.w2);
    unsigned short* Wto = Wt + (size_t)blockIdx.z * N * K;
    const int tid = threadIdx.x;
    const int n0 = blockIdx.x * 64, k0 = blockIdx.y * 64;
    const int c4 = (tid & 15) * 4;
    const int r  = tid >> 4;
    #pragma unroll
    for (int p = 0; p < 4; ++p) {
        float4 v = *(const float4*)&W[(size_t)(k0 + r + p * 16) * N + n0 + c4];
        ushort4 o;
        o.x = f2bf(v.x); o.y = f2bf(v.y); o.z = f2bf(v.z); o.w = f2bf(v.w);
        *(ushort4*)&t[r + p * 16][c4] = o;
    }
    __syncthreads();
    const int n = tid >> 2;
    const int kq = (tid & 3) * 16;
    unsigned short* dst = &Wto[(size_t)(n0 + n) * K + k0 + kq];
    bf16x8 v0, v1;
    #pragma unroll
    for (int j = 0; j < 8; ++j) v0[j] = (short)t[kq + j][n];
    #pragma unroll
    for (int j = 0; j < 8; ++j) v1[j] = (short)t[kq + 8 + j][n];
    *(bf16x8*)dst = v0;
    *(bf16x8*)(dst + 8) = v1;
}

// ---------------- bf16 V slab [s][c] -> Vtg [c][s] transpose (+ optional split-K combine) ----------------
template<bool SPLIT>
__global__ __launch_bounds__(256)
void v_transpose(const unsigned short* __restrict__ P0, const unsigned short* __restrict__ P1,
                 unsigned short* __restrict__ Vtg)
{
    __shared__ unsigned short t[64][72];
    const int tid = threadIdx.x;
    const int s0 = blockIdx.x * 64;
    const int c0 = blockIdx.y * 64;
    #pragma unroll
    for (int i = 0; i < 2; ++i) {
        int idx = i * 256 + tid;
        int r = idx >> 3, c8 = (idx & 7) * 8;
        size_t off = (size_t)(s0 + r) * QKV_N + 2 * HID + c0 + c8;
        bf16x8 a = *(const bf16x8*)&P0[off];
        if (SPLIT) {
            bf16x8 b = *(const bf16x8*)&P1[off];
            #pragma unroll
            for (int j = 0; j < 8; ++j)
                a[j] = (short)f2bf(bf2f((unsigned short)a[j]) + bf2f((unsigned short)b[j]));
        }
        *(bf16x8*)&t[r][c8] = a;
    }
    __syncthreads();
    #pragma unroll
    for (int i = 0; i < 2; ++i) {
        int idx = i * 256 + tid;
        int oc = idx >> 3, os8 = (idx & 7) * 8;
        bf16x8 v;
        #pragma unroll
        for (int j = 0; j < 8; ++j) v[j] = (short)t[os8 + j][oc];
        *(bf16x8*)&Vtg[(size_t)(c0 + oc) * S_LEN + s0 + os8] = v;
    }
}

// ---------------- 256x256 GEMM, bf16 out, optional K-split via blockIdx.z ----------------
// single-barrier K-tile (r13); r16: all 8 stage-issues hoisted to tile top (max slack)
__device__ __forceinline__ void lda4(bf16x8 af[4][2], const char* base, int rq, int l15, int lg) {
    const int sw = (l15 & 7) << 4;
    #pragma unroll
    for (int i = 0; i < 4; ++i) {
        const char* rb = base + ((rq * 4 + i) * 16 + l15) * 128;
        af[i][0] = *(const bf16x8*)(rb + ((lg * 16) ^ sw));
        af[i][1] = *(const bf16x8*)(rb + ((64 + lg * 16) ^ sw));
    }
}
__device__ __forceinline__ void ldb2(bf16x8 bf[2][2], const char* base, int cq, int l15, int lg) {
    const int sw = (l15 & 7) << 4;
    #pragma unroll
    for (int j = 0; j < 2; ++j) {
        const char* rb = base + ((cq * 2 + j) * 16 + l15) * 128;
        bf[j][0] = *(const bf16x8*)(rb + ((lg * 16) ^ sw));
        bf[j][1] = *(const bf16x8*)(rb + ((64 + lg * 16) ^ sw));
    }
}
__device__ __forceinline__ void mfma16(f32x4 acc[8][4], const bf16x8 af[4][2], const bf16x8 bf[2][2],
                                       int mi0, int nj0) {
    __builtin_amdgcn_s_setprio(1);
    #pragma unroll
    for (int kk = 0; kk < 2; ++kk)
        #pragma unroll
        for (int i = 0; i < 4; ++i)
            #pragma unroll
            for (int j = 0; j < 2; ++j)
                acc[mi0 + i][nj0 + j] =
                    __builtin_amdgcn_mfma_f32_16x16x32_bf16(af[i][kk], bf[j][kk], acc[mi0 + i][nj0 + j], 0, 0, 0);
    __builtin_amdgcn_s_setprio(0);
}
__device__ __forceinline__ void stage2(const unsigned short* g, char* dst, int ldk, int r32, int kn) {
    gl16(g + (size_t)r32 * ldk + kn, dst);
    gl16(g + (size_t)(r32 + 8) * ldk + kn, dst + 1024);
}

__global__ __launch_bounds__(512, 2)
void gemm256(const unsigned short* __restrict__ A,   // [M][ldk] bf16
             const unsigned short* __restrict__ Bt,  // [N][ldk] bf16
             unsigned short* __restrict__ Cp,        // bf16, + z*zstride
             int N, int K, int ldk, size_t zstride)
{
    extern __shared__ char lds[];
    const int tid = threadIdx.x;
    const int l   = tid & 63;
    const int l15 = l & 15, lg = l >> 4;
    const int wid = tid >> 6;
    const int wr  = wid >> 2;
    const int wc  = wid & 3;

    const int nwg = gridDim.x;
    const int bid = blockIdx.x;
    const int ntx = N >> 8;
    const int nty = nwg / ntx;
    const int cpx = ntx >> 3;
    const int xcd = bid & 7;
    const int idx = bid >> 3;
    const int bx = xcd * cpx + idx / nty;
    const int by = idx % nty;
    const int m0 = by * 256, n0 = bx * 256;
    const int koff = blockIdx.z * K;

    char* const Abase = lds + wr * 16384;
    char* const Bbase = lds + 32768 + (wc >> 1) * 16384 + (wc & 1) * 8192;

    const int l8 = l >> 3, l7 = l & 7;
    const int swslot = (l7 ^ l8) << 3;

    const unsigned short* Ag = A  + (size_t)(m0 + wr * 128 + wc * 16 + l8) * ldk + koff + swslot;
    const unsigned short* Bg = Bt + (size_t)(n0 + wc * 64 + wr * 16 + l8) * ldk + koff + swslot;
    char* const Adst = Abase + (wc * 16) * 128 + l * 16;
    char* const Bdst = Bbase + (wr * 16) * 128 + l * 16;

    f32x4 acc[8][4] = {};
    bf16x8 af[4][2], bfA[2][2], bfB[2][2];

    stage2(Ag, Adst, ldk, 0, 0);
    stage2(Bg, Bdst, ldk, 0, 0);
    stage2(Ag, Adst + 64 * 128, ldk, 64, 0);
    stage2(Bg, Bdst + 32 * 128, ldk, 32, 0);
    VMCNT(0);
    BAR();

    const int NT = K >> 6;
    for (int t = 0; t < NT; ++t) {
        const int cb = (t & 1) * 65536, nb = cb ^ 65536;
        const int kn = (t + 1) << 6;
        const bool hn = (t + 1) < NT;

        lda4(af, Abase + cb, 0, l15, lg);
        ldb2(bfA, Bbase + cb, 0, l15, lg);
        if (hn) {
            stage2(Ag, Adst + nb, ldk, 0, kn);
            stage2(Bg, Bdst + nb, ldk, 0, kn);
            stage2(Ag, Adst + nb + 64 * 128, ldk, 64, kn);
            stage2(Bg, Bdst + nb + 32 * 128, ldk, 32, kn);
        }
        mfma16(acc, af, bfA, 0, 0);

        ldb2(bfB, Bbase + cb, 1, l15, lg);
        mfma16(acc, af, bfB, 0, 2);

        lda4(af, Abase + cb, 1, l15, lg);
        mfma16(acc, af, bfB, 4, 2);
        mfma16(acc, af, bfA, 4, 0);

        VMCNT(0);   // own 8 stages for t+1 issued a full tile ago -> usually landed
        BAR();      // all waves done reading cb; all stages visible
    }

    unsigned short* C = Cp + (size_t)blockIdx.z * zstride;
    const int crow = m0 + wr * 128 + lg * 4;
    const int ccol = n0 + wc * 64 + l15;
    #pragma unroll
    for (int mi = 0; mi < 8; ++mi)
        #pragma unroll
        for (int nj = 0; nj < 4; ++nj)
            #pragma unroll
            for (int rr = 0; rr < 4; ++rr)
                C[(size_t)(crow + mi * 16 + rr) * N + ccol + nj * 16] = f2bf(acc[mi][nj][rr]);
}

// ---------------- combine 2 bf16 split-K partials -> fp32 out ----------------
__global__ __launch_bounds__(256)
void combine2(const unsigned short* __restrict__ P, float* __restrict__ out)
{
    const size_t i = ((size_t)blockIdx.x * 256 + threadIdx.x) * 8;
    const size_t stride = (size_t)S_LEN * HID;
    bf16x8 a = *(const bf16x8*)&P[i];
    bf16x8 b = *(const bf16x8*)&P[stride + i];
    #pragma unroll
    for (int j = 0; j < 8; ++j)
        out[i + j] = bf2f((unsigned short)a[j]) + bf2f((unsigned short)b[j]);
}

// ---------------- per-head LayerNorm + RoPE (+ optional split-K combine), writes into P0 ----------------
template<bool SPLIT>
__global__ __launch_bounds__(256)
void ln_rope(unsigned short* __restrict__ P0, const unsigned short* __restrict__ P1,
             const float* __restrict__ qg, const float* __restrict__ qb,
             const float* __restrict__ kg, const float* __restrict__ kb,
             const int* __restrict__ pos)
{
    const int tid = threadIdx.x;
    const int l = tid & 63;
    const int w = tid >> 6;
    const int rid = blockIdx.x * 4 + w;
    const int s = rid >> 6;
    const int hh = rid & 63;
    const int which = hh >> 5;
    const int h = hh & 31;
    const size_t off = (size_t)s * QKV_N + which * HID + h * HD;
    unsigned short* p = P0 + off;
    const float* gamma = which ? kg : qg;
    const float* beta  = which ? kb : qb;

    float lo = bf2f(p[l]);
    float hi = bf2f(p[l + 64]);
    if (SPLIT) {
        const unsigned short* q = P1 + off;
        lo += bf2f(q[l]);
        hi += bf2f(q[l + 64]);
    }
    float sum = lo + hi;
    #pragma unroll
    for (int off2 = 32; off2 >= 1; off2 >>= 1) sum += __shfl_xor(sum, off2, 64);
    float mu = sum * (1.0f / 128.0f);
    float dlo = lo - mu, dhi = hi - mu;
    float vs = dlo * dlo + dhi * dhi;
    #pragma unroll
    for (int off2 = 32; off2 >= 1; off2 >>= 1) vs += __shfl_xor(vs, off2, 64);
    float rstd = rsqrtf(vs * (1.0f / 128.0f) + 1e-5f);
    float xlo = dlo * rstd * gamma[l] + beta[l];
    float xhi = dhi * rstd * gamma[l + 64] + beta[l + 64];

    float fpos = (float)pos[s];
    float invf = exp2f(-13.287712379549449f * (float)l * (1.0f / 64.0f));
    float ang = fpos * invf;
    float sn, cs;
    sincosf(ang, &sn, &cs);
    p[l]      = f2bf(xlo * cs - xhi * sn);
    p[l + 64] = f2bf(xhi * cs + xlo * sn);
}

// ---------------- causal flash attention: 8 waves (QBLK=128), KVB=128 ----------------
// r16: single barrier per KV-tile — end-of-tile VMCNT(0) makes V(t) visible at entry
// barrier, so the mid-tile barrier is removed and waves free-run through QK/softmax/PV.
#define KVB 128
#define ATTN_LDS 149504

__global__ __launch_bounds__(512)
void attn_fwd(const unsigned short* __restrict__ QKV,   // [S][12288]
              const unsigned short* __restrict__ Vtg,   // [4096][S]
              unsigned short* __restrict__ O)           // [S][4096]
{
    extern __shared__ char shb[];
    unsigned short* const Psw = (unsigned short*)(shb + 131072) + (threadIdx.x >> 6) * (16 * 72);

    const int tid = threadIdx.x;
    const int l = tid & 63;
    const int w = tid >> 6;
    const int l15 = l & 15, lg = l >> 4;
    const int h = blockIdx.y;
    const int qb = gridDim.x - 1 - blockIdx.x;
    const int q0 = qb * 128;
    const int qw = q0 + w * 16;

    const unsigned short* Qp = QKV + h * HD;
    const unsigned short* Kp = QKV + HID + h * HD;
    const unsigned short* Vp = Vtg + (size_t)h * HD * S_LEN;

    bf16x8 qf[4];
    #pragma unroll
    for (int d = 0; d < 4; ++d)
        qf[d] = *(const bf16x8*)&Qp[(size_t)(qw + l15) * QKV_N + d * 32 + lg * 8];

    f32x4 o_acc[8] = {};
    float mgrp = -1e30f;
    float lsum[4] = {0.0f, 0.0f, 0.0f, 0.0f};

    const float scale = 0.08838834764831845f;

    const int ksl = tid & 15;
    const int kr7 = (tid >> 4) & 7;
    const int ksg = (ksl & 8) | ((ksl ^ kr7) & 7);
    const unsigned short* Kg = Kp + (size_t)(tid >> 4) * QKV_N + ksg * 8;
    const unsigned short* Vg = Vp + (size_t)(tid >> 4) * S_LEN + ksg * 8;

#define STAGE(buf, kv0s) do {                                                          \
    _Pragma("unroll")                                                                  \
    for (int i_ = 0; i_ < 4; ++i_)                                                     \
        gl16(Kg + (size_t)((kv0s) + i_ * 32) * QKV_N,                                  \
             shb + (buf) * 32768 + (i_ * 512 + tid) * 16);                             \
    _Pragma("unroll")                                                                  \
    for (int i_ = 0; i_ < 4; ++i_)                                                     \
        gl16(Vg + (size_t)i_ * 32 * S_LEN + (kv0s),                                    \
             shb + 65536 + (buf) * 32768 + (i_ * 512 + tid) * 16);                     \
} while (0)

    STAGE(0, 0);
    VMCNT(0);        // K0 and V0 landed
    __syncthreads();

    // ledger: entering tile t, this wave's K(t),V(t) stages are landed & visible
    // (waited by the t-1-end VMCNT(0), published by the entry barrier).
    const int nt = qb + 1;
    for (int t = 0; t < nt; ++t) {
        const int kv0 = t * KVB;
        const int cur = t & 1;
        const bool hn = (t + 1) < nt;
        if (hn) STAGE(cur ^ 1, kv0 + KVB);   // 8 loads for t+1, waited at tile end

        f32x4 sc[8] = {};
        const char* Kb = shb + cur * 32768;
        #pragma unroll
        for (int kvf = 0; kvf < 8; ++kvf) {
            int r = kvf * 16 + l15;
            int sw = (r & 7) << 4;
            #pragma unroll
            for (int d = 0; d < 4; ++d) {
                bf16x8 kf = *(const bf16x8*)(Kb + r * 256 + ((d * 64 + lg * 16) ^ sw));
                sc[kvf] = __builtin_amdgcn_mfma_f32_16x16x32_bf16(qf[d], kf, sc[kvf], 0, 0, 0);
            }
        }

        const bool full = (kv0 + KVB <= qw);
        if (!full) {
            #pragma unroll
            for (int k = 0; k < 8; ++k) {
                #pragma unroll
                for (int r = 0; r < 4; ++r) {
                    int qg = qw + lg * 4 + r;
                    if (kv0 + k * 16 + l15 > qg) sc[k][r] = -1e30f;
                }
            }
        }
        float mx = fmaxf(fmaxf(sc[0][0], sc[0][1]), fmaxf(sc[0][2], sc[0][3]));
        #pragma unroll
        for (int k = 1; k < 8; ++k) {
            float m2 = fmaxf(fmaxf(sc[k][0], sc[k][1]), fmaxf(sc[k][2], sc[k][3]));
            mx = fmaxf(mx, m2);
        }
        mx *= scale;
        #pragma unroll
        for (int off = 8; off >= 1; off >>= 1) mx = fmaxf(mx, __shfl_xor(mx, off, 64));
        if (!__all(mx <= mgrp + 8.0f)) {
            float mn = fmaxf(mgrp, mx);
            float corr = __expf(mgrp - mn);
            #pragma unroll
            for (int r = 0; r < 4; ++r) lsum[r] *= corr;
            #pragma unroll
            for (int df = 0; df < 8; ++df) o_acc[df] *= corr;
            mgrp = mn;
        }
        const float mn = mgrp;

        float ph[4][4];
        #pragma unroll
        for (int r = 0; r < 4; ++r) {
            int ql = lg * 4 + r;
            float psum = 0.0f;
            #pragma unroll
            for (int k = 0; k < 8; ++k) {
                float p = __expf(fmaf(sc[k][r], scale, -mn));
                psum += p;
                if (k < 4) Psw[ql * 72 + k * 16 + l15] = f2bf(p);
                else       ph[r][k - 4] = p;
            }
            lsum[r] += psum;
        }

        // no mid barrier: V(t) already visible since tile entry; Psw is wave-private
        const char* Vb = shb + 65536 + cur * 32768;
        {
            bf16x8 pa0 = *(const bf16x8*)&Psw[l15 * 72 + lg * 8];
            bf16x8 pa1 = *(const bf16x8*)&Psw[l15 * 72 + 32 + lg * 8];
            #pragma unroll
            for (int df = 0; df < 8; ++df) {
                int d = df * 16 + l15;
                int sw = (d & 7) << 4;
                const char* vrow = Vb + d * 256;
                bf16x8 v0 = *(const bf16x8*)(vrow + ((lg * 16) ^ sw));
                bf16x8 v1 = *(const bf16x8*)(vrow + ((64 + lg * 16) ^ sw));
                o_acc[df] = __builtin_amdgcn_mfma_f32_16x16x32_bf16(pa0, v0, o_acc[df], 0, 0, 0);
                o_acc[df] = __builtin_amdgcn_mfma_f32_16x16x32_bf16(pa1, v1, o_acc[df], 0, 0, 0);
            }
        }
        #pragma unroll
        for (int r = 0; r < 4; ++r) {
            int ql = lg * 4 + r;
            #pragma unroll
            for (int k = 0; k < 4; ++k)
                Psw[ql * 72 + k * 16 + l15] = f2bf(ph[r][k]);
        }
        {
            bf16x8 pa0 = *(const bf16x8*)&Psw[l15 * 72 + lg * 8];
            bf16x8 pa1 = *(const bf16x8*)&Psw[l15 * 72 + 32 + lg * 8];
            #pragma unroll
            for (int df = 0; df < 8; ++df) {
                int d = df * 16 + l15;
                int sw = (d & 7) << 4;
                const char* vrow = Vb + d * 256;
                bf16x8 v0 = *(const bf16x8*)(vrow + ((128 + lg * 16) ^ sw));
                bf16x8 v1 = *(const bf16x8*)(vrow + ((128 + 64 + lg * 16) ^ sw));
                o_acc[df] = __builtin_amdgcn_mfma_f32_16x16x32_bf16(pa0, v0, o_acc[df], 0, 0, 0);
                o_acc[df] = __builtin_amdgcn_mfma_f32_16x16x32_bf16(pa1, v1, o_acc[df], 0, 0, 0);
            }
        }

        if (hn) {
            VMCNT(0);   // K(t+1),V(t+1) landed (issued a full tile ago)
            BAR();      // all waves done reading cur; stages visible
        }
    }
#undef STAGE

    float inv[4];
    #pragma unroll
    for (int r = 0; r < 4; ++r) {
        float s = lsum[r];
        #pragma unroll
        for (int off = 8; off >= 1; off >>= 1) s += __shfl_xor(s, off, 64);
        inv[r] = 1.0f / s;
    }
    #pragma unroll
    for (int df = 0; df < 8; ++df) {
        #pragma unroll
        for (int r = 0; r < 4; ++r) {
            int q = qw + lg * 4 + r;
            int d = h * HD + df * 16 + l15;
            O[(size_t)q * HID + d] = f2bf(o_acc[df][r] * inv[r]);
        }
    }
}

extern "C" void kernel_launch(void* const* d_in, const int* in_sizes, int n_in,
                              void* d_out, int out_size, void* d_ws, size_t ws_size,
                              hipStream_t stream)
{
    (void)in_sizes; (void)n_in; (void)out_size;
    const float* X    = (const float*)d_in[0];
    const int*   pos  = (const int*)d_in[1];
    const float* Wq   = (const float*)d_in[2];
    const float* Wk   = (const float*)d_in[3];
    const float* Wv   = (const float*)d_in[4];
    const float* Wo   = (const float*)d_in[5];
    const float* qn_w = (const float*)d_in[6];
    const float* qn_b = (const float*)d_in[7];
    const float* kn_w = (const float*)d_in[8];
    const float* kn_b = (const float*)d_in[9];
    float* out = (float*)d_out;

    unsigned short* Xb    = (unsigned short*)d_ws;
    unsigned short* QKVb  = (unsigned short*)((char*)d_ws + 16777216);
    unsigned short* Wt    = (unsigned short*)((char*)d_ws + 67108864);
    unsigned short* Pp    = (unsigned short*)((char*)d_ws + 100663296);
    unsigned short* Vtg   = (unsigned short*)((char*)d_ws + 134217728);
    unsigned short* P1    = (unsigned short*)((char*)d_ws + 167772160);
    unsigned short* Ab    = Xb;

    const bool splitQKV = ws_size >= (size_t)218103808;

    (void)hipFuncSetAttribute((const void*)gemm256, hipFuncAttributeMaxDynamicSharedMemorySize, 131072);
    (void)hipFuncSetAttribute((const void*)attn_fwd, hipFuncAttributeMaxDynamicSharedMemorySize, ATTN_LDS);

    dim3 blk(256);

    cvt_f32_bf16<<<dim3((S_LEN * HID / 8 + 255) / 256), blk, 0, stream>>>(X, Xb, S_LEN * HID / 8);

    W3 w3{Wq, Wk, Wv};
    cvt_w_t3<<<dim3(HID / 64, HID / 64, 3), blk, 0, stream>>>(w3, Wt, HID, HID);

    if (splitQKV) {
        gemm256<<<dim3(384, 1, 2), dim3(512), 131072, stream>>>(
            Xb, Wt, QKVb, QKV_N, HID / 2, HID, (size_t)75497472);
        v_transpose<true><<<dim3(S_LEN / 64, HID / 64), blk, 0, stream>>>(QKVb, P1, Vtg);
        ln_rope<true><<<dim3(S_LEN * 64 / 4), blk, 0, stream>>>(QKVb, P1, qn_w, qn_b, kn_w, kn_b, pos);
    } else {
        gemm256<<<dim3(384, 1, 1), dim3(512), 131072, stream>>>(
            Xb, Wt, QKVb, QKV_N, HID, HID, (size_t)0);
        v_transpose<false><<<dim3(S_LEN / 64, HID / 64), blk, 0, stream>>>(QKVb, QKVb, Vtg);
        ln_rope<false><<<dim3(S_LEN * 64 / 4), blk, 0, stream>>>(QKVb, QKVb, qn_w, qn_b, kn_w, kn_b, pos);
    }

    attn_fwd<<<dim3(S_LEN / 128, NH), dim3(512), ATTN_LDS, stream>>>(QKVb, Vtg, Ab);

    W3 wo3{Wo, Wo, Wo};
    cvt_w_t3<<<dim3(HID / 64, HID / 64, 1), blk, 0, stream>>>(wo3, Wt, HID, HID);

    gemm256<<<dim3(128, 1, 2), dim3(512), 131072, stream>>>(
        Ab, Wt, Pp, HID, HID / 2, HID, (size_t)S_LEN * HID);
    combine2<<<dim3(S_LEN * HID / 8 / 256), blk, 0, stream>>>(Pp, out);
}